// Round 11
// baseline (584.443 us; speedup 1.0000x reference)
//
#include <hip/hip_runtime.h>

typedef __bf16 bf16_t;
typedef __bf16 bf16x8 __attribute__((ext_vector_type(8)));
typedef __bf16 bf16x4 __attribute__((ext_vector_type(4)));
typedef float  f32x4  __attribute__((ext_vector_type(4)));
typedef float  f32x16 __attribute__((ext_vector_type(16)));

#define NB   2
#define NS   2048
#define ND   4096
#define NH   32
#define NKVH 8
#define NHD  128

#define BAR()    asm volatile("s_barrier" ::: "memory")
#define LGKM0()  asm volatile("s_waitcnt lgkmcnt(0)" ::: "memory")
#define VMCNT6() asm volatile("s_waitcnt vmcnt(6)" ::: "memory")
#define VMCNT5() asm volatile("s_waitcnt vmcnt(5)" ::: "memory")
#define VMCNT0() asm volatile("s_waitcnt vmcnt(0)" ::: "memory")

__device__ __forceinline__ void gl_lds16(const bf16_t* g, bf16_t* l) {
  __builtin_amdgcn_global_load_lds(
      (const __attribute__((address_space(1))) void*)g,
      (__attribute__((address_space(3))) void*)l, 16, 0, 0);
}

// ---------------- convert x fp32 -> bf16 ----------------
__global__ void convert_f32_bf16(const float* __restrict__ in, bf16_t* __restrict__ out, int n4) {
  int i = blockIdx.x * 256 + threadIdx.x;
  if (i < n4) {
    f32x4 v = *(const f32x4*)&in[(size_t)i * 4];
    bf16x4 o;
    #pragma unroll
    for (int j = 0; j < 4; ++j) o[j] = (bf16_t)v[j];
    *(bf16x4*)&out[(size_t)i * 4] = o;
  }
}

// ------------- transpose-convert W[4096][Nin] fp32 -> Wt[Nin][4096] bf16 -------------
__global__ void transpose_convert(const float* __restrict__ in, bf16_t* __restrict__ out, int Nin) {
  __shared__ float t[32][33];
  int tx = threadIdx.x & 31, ty = threadIdx.x >> 5;
  int n0 = blockIdx.x * 32, k0 = blockIdx.y * 32;
  #pragma unroll
  for (int i = 0; i < 4; ++i)
    t[ty + i * 8][tx] = in[(size_t)(k0 + ty + i * 8) * Nin + n0 + tx];
  __syncthreads();
  #pragma unroll
  for (int i = 0; i < 4; ++i)
    out[(size_t)(n0 + ty + i * 8) * 4096 + k0 + tx] = (bf16_t)t[tx][ty + i * 8];
}

// ============ 256x192 GEMM for QKV (R8-proven schedule + lgkm0-after-bar + unroll2) ============
// Grid 16x32 = 512 blocks = 2 full dispatch rounds (100% packing). bf16 out.
// RACE AUDIT (correct): each wave reads its As[cur][wm] half across ALL 4 phases
// (mh0 @p0/p2, mh1 @p1/p2) -> stages into `cur` ONLY at p3, after p2's last reads.
// Ah1(t+1)->nxt at p0: As[nxt][1] last read at tile t-1's p2. vmcnt FIFO: enter tile
// with 5 outstanding; +2 @p0 = 7; +5 @p3 = 12; vmcnt(5) drains 7 = tile t+1 complete.
__global__ __launch_bounds__(512, 2) void gemm192(const bf16_t* __restrict__ A,
                                                  const bf16_t* __restrict__ Bt,
                                                  bf16_t* __restrict__ C, int M, int N, int K) {
  __shared__ __align__(16) bf16_t As[2][2][128 * 64];
  __shared__ __align__(16) bf16_t Bs[2][192 * 64];
  const int tid = threadIdx.x, lane = tid & 63, wid = tid >> 6;
  const int l15 = lane & 15, l4 = lane >> 4;
  const int wm = wid >> 2, wn = wid & 3;

  const int gx = gridDim.x;
  const int nwg = gx * gridDim.y;
  const int id = blockIdx.y * gx + blockIdx.x;
  const int wg = (id & 7) * (nwg >> 3) + (id >> 3);
  const int bx = wg % gx, by = wg / gx;
  const int row0 = bx * 256, col0 = by * 192;

  const bf16_t* Ab = A + (size_t)row0 * K;
  const bf16_t* Bb = Bt + (size_t)col0 * K;

  auto stA = [&](int t, int h, int buf) {
    #pragma unroll
    for (int i = 0; i < 2; ++i) {
      int phys = i * 8192 + tid * 16;
      int logi = phys ^ (((phys >> 8) & 7) << 4);
      gl_lds16(Ab + (size_t)(h * 128 + (logi >> 7)) * K + t * 64 + ((logi & 127) >> 1),
               &As[buf][h][phys >> 1]);
    }
  };
  auto stB = [&](int t, int buf) {
    #pragma unroll
    for (int i = 0; i < 3; ++i) {
      int phys = i * 8192 + tid * 16;
      int logi = phys ^ (((phys >> 8) & 7) << 4);
      gl_lds16(Bb + (size_t)(logi >> 7) * K + t * 64 + ((logi & 127) >> 1),
               &Bs[buf][phys >> 1]);
    }
  };

  f32x4 acc[8][3];
  #pragma unroll
  for (int m = 0; m < 8; ++m)
    #pragma unroll
    for (int n = 0; n < 3; ++n)
      #pragma unroll
      for (int j = 0; j < 4; ++j) acc[m][n][j] = 0.f;

  const int nt = K >> 6;
  stA(0, 0, 0); stA(0, 1, 0); stB(0, 0);
  stA(1, 0, 1); stB(1, 1);
  VMCNT5();
  BAR();

  auto ardA = [&](int buf, int mh, int kh, int mf) -> bf16x8 {
    int lb = (mh * 64 + mf * 16 + l15) * 128 + kh * 64 + l4 * 16;
    return *(const bf16x8*)&As[buf][wm][(lb ^ (((lb >> 8) & 7) << 4)) >> 1];
  };
  auto brdB = [&](int buf, int kh, int nf) -> bf16x8 {
    int lb = (wn * 48 + nf * 16 + l15) * 128 + kh * 64 + l4 * 16;
    return *(const bf16x8*)&Bs[buf][(lb ^ (((lb >> 8) & 7) << 4)) >> 1];
  };

  #pragma unroll 2
  for (int t = 0; t < nt; ++t) {
    const int cur = t & 1, nxt = cur ^ 1;
    bf16x8 a00[4], a10[4], a11[4], a01[4], b0[3], b1[3];

    // ---- p0: read a00(4)+b0(3); stage Ah1(t+1)->nxt; MFMA mh0 x kh0 ----
    #pragma unroll
    for (int mf = 0; mf < 4; ++mf) a00[mf] = ardA(cur, 0, 0, mf);
    #pragma unroll
    for (int nf = 0; nf < 3; ++nf) b0[nf] = brdB(cur, 0, nf);
    if (t + 1 < nt) stA(t + 1, 1, nxt);
    BAR();
    LGKM0();
    __builtin_amdgcn_s_setprio(1);
    #pragma unroll
    for (int mf = 0; mf < 4; ++mf)
      #pragma unroll
      for (int nf = 0; nf < 3; ++nf)
        acc[mf][nf] = __builtin_amdgcn_mfma_f32_16x16x32_bf16(a00[mf], b0[nf], acc[mf][nf], 0, 0, 0);
    __builtin_amdgcn_s_setprio(0);
    BAR();

    // ---- p1: read a10(4); MFMA mh1 x kh0 ----
    #pragma unroll
    for (int mf = 0; mf < 4; ++mf) a10[mf] = ardA(cur, 1, 0, mf);
    BAR();
    LGKM0();
    __builtin_amdgcn_s_setprio(1);
    #pragma unroll
    for (int mf = 0; mf < 4; ++mf)
      #pragma unroll
      for (int nf = 0; nf < 3; ++nf)
        acc[4 + mf][nf] = __builtin_amdgcn_mfma_f32_16x16x32_bf16(a10[mf], b0[nf], acc[4 + mf][nf], 0, 0, 0);
    __builtin_amdgcn_s_setprio(0);
    BAR();

    // ---- p2: read a11(4)+b1(3)+a01(4); MFMA mh1 x kh1 ----
    #pragma unroll
    for (int mf = 0; mf < 4; ++mf) a11[mf] = ardA(cur, 1, 1, mf);
    #pragma unroll
    for (int nf = 0; nf < 3; ++nf) b1[nf] = brdB(cur, 1, nf);
    #pragma unroll
    for (int mf = 0; mf < 4; ++mf) a01[mf] = ardA(cur, 0, 1, mf);
    BAR();
    LGKM0();
    __builtin_amdgcn_s_setprio(1);
    #pragma unroll
    for (int mf = 0; mf < 4; ++mf)
      #pragma unroll
      for (int nf = 0; nf < 3; ++nf)
        acc[4 + mf][nf] = __builtin_amdgcn_mfma_f32_16x16x32_bf16(a11[mf], b1[nf], acc[4 + mf][nf], 0, 0, 0);
    __builtin_amdgcn_s_setprio(0);
    BAR();

    // ---- p3: stage Ah0(t+2)+B(t+2)->cur (last reads @p2); MFMA mh0 x kh1 (regs only) ----
    if (t + 2 < nt) { stA(t + 2, 0, cur); stB(t + 2, cur); }
    __builtin_amdgcn_s_setprio(1);
    #pragma unroll
    for (int mf = 0; mf < 4; ++mf)
      #pragma unroll
      for (int nf = 0; nf < 3; ++nf)
        acc[mf][nf] = __builtin_amdgcn_mfma_f32_16x16x32_bf16(a01[mf], b1[nf], acc[mf][nf], 0, 0, 0);
    __builtin_amdgcn_s_setprio(0);
    if (t + 2 < nt) { VMCNT5(); } else { VMCNT0(); }
    BAR();
  }

  #pragma unroll
  for (int mh = 0; mh < 2; ++mh)
    #pragma unroll
    for (int mf = 0; mf < 4; ++mf)
      #pragma unroll
      for (int nf = 0; nf < 3; ++nf)
        #pragma unroll
        for (int r = 0; r < 4; ++r) {
          size_t row = (size_t)row0 + wm * 128 + mh * 64 + mf * 16 + l4 * 4 + r;
          size_t col = (size_t)col0 + wn * 48 + nf * 16 + l15;
          C[row * N + col] = (bf16_t)acc[mh * 4 + mf][nf][r];
        }
}

// ============ 256x256 GEMM for WO (R8-proven schedule + lgkm0-after-bar + unroll2) ============
// Grid 16x16 = 256 blocks = exactly 1 dispatch round. f32 out. vmcnt(6): enter tile
// with 6 outstanding; +2 @p0 = 8; +6 @p3 = 14; vmcnt(6) drains 8 = tile t+1 complete.
__global__ __launch_bounds__(512, 2) void gemm256j(const bf16_t* __restrict__ A,
                                                   const bf16_t* __restrict__ Bt,
                                                   float* __restrict__ C, int M, int N, int K) {
  __shared__ __align__(16) bf16_t As[2][2][128 * 64];
  __shared__ __align__(16) bf16_t Bs[2][256 * 64];
  const int tid = threadIdx.x, lane = tid & 63, wid = tid >> 6;
  const int l15 = lane & 15, l4 = lane >> 4;
  const int wm = wid >> 2, wn = wid & 3;

  const int gx = gridDim.x;
  const int nwg = gx * gridDim.y;
  const int id = blockIdx.y * gx + blockIdx.x;
  const int wg = (id & 7) * (nwg >> 3) + (id >> 3);
  const int bx = wg % gx, by = wg / gx;
  const int row0 = bx * 256, col0 = by * 256;

  const bf16_t* Ab = A + (size_t)row0 * K;
  const bf16_t* Bb = Bt + (size_t)col0 * K;

  auto stA = [&](int t, int h, int buf) {
    #pragma unroll
    for (int i = 0; i < 2; ++i) {
      int phys = i * 8192 + tid * 16;
      int logi = phys ^ (((phys >> 8) & 7) << 4);
      gl_lds16(Ab + (size_t)(h * 128 + (logi >> 7)) * K + t * 64 + ((logi & 127) >> 1),
               &As[buf][h][phys >> 1]);
    }
  };
  auto stB = [&](int t, int buf) {
    #pragma unroll
    for (int i = 0; i < 4; ++i) {
      int phys = i * 8192 + tid * 16;
      int logi = phys ^ (((phys >> 8) & 7) << 4);
      gl_lds16(Bb + (size_t)(logi >> 7) * K + t * 64 + ((logi & 127) >> 1),
               &Bs[buf][phys >> 1]);
    }
  };

  f32x4 acc[8][4];
  #pragma unroll
  for (int m = 0; m < 8; ++m)
    #pragma unroll
    for (int n = 0; n < 4; ++n)
      #pragma unroll
      for (int j = 0; j < 4; ++j) acc[m][n][j] = 0.f;

  const int nt = K >> 6;
  stA(0, 0, 0); stA(0, 1, 0); stB(0, 0);
  stA(1, 0, 1); stB(1, 1);
  VMCNT6();
  BAR();

  auto ardA = [&](int buf, int mh, int kh, int mf) -> bf16x8 {
    int lb = (mh * 64 + mf * 16 + l15) * 128 + kh * 64 + l4 * 16;
    return *(const bf16x8*)&As[buf][wm][(lb ^ (((lb >> 8) & 7) << 4)) >> 1];
  };
  auto brdB = [&](int buf, int kh, int nf) -> bf16x8 {
    int lb = (wn * 64 + nf * 16 + l15) * 128 + kh * 64 + l4 * 16;
    return *(const bf16x8*)&Bs[buf][(lb ^ (((lb >> 8) & 7) << 4)) >> 1];
  };

  #pragma unroll 2
  for (int t = 0; t < nt; ++t) {
    const int cur = t & 1, nxt = cur ^ 1;
    bf16x8 a00[4], a10[4], a11[4], a01[4], b0[4], b1[4];

    // ---- p0: read a00(4)+b0(4); stage Ah1(t+1)->nxt; MFMA mh0 x kh0 ----
    #pragma unroll
    for (int mf = 0; mf < 4; ++mf) a00[mf] = ardA(cur, 0, 0, mf);
    #pragma unroll
    for (int nf = 0; nf < 4; ++nf) b0[nf] = brdB(cur, 0, nf);
    if (t + 1 < nt) stA(t + 1, 1, nxt);
    BAR();
    LGKM0();
    __builtin_amdgcn_s_setprio(1);
    #pragma unroll
    for (int mf = 0; mf < 4; ++mf)
      #pragma unroll
      for (int nf = 0; nf < 4; ++nf)
        acc[mf][nf] = __builtin_amdgcn_mfma_f32_16x16x32_bf16(a00[mf], b0[nf], acc[mf][nf], 0, 0, 0);
    __builtin_amdgcn_s_setprio(0);
    BAR();

    // ---- p1: read a10(4); MFMA mh1 x kh0 ----
    #pragma unroll
    for (int mf = 0; mf < 4; ++mf) a10[mf] = ardA(cur, 1, 0, mf);
    BAR();
    LGKM0();
    __builtin_amdgcn_s_setprio(1);
    #pragma unroll
    for (int mf = 0; mf < 4; ++mf)
      #pragma unroll
      for (int nf = 0; nf < 4; ++nf)
        acc[4 + mf][nf] = __builtin_amdgcn_mfma_f32_16x16x32_bf16(a10[mf], b0[nf], acc[4 + mf][nf], 0, 0, 0);
    __builtin_amdgcn_s_setprio(0);
    BAR();

    // ---- p2: read a11(4)+b1(4)+a01(4); MFMA mh1 x kh1 ----
    #pragma unroll
    for (int mf = 0; mf < 4; ++mf) a11[mf] = ardA(cur, 1, 1, mf);
    #pragma unroll
    for (int nf = 0; nf < 4; ++nf) b1[nf] = brdB(cur, 1, nf);
    #pragma unroll
    for (int mf = 0; mf < 4; ++mf) a01[mf] = ardA(cur, 0, 1, mf);
    BAR();
    LGKM0();
    __builtin_amdgcn_s_setprio(1);
    #pragma unroll
    for (int mf = 0; mf < 4; ++mf)
      #pragma unroll
      for (int nf = 0; nf < 4; ++nf)
        acc[4 + mf][nf] = __builtin_amdgcn_mfma_f32_16x16x32_bf16(a11[mf], b1[nf], acc[4 + mf][nf], 0, 0, 0);
    __builtin_amdgcn_s_setprio(0);
    BAR();

    // ---- p3: stage Ah0(t+2)+B(t+2)->cur (last reads @p2); MFMA mh0 x kh1 (regs only) ----
    if (t + 2 < nt) { stA(t + 2, 0, cur); stB(t + 2, cur); }
    __builtin_amdgcn_s_setprio(1);
    #pragma unroll
    for (int mf = 0; mf < 4; ++mf)
      #pragma unroll
      for (int nf = 0; nf < 4; ++nf)
        acc[mf][nf] = __builtin_amdgcn_mfma_f32_16x16x32_bf16(a01[mf], b1[nf], acc[mf][nf], 0, 0, 0);
    __builtin_amdgcn_s_setprio(0);
    if (t + 2 < nt) { VMCNT6(); } else { VMCNT0(); }
    BAR();
  }

  #pragma unroll
  for (int mh = 0; mh < 2; ++mh)
    #pragma unroll
    for (int mf = 0; mf < 4; ++mf)
      #pragma unroll
      for (int nf = 0; nf < 4; ++nf)
        #pragma unroll
        for (int r = 0; r < 4; ++r) {
          size_t row = (size_t)row0 + wm * 128 + mh * 64 + mf * 16 + l4 * 4 + r;
          size_t col = (size_t)col0 + wn * 64 + nf * 16 + l15;
          C[row * N + col] = acc[mh * 4 + mf][nf][r];
        }
}

// ---------------- RoPE on Q and K, reshape to [b][h][s][hd] ----------------
__global__ void rope_qk(const bf16_t* __restrict__ qkv, const float* __restrict__ cosT,
                        const float* __restrict__ sinT, bf16_t* __restrict__ Q,
                        bf16_t* __restrict__ Kout) {
  int it = blockIdx.x * 256 + threadIdx.x;
  int chunk = it & 15;
  int hs = (it >> 4) % 40;
  int m = (it >> 4) / 40;
  int b = m >> 11, srow = m & 2047;

  bf16x8 v = *(const bf16x8*)&qkv[(size_t)m * 6144 + hs * 128 + chunk * 8];
  f32x4 c4 = *(const f32x4*)&cosT[(size_t)srow * 64 + chunk * 4];
  f32x4 s4 = *(const f32x4*)&sinT[(size_t)srow * 64 + chunk * 4];
  bf16x8 o;
  #pragma unroll
  for (int j = 0; j < 4; ++j) {
    float t1 = (float)v[2 * j], t2 = (float)v[2 * j + 1];
    o[2 * j]     = (bf16_t)(t1 * c4[j] - t2 * s4[j]);
    o[2 * j + 1] = (bf16_t)(t1 * s4[j] + t2 * c4[j]);
  }
  bf16_t* dst;
  if (hs < 32) dst = Q + (((size_t)(b * 32 + hs)) * 2048 + srow) * 128 + chunk * 8;
  else         dst = Kout + (((size_t)(b * 8 + (hs - 32))) * 2048 + srow) * 128 + chunk * 8;
  *(bf16x8*)dst = o;
}

// ---------------- transpose V section of qkv -> Vt[b*8+kv][128][2048] ----------------
__global__ void transpose_v(const bf16_t* __restrict__ qkv, bf16_t* __restrict__ Vt) {
  __shared__ bf16_t t[32][33];
  int tx = threadIdx.x & 31, ty = threadIdx.x >> 5;
  int s0 = blockIdx.x * 32, d0 = blockIdx.y * 32, g = blockIdx.z;
  int b = g >> 3, kv = g & 7;
  const bf16_t* src = qkv + (size_t)(b * 2048) * 6144 + 5120 + kv * 128;
  #pragma unroll
  for (int i = 0; i < 4; ++i)
    t[ty + i * 8][tx] = src[(size_t)(s0 + ty + i * 8) * 6144 + d0 + tx];
  __syncthreads();
  bf16_t* dst = Vt + (size_t)g * 128 * 2048;
  #pragma unroll
  for (int i = 0; i < 4; ++i)
    dst[(size_t)(d0 + ty + i * 8) * 2048 + s0 + tx] = t[tx][ty + i * 8];
}

// ---------------- causal flash attention, 8-wave swapped-QK in-register softmax ----------------
__global__ __launch_bounds__(512, 2) void attn_kernel(const bf16_t* __restrict__ Q,
                                                      const bf16_t* __restrict__ Kc,
                                                      const bf16_t* __restrict__ Vt,
                                                      bf16_t* __restrict__ Oout) {
  __shared__ __align__(16) bf16_t Ks[2][64 * 128];
  __shared__ __align__(16) bf16_t Vs[2][128 * 64];

  const int tid = threadIdx.x, wid = tid >> 6, lane = tid & 63;
  const int l31 = lane & 31, hi = lane >> 5;
  const int bh = blockIdx.y;
  const int b = bh >> 5, h = bh & 31, kv = h >> 2;
  const int pr = blockIdx.x;

  const bf16_t* Qp = Q + ((size_t)bh * 2048) * 128;
  const bf16_t* Kp = Kc + ((size_t)(b * 8 + kv) * 2048) * 128;
  const bf16_t* Vp = Vt + ((size_t)(b * 8 + kv) * 128) * 2048;

  const float kscale = 0.08838834764831845f * 1.44269504088896f;
  const int qoff = (wid < 4) ? wid * 32 : 224 - (wid - 4) * 32;

  auto stage = [&](int kt, int buf) {
    const int k0 = kt * 64;
    #pragma unroll
    for (int i = 0; i < 2; ++i) {
      int phys = i * 8192 + tid * 16;
      int logi = phys ^ (((phys >> 8) & 15) << 4);
      gl_lds16(Kp + (size_t)(k0 + (phys >> 8)) * 128 + ((logi & 255) >> 1), &Ks[buf][phys >> 1]);
    }
    #pragma unroll
    for (int i = 0; i < 2; ++i) {
      int phys = i * 8192 + tid * 16;
      int logi = phys ^ (((phys >> 7) & 7) << 4);
      gl_lds16(Vp + (size_t)(phys >> 7) * 2048 + k0 + ((logi & 127) >> 1), &Vs[buf][phys >> 1]);
    }
  };

  for (int half = 0; half < 2; ++half) {
    const int qt = half ? pr : 7 - pr;
    const int q0b = qt * 256;
    const int q0w = q0b + qoff;
    const int qg = q0w + l31;
    const int nkt = (qt + 1) * 4;

    bf16x8 qf[8];
    #pragma unroll
    for (int c = 0; c < 8; ++c) {
      bf16x8 t = *(const bf16x8*)&Qp[(size_t)qg * 128 + c * 16 + hi * 8];
      #pragma unroll
      for (int j = 0; j < 8; ++j) t[j] = (bf16_t)((float)t[j] * kscale);
      qf[c] = t;
    }

    f32x16 oa[4];
    #pragma unroll
    for (int nc = 0; nc < 4; ++nc)
      #pragma unroll
      for (int r = 0; r < 16; ++r) oa[nc][r] = 0.f;
    float m_old = -1e30f, lrow = 0.f;

    stage(0, 0);
    __syncthreads();

    for (int kt = 0; kt < nkt; ++kt) {
      const int k0 = kt * 64, cur = kt & 1;
      if (kt + 1 < nkt) stage(kt + 1, cur ^ 1);

      if (k0 <= q0w + 31) {
        f32x16 s0, s1;
        #pragma unroll
        for (int r = 0; r < 16; ++r) { s0[r] = 0.f; s1[r] = 0.f; }
        __builtin_amdgcn_s_setprio(1);
        #pragma unroll
        for (int c = 0; c < 8; ++c) {
          int lb0 = l31 * 256 + c * 32 + hi * 16;
          int pb0 = lb0 ^ (((lb0 >> 8) & 15) << 4);
          bf16x8 kf0 = *(const bf16x8*)&Ks[cur][pb0 >> 1];
          s0 = __builtin_amdgcn_mfma_f32_32x32x16_bf16(kf0, qf[c], s0, 0, 0, 0);
          int lb1 = (32 + l31) * 256 + c * 32 + hi * 16;
          int pb1 = lb1 ^ (((lb1 >> 8) & 15) << 4);
          bf16x8 kf1 = *(const bf16x8*)&Ks[cur][pb1 >> 1];
          s1 = __builtin_amdgcn_mfma_f32_32x32x16_bf16(kf1, qf[c], s1, 0, 0, 0);
        }
        __builtin_amdgcn_s_setprio(0);

        if (k0 + 63 > q0w) {
          #pragma unroll
          for (int r = 0; r < 16; ++r) {
            int key0 = k0 + ((r & 3) + 8 * (r >> 2)) + 4 * hi;
            if (key0 > qg) s0[r] = -1e30f;
            if (key0 + 32 > qg) s1[r] = -1e30f;
          }
        }

        float m8[8];
        #pragma unroll
        for (int j = 0; j < 8; ++j)
          m8[j] = fmaxf(fmaxf(s0[j], s0[j + 8]), fmaxf(s1[j], s1[j + 8]));
        float ma = fmaxf(fmaxf(m8[0], m8[4]), fmaxf(m8[1], m8[5]));
        float mb = fmaxf(fmaxf(m8[2], m8[6]), fmaxf(m8[3], m8[7]));
        float mh = fmaxf(ma, mb);
        float mfull = fmaxf(mh, __shfl_xor(mh, 32));
        float mn = fmaxf(m_old, mfull);
        bool nores = (mfull <= m_old);
        float sc = exp2f(m_old - mn);
        m_old = mn;

        if (!__all((int)nores)) {
          #pragma unroll
          for (int r = 0; r < 16; ++r) {
            int qi = (r & 3) + 8 * (r >> 2) + 4 * hi;
            float scv = __int_as_float(__builtin_amdgcn_ds_bpermute(qi << 2, __float_as_int(sc)));
            oa[0][r] *= scv; oa[1][r] *= scv; oa[2][r] *= scv; oa[3][r] *= scv;
          }
        }

        #pragma unroll
        for (int r = 0; r < 16; ++r) {
          s0[r] = exp2f(s0[r] - mn);
          s1[r] = exp2f(s1[r] - mn);
        }
        float rsA = 0.f, rsB = 0.f, rsC = 0.f, rsD = 0.f;
        #pragma unroll
        for (int r = 0; r < 16; r += 4) {
          rsA += s0[r];     rsB += s0[r + 1]; rsC += s0[r + 2]; rsD += s0[r + 3];
          rsA += s1[r];     rsB += s1[r + 1]; rsC += s1[r + 2]; rsD += s1[r + 3];
        }
        float rs = (rsA + rsB) + (rsC + rsD);
        rs += __shfl_xor(rs, 32);
        lrow = lrow * sc + rs;

        #pragma unroll
        for (int ks = 0; ks < 4; ++ks) {
          const int qi0 = (ks & 1) * 8;
          union { bf16_t hh[4]; int ii[2]; } ku, su;
          #pragma unroll
          for (int j = 0; j < 4; ++j) {
            float lo, hv;
            if (ks >> 1) { lo = s1[qi0 + j]; hv = s1[qi0 + 4 + j]; }
            else         { lo = s0[qi0 + j]; hv = s0[qi0 + 4 + j]; }
            ku.hh[j] = (bf16_t)(hi ? hv : lo);
            su.hh[j] = (bf16_t)(hi ? lo : hv);
          }
          int r0 = __shfl_xor(su.ii[0], 32), r1 = __shfl_xor(su.ii[1], 32);
          union { int ii[4]; bf16x8 v; } fa;
          fa.ii[0] = hi ? r0 : ku.ii[0];
          fa.ii[1] = hi ? r1 : ku.ii[1];
          fa.ii[2] = hi ? ku.ii[0] : r0;
          fa.ii[3] = hi ? ku.ii[1] : r1;
          __builtin_amdgcn_s_setprio(1);
          #pragma unroll
          for (int nc = 0; nc < 4; ++nc) {
            int lb = (nc * 32 + l31) * 128 + ks * 32 + hi * 16;
            int pb = lb ^ (((lb >> 7) & 7) << 4);
            bf16x8 vf = *(const bf16x8*)&Vs[cur][pb >> 1];
            oa[nc] = __builtin_amdgcn_mfma_f32_32x32x16_bf16(fa.v, vf, oa[nc], 0, 0, 0);
          }
          __builtin_amdgcn_s_setprio(0);
        }
      }
      __syncthreads();
    }

    float inv = 1.0f / lrow;
    bf16_t* Op = Oout + ((size_t)(b * 2048 + q0w)) * 4096 + (size_t)h * 128;
    #pragma unroll
    for (int r = 0; r < 16; ++r) {
      int qi = (r & 3) + 8 * (r >> 2) + 4 * hi;
      float iv = __int_as_float(__builtin_amdgcn_ds_bpermute(qi << 2, __float_as_int(inv)));
      #pragma unroll
      for (int nc = 0; nc < 4; ++nc)
        Op[(size_t)qi * 4096 + nc * 32 + l31] = (bf16_t)(oa[nc][r] * iv);
    }
  }
}

extern "C" void kernel_launch(void* const* d_in, const int* in_sizes, int n_in,
                              void* d_out, int out_size, void* d_ws, size_t ws_size,
                              hipStream_t stream) {
  const float* x    = (const float*)d_in[0];
  const float* cosT = (const float*)d_in[1];
  const float* sinT = (const float*)d_in[2];
  const float* wq   = (const float*)d_in[3];
  const float* wk   = (const float*)d_in[4];
  const float* wv   = (const float*)d_in[5];
  const float* wo   = (const float*)d_in[6];
  float* out = (float*)d_out;
  char* ws = (char*)d_ws;

  bf16_t* wqkvT = (bf16_t*)(ws + 0);           // 6144*4096*2
  bf16_t* woT   = wqkvT;                       // reused after QKV GEMM
  bf16_t* xb    = (bf16_t*)(ws + 50331648);    // 4096*4096*2
  bf16_t* Qb    = xb;                          // reused after QKV GEMM
  bf16_t* qkv   = (bf16_t*)(ws + 83886080);    // 4096*6144*2
  bf16_t* attn_out = qkv;                      // reused after rope/transpose_v
  bf16_t* Kb    = (bf16_t*)(ws + 134217728);
  bf16_t* Vt    = (bf16_t*)(ws + 142606336);

  convert_f32_bf16<<<16384, 256, 0, stream>>>(x, xb, 4194304);
  transpose_convert<<<dim3(128, 128), 256, 0, stream>>>(wq, wqkvT, 4096);
  transpose_convert<<<dim3(32, 128), 256, 0, stream>>>(wk, wqkvT + (size_t)4096 * 4096, 1024);
  transpose_convert<<<dim3(32, 128), 256, 0, stream>>>(wv, wqkvT + (size_t)5120 * 4096, 1024);

  gemm192<<<dim3(16, 32), 512, 0, stream>>>(xb, wqkvT, qkv, 4096, 6144, 4096);

  transpose_convert<<<dim3(128, 128), 256, 0, stream>>>(wo, woT, 4096);  // wqkvT now dead
  rope_qk<<<10240, 256, 0, stream>>>(qkv, cosT, sinT, Qb, Kb);           // xb now dead
  transpose_v<<<dim3(64, 4, 16), 256, 0, stream>>>(qkv, Vt);

  attn_kernel<<<dim3(4, 64), 512, 0, stream>>>(Qb, Kb, Vt, attn_out);    // qkv now dead

  gemm256j<<<dim3(16, 16), 512, 0, stream>>>(attn_out, woT, out, 4096, 4096, 4096);
}

// Round 12
// 555.279 us; speedup vs baseline: 1.0525x; 1.0525x over previous
//
#include <hip/hip_runtime.h>

typedef __bf16 bf16_t;
typedef __bf16 bf16x8 __attribute__((ext_vector_type(8)));
typedef __bf16 bf16x4 __attribute__((ext_vector_type(4)));
typedef float  f32x4  __attribute__((ext_vector_type(4)));
typedef float  f32x16 __attribute__((ext_vector_type(16)));

#define NB   2
#define NS   2048
#define ND   4096
#define NH   32
#define NKVH 8
#define NHD  128

#define BAR()    asm volatile("s_barrier" ::: "memory")
#define LGKM0()  asm volatile("s_waitcnt lgkmcnt(0)" ::: "memory")
#define VMCNT6() asm volatile("s_waitcnt vmcnt(6)" ::: "memory")
#define VMCNT5() asm volatile("s_waitcnt vmcnt(5)" ::: "memory")
#define VMCNT0() asm volatile("s_waitcnt vmcnt(0)" ::: "memory")

__device__ __forceinline__ void gl_lds16(const bf16_t* g, bf16_t* l) {
  __builtin_amdgcn_global_load_lds(
      (const __attribute__((address_space(1))) void*)g,
      (__attribute__((address_space(3))) void*)l, 16, 0, 0);
}

// ---------------- convert x fp32 -> bf16 ----------------
__global__ void convert_f32_bf16(const float* __restrict__ in, bf16_t* __restrict__ out, int n4) {
  int i = blockIdx.x * 256 + threadIdx.x;
  if (i < n4) {
    f32x4 v = *(const f32x4*)&in[(size_t)i * 4];
    bf16x4 o;
    #pragma unroll
    for (int j = 0; j < 4; ++j) o[j] = (bf16_t)v[j];
    *(bf16x4*)&out[(size_t)i * 4] = o;
  }
}

// ------------- transpose-convert W[4096][Nin] fp32 -> Wt[Nin][4096] bf16 -------------
__global__ void transpose_convert(const float* __restrict__ in, bf16_t* __restrict__ out, int Nin) {
  __shared__ float t[32][33];
  int tx = threadIdx.x & 31, ty = threadIdx.x >> 5;
  int n0 = blockIdx.x * 32, k0 = blockIdx.y * 32;
  #pragma unroll
  for (int i = 0; i < 4; ++i)
    t[ty + i * 8][tx] = in[(size_t)(k0 + ty + i * 8) * Nin + n0 + tx];
  __syncthreads();
  #pragma unroll
  for (int i = 0; i < 4; ++i)
    out[(size_t)(n0 + ty + i * 8) * 4096 + k0 + tx] = (bf16_t)t[tx][ty + i * 8];
}

// ============ 256x192 GEMM for QKV: 2-PHASE schedule (R12) ============
// Grid 16x32 = 512 blocks = 2 full dispatch rounds. bf16 out. 8 waves (2M x 4N),
// BK=64, 16x16x32 MFMA, wave out 128x48 (acc[8][3] = 96 VGPR).
// P0: read a00,a01,b0,b1 (14); stage Ah1(t+1)->nxt; BAR; LGKM0; 24 MFMA (mh0); BAR
// P1: read a10,a11 (8); stage Ah0+B(t+2)->cur; BAR; LGKM0; 24 MFMA (mh1); vmcnt(5); BAR
// RACE AUDIT: Ah0/B(t+2)->cur staged @P1, last cur-reads @P0 (a00,a01,b0,b1), 1 BAR
// between. Ah1(t+1)->nxt staged @P0, last nxt-reads @ tile t-1 P1 (a10,a11), 2 BARs.
// vmcnt FIFO: enter 5 [t+1:Ah0,B]; +2@P0=7; +5@P1=12; vmcnt(5) drains 7 = tile t+1.
__global__ __launch_bounds__(512, 2) void gemm192(const bf16_t* __restrict__ A,
                                                  const bf16_t* __restrict__ Bt,
                                                  bf16_t* __restrict__ C, int M, int N, int K) {
  __shared__ __align__(16) bf16_t As[2][2][128 * 64];
  __shared__ __align__(16) bf16_t Bs[2][192 * 64];
  const int tid = threadIdx.x, lane = tid & 63, wid = tid >> 6;
  const int l15 = lane & 15, l4 = lane >> 4;
  const int wm = wid >> 2, wn = wid & 3;

  const int gx = gridDim.x;
  const int nwg = gx * gridDim.y;
  const int id = blockIdx.y * gx + blockIdx.x;
  const int wg = (id & 7) * (nwg >> 3) + (id >> 3);
  const int bx = wg % gx, by = wg / gx;
  const int row0 = bx * 256, col0 = by * 192;

  const bf16_t* Ab = A + (size_t)row0 * K;
  const bf16_t* Bb = Bt + (size_t)col0 * K;

  auto stA = [&](int t, int h, int buf) {
    #pragma unroll
    for (int i = 0; i < 2; ++i) {
      int phys = i * 8192 + tid * 16;
      int logi = phys ^ (((phys >> 8) & 7) << 4);
      gl_lds16(Ab + (size_t)(h * 128 + (logi >> 7)) * K + t * 64 + ((logi & 127) >> 1),
               &As[buf][h][phys >> 1]);
    }
  };
  auto stB = [&](int t, int buf) {
    #pragma unroll
    for (int i = 0; i < 3; ++i) {
      int phys = i * 8192 + tid * 16;
      int logi = phys ^ (((phys >> 8) & 7) << 4);
      gl_lds16(Bb + (size_t)(logi >> 7) * K + t * 64 + ((logi & 127) >> 1),
               &Bs[buf][phys >> 1]);
    }
  };

  f32x4 acc[8][3];
  #pragma unroll
  for (int m = 0; m < 8; ++m)
    #pragma unroll
    for (int n = 0; n < 3; ++n)
      #pragma unroll
      for (int j = 0; j < 4; ++j) acc[m][n][j] = 0.f;

  const int nt = K >> 6;
  stA(0, 0, 0); stA(0, 1, 0); stB(0, 0);
  stA(1, 0, 1); stB(1, 1);
  VMCNT5();
  BAR();

  auto ardA = [&](int buf, int mh, int kh, int mf) -> bf16x8 {
    int lb = (mh * 64 + mf * 16 + l15) * 128 + kh * 64 + l4 * 16;
    return *(const bf16x8*)&As[buf][wm][(lb ^ (((lb >> 8) & 7) << 4)) >> 1];
  };
  auto brdB = [&](int buf, int kh, int nf) -> bf16x8 {
    int lb = (wn * 48 + nf * 16 + l15) * 128 + kh * 64 + l4 * 16;
    return *(const bf16x8*)&Bs[buf][(lb ^ (((lb >> 8) & 7) << 4)) >> 1];
  };

  #pragma unroll 2
  for (int t = 0; t < nt; ++t) {
    const int cur = t & 1, nxt = cur ^ 1;
    bf16x8 a00[4], a01[4], a10[4], a11[4], b0[3], b1[3];

    // ---- P0: read a00,a01,b0,b1 (14); stage Ah1(t+1)->nxt; MFMA mh0 (24) ----
    #pragma unroll
    for (int mf = 0; mf < 4; ++mf) a00[mf] = ardA(cur, 0, 0, mf);
    #pragma unroll
    for (int nf = 0; nf < 3; ++nf) b0[nf] = brdB(cur, 0, nf);
    #pragma unroll
    for (int mf = 0; mf < 4; ++mf) a01[mf] = ardA(cur, 0, 1, mf);
    #pragma unroll
    for (int nf = 0; nf < 3; ++nf) b1[nf] = brdB(cur, 1, nf);
    if (t + 1 < nt) stA(t + 1, 1, nxt);
    BAR();
    LGKM0();
    __builtin_amdgcn_s_setprio(1);
    #pragma unroll
    for (int mf = 0; mf < 4; ++mf)
      #pragma unroll
      for (int nf = 0; nf < 3; ++nf)
        acc[mf][nf] = __builtin_amdgcn_mfma_f32_16x16x32_bf16(a00[mf], b0[nf], acc[mf][nf], 0, 0, 0);
    #pragma unroll
    for (int mf = 0; mf < 4; ++mf)
      #pragma unroll
      for (int nf = 0; nf < 3; ++nf)
        acc[mf][nf] = __builtin_amdgcn_mfma_f32_16x16x32_bf16(a01[mf], b1[nf], acc[mf][nf], 0, 0, 0);
    __builtin_amdgcn_s_setprio(0);
    BAR();

    // ---- P1: read a10,a11 (8); stage Ah0+B(t+2)->cur; MFMA mh1 (24); vmcnt(5) ----
    #pragma unroll
    for (int mf = 0; mf < 4; ++mf) a10[mf] = ardA(cur, 1, 0, mf);
    #pragma unroll
    for (int mf = 0; mf < 4; ++mf) a11[mf] = ardA(cur, 1, 1, mf);
    if (t + 2 < nt) { stA(t + 2, 0, cur); stB(t + 2, cur); }
    BAR();
    LGKM0();
    __builtin_amdgcn_s_setprio(1);
    #pragma unroll
    for (int mf = 0; mf < 4; ++mf)
      #pragma unroll
      for (int nf = 0; nf < 3; ++nf)
        acc[4 + mf][nf] = __builtin_amdgcn_mfma_f32_16x16x32_bf16(a10[mf], b0[nf], acc[4 + mf][nf], 0, 0, 0);
    #pragma unroll
    for (int mf = 0; mf < 4; ++mf)
      #pragma unroll
      for (int nf = 0; nf < 3; ++nf)
        acc[4 + mf][nf] = __builtin_amdgcn_mfma_f32_16x16x32_bf16(a11[mf], b1[nf], acc[4 + mf][nf], 0, 0, 0);
    __builtin_amdgcn_s_setprio(0);
    if (t + 2 < nt) { VMCNT5(); } else { VMCNT0(); }
    BAR();
  }

  #pragma unroll
  for (int mh = 0; mh < 2; ++mh)
    #pragma unroll
    for (int mf = 0; mf < 4; ++mf)
      #pragma unroll
      for (int nf = 0; nf < 3; ++nf)
        #pragma unroll
        for (int r = 0; r < 4; ++r) {
          size_t row = (size_t)row0 + wm * 128 + mh * 64 + mf * 16 + l4 * 4 + r;
          size_t col = (size_t)col0 + wn * 48 + nf * 16 + l15;
          C[row * N + col] = (bf16_t)acc[mh * 4 + mf][nf][r];
        }
}

// ============ 256x256 GEMM for WO (R11-passing schedule, unchanged) ============
__global__ __launch_bounds__(512, 2) void gemm256j(const bf16_t* __restrict__ A,
                                                   const bf16_t* __restrict__ Bt,
                                                   float* __restrict__ C, int M, int N, int K) {
  __shared__ __align__(16) bf16_t As[2][2][128 * 64];
  __shared__ __align__(16) bf16_t Bs[2][256 * 64];
  const int tid = threadIdx.x, lane = tid & 63, wid = tid >> 6;
  const int l15 = lane & 15, l4 = lane >> 4;
  const int wm = wid >> 2, wn = wid & 3;

  const int gx = gridDim.x;
  const int nwg = gx * gridDim.y;
  const int id = blockIdx.y * gx + blockIdx.x;
  const int wg = (id & 7) * (nwg >> 3) + (id >> 3);
  const int bx = wg % gx, by = wg / gx;
  const int row0 = bx * 256, col0 = by * 256;

  const bf16_t* Ab = A + (size_t)row0 * K;
  const bf16_t* Bb = Bt + (size_t)col0 * K;

  auto stA = [&](int t, int h, int buf) {
    #pragma unroll
    for (int i = 0; i < 2; ++i) {
      int phys = i * 8192 + tid * 16;
      int logi = phys ^ (((phys >> 8) & 7) << 4);
      gl_lds16(Ab + (size_t)(h * 128 + (logi >> 7)) * K + t * 64 + ((logi & 127) >> 1),
               &As[buf][h][phys >> 1]);
    }
  };
  auto stB = [&](int t, int buf) {
    #pragma unroll
    for (int i = 0; i < 4; ++i) {
      int phys = i * 8192 + tid * 16;
      int logi = phys ^ (((phys >> 8) & 7) << 4);
      gl_lds16(Bb + (size_t)(logi >> 7) * K + t * 64 + ((logi & 127) >> 1),
               &Bs[buf][phys >> 1]);
    }
  };

  f32x4 acc[8][4];
  #pragma unroll
  for (int m = 0; m < 8; ++m)
    #pragma unroll
    for (int n = 0; n < 4; ++n)
      #pragma unroll
      for (int j = 0; j < 4; ++j) acc[m][n][j] = 0.f;

  const int nt = K >> 6;
  stA(0, 0, 0); stA(0, 1, 0); stB(0, 0);
  stA(1, 0, 1); stB(1, 1);
  VMCNT6();
  BAR();

  auto ardA = [&](int buf, int mh, int kh, int mf) -> bf16x8 {
    int lb = (mh * 64 + mf * 16 + l15) * 128 + kh * 64 + l4 * 16;
    return *(const bf16x8*)&As[buf][wm][(lb ^ (((lb >> 8) & 7) << 4)) >> 1];
  };
  auto brdB = [&](int buf, int kh, int nf) -> bf16x8 {
    int lb = (wn * 64 + nf * 16 + l15) * 128 + kh * 64 + l4 * 16;
    return *(const bf16x8*)&Bs[buf][(lb ^ (((lb >> 8) & 7) << 4)) >> 1];
  };

  #pragma unroll 2
  for (int t = 0; t < nt; ++t) {
    const int cur = t & 1, nxt = cur ^ 1;
    bf16x8 a00[4], a10[4], a11[4], a01[4], b0[4], b1[4];

    // ---- p0: read a00(4)+b0(4); stage Ah1(t+1)->nxt; MFMA mh0 x kh0 ----
    #pragma unroll
    for (int mf = 0; mf < 4; ++mf) a00[mf] = ardA(cur, 0, 0, mf);
    #pragma unroll
    for (int nf = 0; nf < 4; ++nf) b0[nf] = brdB(cur, 0, nf);
    if (t + 1 < nt) stA(t + 1, 1, nxt);
    BAR();
    LGKM0();
    __builtin_amdgcn_s_setprio(1);
    #pragma unroll
    for (int mf = 0; mf < 4; ++mf)
      #pragma unroll
      for (int nf = 0; nf < 4; ++nf)
        acc[mf][nf] = __builtin_amdgcn_mfma_f32_16x16x32_bf16(a00[mf], b0[nf], acc[mf][nf], 0, 0, 0);
    __builtin_amdgcn_s_setprio(0);
    BAR();

    // ---- p1: read a10(4); MFMA mh1 x kh0 ----
    #pragma unroll
    for (int mf = 0; mf < 4; ++mf) a10[mf] = ardA(cur, 1, 0, mf);
    BAR();
    LGKM0();
    __builtin_amdgcn_s_setprio(1);
    #pragma unroll
    for (int mf = 0; mf < 4; ++mf)
      #pragma unroll
      for (int nf = 0; nf < 4; ++nf)
        acc[4 + mf][nf] = __builtin_amdgcn_mfma_f32_16x16x32_bf16(a10[mf], b0[nf], acc[4 + mf][nf], 0, 0, 0);
    __builtin_amdgcn_s_setprio(0);
    BAR();

    // ---- p2: read a11(4)+b1(4)+a01(4); MFMA mh1 x kh1 ----
    #pragma unroll
    for (int mf = 0; mf < 4; ++mf) a11[mf] = ardA(cur, 1, 1, mf);
    #pragma unroll
    for (int nf = 0; nf < 4; ++nf) b1[nf] = brdB(cur, 1, nf);
    #pragma unroll
    for (int mf = 0; mf < 4; ++mf) a01[mf] = ardA(cur, 0, 1, mf);
    BAR();
    LGKM0();
    __builtin_amdgcn_s_setprio(1);
    #pragma unroll
    for (int mf = 0; mf < 4; ++mf)
      #pragma unroll
      for (int nf = 0; nf < 4; ++nf)
        acc[4 + mf][nf] = __builtin_amdgcn_mfma_f32_16x16x32_bf16(a11[mf], b1[nf], acc[4 + mf][nf], 0, 0, 0);
    __builtin_amdgcn_s_setprio(0);
    BAR();

    // ---- p3: stage Ah0(t+2)+B(t+2)->cur (last reads @p2); MFMA mh0 x kh1 (regs only) ----
    if (t + 2 < nt) { stA(t + 2, 0, cur); stB(t + 2, cur); }
    __builtin_amdgcn_s_setprio(1);
    #pragma unroll
    for (int mf = 0; mf < 4; ++mf)
      #pragma unroll
      for (int nf = 0; nf < 4; ++nf)
        acc[mf][nf] = __builtin_amdgcn_mfma_f32_16x16x32_bf16(a01[mf], b1[nf], acc[mf][nf], 0, 0, 0);
    __builtin_amdgcn_s_setprio(0);
    if (t + 2 < nt) { VMCNT6(); } else { VMCNT0(); }
    BAR();
  }

  #pragma unroll
  for (int mh = 0; mh < 2; ++mh)
    #pragma unroll
    for (int mf = 0; mf < 4; ++mf)
      #pragma unroll
      for (int nf = 0; nf < 4; ++nf)
        #pragma unroll
        for (int r = 0; r < 4; ++r) {
          size_t row = (size_t)row0 + wm * 128 + mh * 64 + mf * 16 + l4 * 4 + r;
          size_t col = (size_t)col0 + wn * 64 + nf * 16 + l15;
          C[row * N + col] = acc[mh * 4 + mf][nf][r];
        }
}

// ---------------- RoPE on Q and K, reshape to [b][h][s][hd] ----------------
__global__ void rope_qk(const bf16_t* __restrict__ qkv, const float* __restrict__ cosT,
                        const float* __restrict__ sinT, bf16_t* __restrict__ Q,
                        bf16_t* __restrict__ Kout) {
  int it = blockIdx.x * 256 + threadIdx.x;
  int chunk = it & 15;
  int hs = (it >> 4) % 40;
  int m = (it >> 4) / 40;
  int b = m >> 11, srow = m & 2047;

  bf16x8 v = *(const bf16x8*)&qkv[(size_t)m * 6144 + hs * 128 + chunk * 8];
  f32x4 c4 = *(const f32x4*)&cosT[(size_t)srow * 64 + chunk * 4];
  f32x4 s4 = *(const f32x4*)&sinT[(size_t)srow * 64 + chunk * 4];
  bf16x8 o;
  #pragma unroll
  for (int j = 0; j < 4; ++j) {
    float t1 = (float)v[2 * j], t2 = (float)v[2 * j + 1];
    o[2 * j]     = (bf16_t)(t1 * c4[j] - t2 * s4[j]);
    o[2 * j + 1] = (bf16_t)(t1 * s4[j] + t2 * c4[j]);
  }
  bf16_t* dst;
  if (hs < 32) dst = Q + (((size_t)(b * 32 + hs)) * 2048 + srow) * 128 + chunk * 8;
  else         dst = Kout + (((size_t)(b * 8 + (hs - 32))) * 2048 + srow) * 128 + chunk * 8;
  *(bf16x8*)dst = o;
}

// ---------------- transpose V section of qkv -> Vt[b*8+kv][128][2048] ----------------
__global__ void transpose_v(const bf16_t* __restrict__ qkv, bf16_t* __restrict__ Vt) {
  __shared__ bf16_t t[32][33];
  int tx = threadIdx.x & 31, ty = threadIdx.x >> 5;
  int s0 = blockIdx.x * 32, d0 = blockIdx.y * 32, g = blockIdx.z;
  int b = g >> 3, kv = g & 7;
  const bf16_t* src = qkv + (size_t)(b * 2048) * 6144 + 5120 + kv * 128;
  #pragma unroll
  for (int i = 0; i < 4; ++i)
    t[ty + i * 8][tx] = src[(size_t)(s0 + ty + i * 8) * 6144 + d0 + tx];
  __syncthreads();
  bf16_t* dst = Vt + (size_t)g * 128 * 2048;
  #pragma unroll
  for (int i = 0; i < 4; ++i)
    dst[(size_t)(d0 + ty + i * 8) * 2048 + s0 + tx] = t[tx][ty + i * 8];
}

// ---------------- causal flash attention, 8-wave swapped-QK in-register softmax ----------------
__global__ __launch_bounds__(512, 2) void attn_kernel(const bf16_t* __restrict__ Q,
                                                      const bf16_t* __restrict__ Kc,
                                                      const bf16_t* __restrict__ Vt,
                                                      bf16_t* __restrict__ Oout) {
  __shared__ __align__(16) bf16_t Ks[2][64 * 128];
  __shared__ __align__(16) bf16_t Vs[2][128 * 64];

  const int tid = threadIdx.x, wid = tid >> 6, lane = tid & 63;
  const int l31 = lane & 31, hi = lane >> 5;
  const int bh = blockIdx.y;
  const int b = bh >> 5, h = bh & 31, kv = h >> 2;
  const int pr = blockIdx.x;

  const bf16_t* Qp = Q + ((size_t)bh * 2048) * 128;
  const bf16_t* Kp = Kc + ((size_t)(b * 8 + kv) * 2048) * 128;
  const bf16_t* Vp = Vt + ((size_t)(b * 8 + kv) * 128) * 2048;

  const float kscale = 0.08838834764831845f * 1.44269504088896f;
  const int qoff = (wid < 4) ? wid * 32 : 224 - (wid - 4) * 32;

  auto stage = [&](int kt, int buf) {
    const int k0 = kt * 64;
    #pragma unroll
    for (int i = 0; i < 2; ++i) {
      int phys = i * 8192 + tid * 16;
      int logi = phys ^ (((phys >> 8) & 15) << 4);
      gl_lds16(Kp + (size_t)(k0 + (phys >> 8)) * 128 + ((logi & 255) >> 1), &Ks[buf][phys >> 1]);
    }
    #pragma unroll
    for (int i = 0; i < 2; ++i) {
      int phys = i * 8192 + tid * 16;
      int logi = phys ^ (((phys >> 7) & 7) << 4);
      gl_lds16(Vp + (size_t)(phys >> 7) * 2048 + k0 + ((logi & 127) >> 1), &Vs[buf][phys >> 1]);
    }
  };

  for (int half = 0; half < 2; ++half) {
    const int qt = half ? pr : 7 - pr;
    const int q0b = qt * 256;
    const int q0w = q0b + qoff;
    const int qg = q0w + l31;
    const int nkt = (qt + 1) * 4;

    bf16x8 qf[8];
    #pragma unroll
    for (int c = 0; c < 8; ++c) {
      bf16x8 t = *(const bf16x8*)&Qp[(size_t)qg * 128 + c * 16 + hi * 8];
      #pragma unroll
      for (int j = 0; j < 8; ++j) t[j] = (bf16_t)((float)t[j] * kscale);
      qf[c] = t;
    }

    f32x16 oa[4];
    #pragma unroll
    for (int nc = 0; nc < 4; ++nc)
      #pragma unroll
      for (int r = 0; r < 16; ++r) oa[nc][r] = 0.f;
    float m_old = -1e30f, lrow = 0.f;

    stage(0, 0);
    __syncthreads();

    for (int kt = 0; kt < nkt; ++kt) {
      const int k0 = kt * 64, cur = kt & 1;
      if (kt + 1 < nkt) stage(kt + 1, cur ^ 1);

      if (k0 <= q0w + 31) {
        f32x16 s0, s1;
        #pragma unroll
        for (int r = 0; r < 16; ++r) { s0[r] = 0.f; s1[r] = 0.f; }
        __builtin_amdgcn_s_setprio(1);
        #pragma unroll
        for (int c = 0; c < 8; ++c) {
          int lb0 = l31 * 256 + c * 32 + hi * 16;
          int pb0 = lb0 ^ (((lb0 >> 8) & 15) << 4);
          bf16x8 kf0 = *(const bf16x8*)&Ks[cur][pb0 >> 1];
          s0 = __builtin_amdgcn_mfma_f32_32x32x16_bf16(kf0, qf[c], s0, 0, 0, 0);
          int lb1 = (32 + l31) * 256 + c * 32 + hi * 16;
          int pb1 = lb1 ^ (((lb1 >> 8) & 15) << 4);
          bf16x8 kf1 = *(const bf16x8*)&Ks[cur][pb1 >> 1];
          s1 = __builtin_amdgcn_mfma_f32_32x32x16_bf16(kf1, qf[c], s1, 0, 0, 0);
        }
        __builtin_amdgcn_s_setprio(0);

        if (k0 + 63 > q0w) {
          #pragma unroll
          for (int r = 0; r < 16; ++r) {
            int key0 = k0 + ((r & 3) + 8 * (r >> 2)) + 4 * hi;
            if (key0 > qg) s0[r] = -1e30f;
            if (key0 + 32 > qg) s1[r] = -1e30f;
          }
        }

        float m8[8];
        #pragma unroll
        for (int j = 0; j < 8; ++j)
          m8[j] = fmaxf(fmaxf(s0[j], s0[j + 8]), fmaxf(s1[j], s1[j + 8]));
        float ma = fmaxf(fmaxf(m8[0], m8[4]), fmaxf(m8[1], m8[5]));
        float mb = fmaxf(fmaxf(m8[2], m8[6]), fmaxf(m8[3], m8[7]));
        float mh = fmaxf(ma, mb);
        float mfull = fmaxf(mh, __shfl_xor(mh, 32));
        float mn = fmaxf(m_old, mfull);
        bool nores = (mfull <= m_old);
        float sc = exp2f(m_old - mn);
        m_old = mn;

        if (!__all((int)nores)) {
          #pragma unroll
          for (int r = 0; r < 16; ++r) {
            int qi = (r & 3) + 8 * (r >> 2) + 4 * hi;
            float scv = __int_as_float(__builtin_amdgcn_ds_bpermute(qi << 2, __float_as_int(sc)));
            oa[0][r] *= scv; oa[1][r] *= scv; oa[2][r] *= scv; oa[3][r] *= scv;
          }
        }

        #pragma unroll
        for (int r = 0; r < 16; ++r) {
          s0[r] = exp2f(s0[r] - mn);
          s1[r] = exp2f(s1[r] - mn);
        }
        float rsA = 0.f, rsB = 0.f, rsC = 0.f, rsD = 0.f;
        #pragma unroll
        for (int r = 0; r < 16; r += 4) {
          rsA += s0[r];     rsB += s0[r + 1]; rsC += s0[r + 2]; rsD += s0[r + 3];
          rsA += s1[r];     rsB += s1[r + 1]; rsC += s1[r + 2]; rsD += s1[r + 3];
        }
        float rs = (rsA + rsB) + (rsC + rsD);
        rs += __shfl_xor(rs, 32);
        lrow = lrow * sc + rs;

        #pragma unroll
        for (int ks = 0; ks < 4; ++ks) {
          const int qi0 = (ks & 1) * 8;
          union { bf16_t hh[4]; int ii[2]; } ku, su;
          #pragma unroll
          for (int j = 0; j < 4; ++j) {
            float lo, hv;
            if (ks >> 1) { lo = s1[qi0 + j]; hv = s1[qi0 + 4 + j]; }
            else         { lo = s0[qi0 + j]; hv = s0[qi0 + 4 + j]; }
            ku.hh[j] = (bf16_t)(hi ? hv : lo);
            su.hh[j] = (bf16_t)(hi ? lo : hv);
          }
          int r0 = __shfl_xor(su.ii[0], 32), r1 = __shfl_xor(su.ii[1], 32);
          union { int ii[4]; bf16x8 v; } fa;
          fa.ii[0] = hi ? r0 : ku.ii[0];
          fa.ii[1] = hi ? r1 : ku.ii[1];
          fa.ii[2] = hi ? ku.ii[0] : r0;
          fa.ii[3] = hi ? ku.ii[1] : r1;
          __builtin_amdgcn_s_setprio(1);
          #pragma unroll
          for (int nc = 0; nc < 4; ++nc) {
            int lb = (nc * 32 + l31) * 128 + ks * 32 + hi * 16;
            int pb = lb ^ (((lb >> 7) & 7) << 4);
            bf16x8 vf = *(const bf16x8*)&Vs[cur][pb >> 1];
            oa[nc] = __builtin_amdgcn_mfma_f32_32x32x16_bf16(fa.v, vf, oa[nc], 0, 0, 0);
          }
          __builtin_amdgcn_s_setprio(0);
        }
      }
      __syncthreads();
    }

    float inv = 1.0f / lrow;
    bf16_t* Op = Oout + ((size_t)(b * 2048 + q0w)) * 4096 + (size_t)h * 128;
    #pragma unroll
    for (int r = 0; r < 16; ++r) {
      int qi = (r & 3) + 8 * (r >> 2) + 4 * hi;
      float iv = __int_as_float(__builtin_amdgcn_ds_bpermute(qi << 2, __float_as_int(inv)));
      #pragma unroll
      for (int nc = 0; nc < 4; ++nc)
        Op[(size_t)qi * 4096 + nc * 32 + l31] = (bf16_t)(oa[nc][r] * iv);
    }
  }
}

extern "C" void kernel_launch(void* const* d_in, const int* in_sizes, int n_in,
                              void* d_out, int out_size, void* d_ws, size_t ws_size,
                              hipStream_t stream) {
  const float* x    = (const float*)d_in[0];
  const float* cosT = (const float*)d_in[1];
  const float* sinT = (const float*)d_in[2];
  const float* wq   = (const float*)d_in[3];
  const float* wk   = (const float*)d_in[4];
  const float* wv   = (const float*)d_in[5];
  const float* wo   = (const float*)d_in[6];
  float* out = (float*)d_out;
  char* ws = (char*)d_ws;

  bf16_t* wqkvT = (bf16_t*)(ws + 0);           // 6144*4096*2
  bf16_t* woT   = wqkvT;                       // reused after QKV GEMM
  bf16_t* xb    = (bf16_t*)(ws + 50331648);    // 4096*4096*2
  bf16_t* Qb    = xb;                          // reused after QKV GEMM
  bf16_t* qkv   = (bf16_t*)(ws + 83886080);    // 4096*6144*2
  bf16_t* attn_out = qkv;                      // reused after rope/transpose_v
  bf16_t* Kb    = (bf16_t*)(ws + 134217728);
  bf16_t* Vt    = (bf16_t*)(ws + 142606336);

  convert_f32_bf16<<<16384, 256, 0, stream>>>(x, xb, 4194304);
  transpose_convert<<<dim3(128, 128), 256, 0, stream>>>(wq, wqkvT, 4096);
  transpose_convert<<<dim3(32, 128), 256, 0, stream>>>(wk, wqkvT + (size_t)4096 * 4096, 1024);
  transpose_convert<<<dim3(32, 128), 256, 0, stream>>>(wv, wqkvT + (size_t)5120 * 4096, 1024);

  gemm192<<<dim3(16, 32), 512, 0, stream>>>(xb, wqkvT, qkv, 4096, 6144, 4096);

  transpose_convert<<<dim3(128, 128), 256, 0, stream>>>(wo, woT, 4096);  // wqkvT now dead
  rope_qk<<<10240, 256, 0, stream>>>(qkv, cosT, sinT, Qb, Kb);           // xb now dead
  transpose_v<<<dim3(64, 4, 16), 256, 0, stream>>>(qkv, Vt);

  attn_kernel<<<dim3(4, 64), 512, 0, stream>>>(Qb, Kb, Vt, attn_out);    // qkv now dead

  gemm256j<<<dim3(16, 16), 512, 0, stream>>>(attn_out, woT, out, 4096, 4096, 4096);
}

// Round 13
// 545.082 us; speedup vs baseline: 1.0722x; 1.0187x over previous
//
#include <hip/hip_runtime.h>

typedef __bf16 bf16_t;
typedef __bf16 bf16x8 __attribute__((ext_vector_type(8)));
typedef __bf16 bf16x4 __attribute__((ext_vector_type(4)));
typedef float  f32x4  __attribute__((ext_vector_type(4)));
typedef float  f32x16 __attribute__((ext_vector_type(16)));

#define NB   2
#define NS   2048
#define ND   4096
#define NH   32
#define NKVH 8
#define NHD  128

#define BAR()    asm volatile("s_barrier" ::: "memory")
#define LGKM0()  asm volatile("s_waitcnt lgkmcnt(0)" ::: "memory")
#define VMCNT6() asm volatile("s_waitcnt vmcnt(6)" ::: "memory")
#define VMCNT5() asm volatile("s_waitcnt vmcnt(5)" ::: "memory")
#define VMCNT0() asm volatile("s_waitcnt vmcnt(0)" ::: "memory")

__device__ __forceinline__ void gl_lds16(const bf16_t* g, bf16_t* l) {
  __builtin_amdgcn_global_load_lds(
      (const __attribute__((address_space(1))) void*)g,
      (__attribute__((address_space(3))) void*)l, 16, 0, 0);
}

// ---------------- convert x fp32 -> bf16 ----------------
__global__ void convert_f32_bf16(const float* __restrict__ in, bf16_t* __restrict__ out, int n4) {
  int i = blockIdx.x * 256 + threadIdx.x;
  if (i < n4) {
    f32x4 v = *(const f32x4*)&in[(size_t)i * 4];
    bf16x4 o;
    #pragma unroll
    for (int j = 0; j < 4; ++j) o[j] = (bf16_t)v[j];
    *(bf16x4*)&out[(size_t)i * 4] = o;
  }
}

// ------------- transpose-convert W[4096][Nin] fp32 -> Wt[Nin][4096] bf16 -------------
__global__ void transpose_convert(const float* __restrict__ in, bf16_t* __restrict__ out, int Nin) {
  __shared__ float t[32][33];
  int tx = threadIdx.x & 31, ty = threadIdx.x >> 5;
  int n0 = blockIdx.x * 32, k0 = blockIdx.y * 32;
  #pragma unroll
  for (int i = 0; i < 4; ++i)
    t[ty + i * 8][tx] = in[(size_t)(k0 + ty + i * 8) * Nin + n0 + tx];
  __syncthreads();
  #pragma unroll
  for (int i = 0; i < 4; ++i)
    out[(size_t)(n0 + ty + i * 8) * 4096 + k0 + tx] = (bf16_t)t[tx][ty + i * 8];
}

// ============ 256x192 GEMM for QKV: 2-PHASE schedule (R12-proven) ============
// Grid 16x32 = 512 blocks = 2 full dispatch rounds. bf16 out. 8 waves (2M x 4N),
// BK=64, 16x16x32 MFMA, wave out 128x48 (acc[8][3] = 96 VGPR).
// P0: read a00,a01,b0,b1 (14); stage Ah1(t+1)->nxt; BAR; LGKM0; 24 MFMA (mh0); BAR
// P1: read a10,a11 (8); stage Ah0+B(t+2)->cur; BAR; LGKM0; 24 MFMA (mh1); vmcnt(5); BAR
// vmcnt FIFO: enter 5 [t+1:Ah0,B]; +2@P0=7; +5@P1=12; vmcnt(5) drains 7 = tile t+1.
__global__ __launch_bounds__(512, 2) void gemm192(const bf16_t* __restrict__ A,
                                                  const bf16_t* __restrict__ Bt,
                                                  bf16_t* __restrict__ C, int M, int N, int K) {
  __shared__ __align__(16) bf16_t As[2][2][128 * 64];
  __shared__ __align__(16) bf16_t Bs[2][192 * 64];
  const int tid = threadIdx.x, lane = tid & 63, wid = tid >> 6;
  const int l15 = lane & 15, l4 = lane >> 4;
  const int wm = wid >> 2, wn = wid & 3;

  const int gx = gridDim.x;
  const int nwg = gx * gridDim.y;
  const int id = blockIdx.y * gx + blockIdx.x;
  const int wg = (id & 7) * (nwg >> 3) + (id >> 3);
  const int bx = wg % gx, by = wg / gx;
  const int row0 = bx * 256, col0 = by * 192;

  const bf16_t* Ab = A + (size_t)row0 * K;
  const bf16_t* Bb = Bt + (size_t)col0 * K;

  auto stA = [&](int t, int h, int buf) {
    #pragma unroll
    for (int i = 0; i < 2; ++i) {
      int phys = i * 8192 + tid * 16;
      int logi = phys ^ (((phys >> 8) & 7) << 4);
      gl_lds16(Ab + (size_t)(h * 128 + (logi >> 7)) * K + t * 64 + ((logi & 127) >> 1),
               &As[buf][h][phys >> 1]);
    }
  };
  auto stB = [&](int t, int buf) {
    #pragma unroll
    for (int i = 0; i < 3; ++i) {
      int phys = i * 8192 + tid * 16;
      int logi = phys ^ (((phys >> 8) & 7) << 4);
      gl_lds16(Bb + (size_t)(logi >> 7) * K + t * 64 + ((logi & 127) >> 1),
               &Bs[buf][phys >> 1]);
    }
  };

  f32x4 acc[8][3];
  #pragma unroll
  for (int m = 0; m < 8; ++m)
    #pragma unroll
    for (int n = 0; n < 3; ++n)
      #pragma unroll
      for (int j = 0; j < 4; ++j) acc[m][n][j] = 0.f;

  const int nt = K >> 6;
  stA(0, 0, 0); stA(0, 1, 0); stB(0, 0);
  stA(1, 0, 1); stB(1, 1);
  VMCNT5();
  BAR();

  auto ardA = [&](int buf, int mh, int kh, int mf) -> bf16x8 {
    int lb = (mh * 64 + mf * 16 + l15) * 128 + kh * 64 + l4 * 16;
    return *(const bf16x8*)&As[buf][wm][(lb ^ (((lb >> 8) & 7) << 4)) >> 1];
  };
  auto brdB = [&](int buf, int kh, int nf) -> bf16x8 {
    int lb = (wn * 48 + nf * 16 + l15) * 128 + kh * 64 + l4 * 16;
    return *(const bf16x8*)&Bs[buf][(lb ^ (((lb >> 8) & 7) << 4)) >> 1];
  };

  #pragma unroll 2
  for (int t = 0; t < nt; ++t) {
    const int cur = t & 1, nxt = cur ^ 1;
    bf16x8 a00[4], a01[4], a10[4], a11[4], b0[3], b1[3];

    // ---- P0: read a00,a01,b0,b1 (14); stage Ah1(t+1)->nxt; MFMA mh0 (24) ----
    #pragma unroll
    for (int mf = 0; mf < 4; ++mf) a00[mf] = ardA(cur, 0, 0, mf);
    #pragma unroll
    for (int nf = 0; nf < 3; ++nf) b0[nf] = brdB(cur, 0, nf);
    #pragma unroll
    for (int mf = 0; mf < 4; ++mf) a01[mf] = ardA(cur, 0, 1, mf);
    #pragma unroll
    for (int nf = 0; nf < 3; ++nf) b1[nf] = brdB(cur, 1, nf);
    if (t + 1 < nt) stA(t + 1, 1, nxt);
    BAR();
    LGKM0();
    __builtin_amdgcn_s_setprio(1);
    #pragma unroll
    for (int mf = 0; mf < 4; ++mf)
      #pragma unroll
      for (int nf = 0; nf < 3; ++nf)
        acc[mf][nf] = __builtin_amdgcn_mfma_f32_16x16x32_bf16(a00[mf], b0[nf], acc[mf][nf], 0, 0, 0);
    #pragma unroll
    for (int mf = 0; mf < 4; ++mf)
      #pragma unroll
      for (int nf = 0; nf < 3; ++nf)
        acc[mf][nf] = __builtin_amdgcn_mfma_f32_16x16x32_bf16(a01[mf], b1[nf], acc[mf][nf], 0, 0, 0);
    __builtin_amdgcn_s_setprio(0);
    BAR();

    // ---- P1: read a10,a11 (8); stage Ah0+B(t+2)->cur; MFMA mh1 (24); vmcnt(5) ----
    #pragma unroll
    for (int mf = 0; mf < 4; ++mf) a10[mf] = ardA(cur, 1, 0, mf);
    #pragma unroll
    for (int mf = 0; mf < 4; ++mf) a11[mf] = ardA(cur, 1, 1, mf);
    if (t + 2 < nt) { stA(t + 2, 0, cur); stB(t + 2, cur); }
    BAR();
    LGKM0();
    __builtin_amdgcn_s_setprio(1);
    #pragma unroll
    for (int mf = 0; mf < 4; ++mf)
      #pragma unroll
      for (int nf = 0; nf < 3; ++nf)
        acc[4 + mf][nf] = __builtin_amdgcn_mfma_f32_16x16x32_bf16(a10[mf], b0[nf], acc[4 + mf][nf], 0, 0, 0);
    #pragma unroll
    for (int mf = 0; mf < 4; ++mf)
      #pragma unroll
      for (int nf = 0; nf < 3; ++nf)
        acc[4 + mf][nf] = __builtin_amdgcn_mfma_f32_16x16x32_bf16(a11[mf], b1[nf], acc[4 + mf][nf], 0, 0, 0);
    __builtin_amdgcn_s_setprio(0);
    if (t + 2 < nt) { VMCNT5(); } else { VMCNT0(); }
    BAR();
  }

  #pragma unroll
  for (int mh = 0; mh < 2; ++mh)
    #pragma unroll
    for (int mf = 0; mf < 4; ++mf)
      #pragma unroll
      for (int nf = 0; nf < 3; ++nf)
        #pragma unroll
        for (int r = 0; r < 4; ++r) {
          size_t row = (size_t)row0 + wm * 128 + mh * 64 + mf * 16 + l4 * 4 + r;
          size_t col = (size_t)col0 + wn * 48 + nf * 16 + l15;
          C[row * N + col] = (bf16_t)acc[mh * 4 + mf][nf][r];
        }
}

// ============ 256x256 GEMM for WO: 2-PHASE schedule (R13) ============
// Grid 16x16 = 256 blocks = 1 dispatch round. f32 out. wave out 128x64 (acc[8][4]).
// P0: read a00,a01,b0,b1 (16); stage Ah1(t+1)->nxt; BAR; LGKM0; 32 MFMA (mh0); BAR
// P1: read a10,a11 (8); stage Ah0+B(t+2)->cur; BAR; LGKM0; 32 MFMA (mh1); vmcnt(6); BAR
// RACE AUDIT (= gemm192 pattern): Ah0/B(t+2)->cur staged @P1; B last read @P0 (1 BAR);
// Ah1(t+1)->nxt staged @P0, last nxt-reads @ tile t-1 P1 (2 BARs). vmcnt FIFO:
// enter 6 [t+1:Ah0,B]; +2@P0=8; +6@P1=14; vmcnt(6) drains 8 = tile t+1 complete.
__global__ __launch_bounds__(512, 2) void gemm256j(const bf16_t* __restrict__ A,
                                                   const bf16_t* __restrict__ Bt,
                                                   float* __restrict__ C, int M, int N, int K) {
  __shared__ __align__(16) bf16_t As[2][2][128 * 64];
  __shared__ __align__(16) bf16_t Bs[2][256 * 64];
  const int tid = threadIdx.x, lane = tid & 63, wid = tid >> 6;
  const int l15 = lane & 15, l4 = lane >> 4;
  const int wm = wid >> 2, wn = wid & 3;

  const int gx = gridDim.x;
  const int nwg = gx * gridDim.y;
  const int id = blockIdx.y * gx + blockIdx.x;
  const int wg = (id & 7) * (nwg >> 3) + (id >> 3);
  const int bx = wg % gx, by = wg / gx;
  const int row0 = bx * 256, col0 = by * 256;

  const bf16_t* Ab = A + (size_t)row0 * K;
  const bf16_t* Bb = Bt + (size_t)col0 * K;

  auto stA = [&](int t, int h, int buf) {
    #pragma unroll
    for (int i = 0; i < 2; ++i) {
      int phys = i * 8192 + tid * 16;
      int logi = phys ^ (((phys >> 8) & 7) << 4);
      gl_lds16(Ab + (size_t)(h * 128 + (logi >> 7)) * K + t * 64 + ((logi & 127) >> 1),
               &As[buf][h][phys >> 1]);
    }
  };
  auto stB = [&](int t, int buf) {
    #pragma unroll
    for (int i = 0; i < 4; ++i) {
      int phys = i * 8192 + tid * 16;
      int logi = phys ^ (((phys >> 8) & 7) << 4);
      gl_lds16(Bb + (size_t)(logi >> 7) * K + t * 64 + ((logi & 127) >> 1),
               &Bs[buf][phys >> 1]);
    }
  };

  f32x4 acc[8][4];
  #pragma unroll
  for (int m = 0; m < 8; ++m)
    #pragma unroll
    for (int n = 0; n < 4; ++n)
      #pragma unroll
      for (int j = 0; j < 4; ++j) acc[m][n][j] = 0.f;

  const int nt = K >> 6;
  stA(0, 0, 0); stA(0, 1, 0); stB(0, 0);
  stA(1, 0, 1); stB(1, 1);
  VMCNT6();
  BAR();

  auto ardA = [&](int buf, int mh, int kh, int mf) -> bf16x8 {
    int lb = (mh * 64 + mf * 16 + l15) * 128 + kh * 64 + l4 * 16;
    return *(const bf16x8*)&As[buf][wm][(lb ^ (((lb >> 8) & 7) << 4)) >> 1];
  };
  auto brdB = [&](int buf, int kh, int nf) -> bf16x8 {
    int lb = (wn * 64 + nf * 16 + l15) * 128 + kh * 64 + l4 * 16;
    return *(const bf16x8*)&Bs[buf][(lb ^ (((lb >> 8) & 7) << 4)) >> 1];
  };

  #pragma unroll 2
  for (int t = 0; t < nt; ++t) {
    const int cur = t & 1, nxt = cur ^ 1;
    bf16x8 a00[4], a01[4], a10[4], a11[4], b0[4], b1[4];

    // ---- P0: read a00,b0,a01,b1 (16); stage Ah1(t+1)->nxt; MFMA mh0 (32) ----
    #pragma unroll
    for (int mf = 0; mf < 4; ++mf) a00[mf] = ardA(cur, 0, 0, mf);
    #pragma unroll
    for (int nf = 0; nf < 4; ++nf) b0[nf] = brdB(cur, 0, nf);
    #pragma unroll
    for (int mf = 0; mf < 4; ++mf) a01[mf] = ardA(cur, 0, 1, mf);
    #pragma unroll
    for (int nf = 0; nf < 4; ++nf) b1[nf] = brdB(cur, 1, nf);
    if (t + 1 < nt) stA(t + 1, 1, nxt);
    BAR();
    LGKM0();
    __builtin_amdgcn_s_setprio(1);
    #pragma unroll
    for (int mf = 0; mf < 4; ++mf)
      #pragma unroll
      for (int nf = 0; nf < 4; ++nf)
        acc[mf][nf] = __builtin_amdgcn_mfma_f32_16x16x32_bf16(a00[mf], b0[nf], acc[mf][nf], 0, 0, 0);
    #pragma unroll
    for (int mf = 0; mf < 4; ++mf)
      #pragma unroll
      for (int nf = 0; nf < 4; ++nf)
        acc[mf][nf] = __builtin_amdgcn_mfma_f32_16x16x32_bf16(a01[mf], b1[nf], acc[mf][nf], 0, 0, 0);
    __builtin_amdgcn_s_setprio(0);
    BAR();

    // ---- P1: read a10,a11 (8); stage Ah0+B(t+2)->cur; MFMA mh1 (32); vmcnt(6) ----
    #pragma unroll
    for (int mf = 0; mf < 4; ++mf) a10[mf] = ardA(cur, 1, 0, mf);
    #pragma unroll
    for (int mf = 0; mf < 4; ++mf) a11[mf] = ardA(cur, 1, 1, mf);
    if (t + 2 < nt) { stA(t + 2, 0, cur); stB(t + 2, cur); }
    BAR();
    LGKM0();
    __builtin_amdgcn_s_setprio(1);
    #pragma unroll
    for (int mf = 0; mf < 4; ++mf)
      #pragma unroll
      for (int nf = 0; nf < 4; ++nf)
        acc[4 + mf][nf] = __builtin_amdgcn_mfma_f32_16x16x32_bf16(a10[mf], b0[nf], acc[4 + mf][nf], 0, 0, 0);
    #pragma unroll
    for (int mf = 0; mf < 4; ++mf)
      #pragma unroll
      for (int nf = 0; nf < 4; ++nf)
        acc[4 + mf][nf] = __builtin_amdgcn_mfma_f32_16x16x32_bf16(a11[mf], b1[nf], acc[4 + mf][nf], 0, 0, 0);
    __builtin_amdgcn_s_setprio(0);
    if (t + 2 < nt) { VMCNT6(); } else { VMCNT0(); }
    BAR();
  }

  #pragma unroll
  for (int mh = 0; mh < 2; ++mh)
    #pragma unroll
    for (int mf = 0; mf < 4; ++mf)
      #pragma unroll
      for (int nf = 0; nf < 4; ++nf)
        #pragma unroll
        for (int r = 0; r < 4; ++r) {
          size_t row = (size_t)row0 + wm * 128 + mh * 64 + mf * 16 + l4 * 4 + r;
          size_t col = (size_t)col0 + wn * 64 + nf * 16 + l15;
          C[row * N + col] = acc[mh * 4 + mf][nf][r];
        }
}

// ---------------- RoPE on Q and K, reshape to [b][h][s][hd] ----------------
__global__ void rope_qk(const bf16_t* __restrict__ qkv, const float* __restrict__ cosT,
                        const float* __restrict__ sinT, bf16_t* __restrict__ Q,
                        bf16_t* __restrict__ Kout) {
  int it = blockIdx.x * 256 + threadIdx.x;
  int chunk = it & 15;
  int hs = (it >> 4) % 40;
  int m = (it >> 4) / 40;
  int b = m >> 11, srow = m & 2047;

  bf16x8 v = *(const bf16x8*)&qkv[(size_t)m * 6144 + hs * 128 + chunk * 8];
  f32x4 c4 = *(const f32x4*)&cosT[(size_t)srow * 64 + chunk * 4];
  f32x4 s4 = *(const f32x4*)&sinT[(size_t)srow * 64 + chunk * 4];
  bf16x8 o;
  #pragma unroll
  for (int j = 0; j < 4; ++j) {
    float t1 = (float)v[2 * j], t2 = (float)v[2 * j + 1];
    o[2 * j]     = (bf16_t)(t1 * c4[j] - t2 * s4[j]);
    o[2 * j + 1] = (bf16_t)(t1 * s4[j] + t2 * c4[j]);
  }
  bf16_t* dst;
  if (hs < 32) dst = Q + (((size_t)(b * 32 + hs)) * 2048 + srow) * 128 + chunk * 8;
  else         dst = Kout + (((size_t)(b * 8 + (hs - 32))) * 2048 + srow) * 128 + chunk * 8;
  *(bf16x8*)dst = o;
}

// ---------------- transpose V section of qkv -> Vt[b*8+kv][128][2048] ----------------
__global__ void transpose_v(const bf16_t* __restrict__ qkv, bf16_t* __restrict__ Vt) {
  __shared__ bf16_t t[32][33];
  int tx = threadIdx.x & 31, ty = threadIdx.x >> 5;
  int s0 = blockIdx.x * 32, d0 = blockIdx.y * 32, g = blockIdx.z;
  int b = g >> 3, kv = g & 7;
  const bf16_t* src = qkv + (size_t)(b * 2048) * 6144 + 5120 + kv * 128;
  #pragma unroll
  for (int i = 0; i < 4; ++i)
    t[ty + i * 8][tx] = src[(size_t)(s0 + ty + i * 8) * 6144 + d0 + tx];
  __syncthreads();
  bf16_t* dst = Vt + (size_t)g * 128 * 2048;
  #pragma unroll
  for (int i = 0; i < 4; ++i)
    dst[(size_t)(d0 + ty + i * 8) * 2048 + s0 + tx] = t[tx][ty + i * 8];
}

// ---------------- causal flash attention, 8-wave swapped-QK in-register softmax ----------------
__global__ __launch_bounds__(512, 2) void attn_kernel(const bf16_t* __restrict__ Q,
                                                      const bf16_t* __restrict__ Kc,
                                                      const bf16_t* __restrict__ Vt,
                                                      bf16_t* __restrict__ Oout) {
  __shared__ __align__(16) bf16_t Ks[2][64 * 128];
  __shared__ __align__(16) bf16_t Vs[2][128 * 64];

  const int tid = threadIdx.x, wid = tid >> 6, lane = tid & 63;
  const int l31 = lane & 31, hi = lane >> 5;
  const int bh = blockIdx.y;
  const int b = bh >> 5, h = bh & 31, kv = h >> 2;
  const int pr = blockIdx.x;

  const bf16_t* Qp = Q + ((size_t)bh * 2048) * 128;
  const bf16_t* Kp = Kc + ((size_t)(b * 8 + kv) * 2048) * 128;
  const bf16_t* Vp = Vt + ((size_t)(b * 8 + kv) * 128) * 2048;

  const float kscale = 0.08838834764831845f * 1.44269504088896f;
  const int qoff = (wid < 4) ? wid * 32 : 224 - (wid - 4) * 32;

  auto stage = [&](int kt, int buf) {
    const int k0 = kt * 64;
    #pragma unroll
    for (int i = 0; i < 2; ++i) {
      int phys = i * 8192 + tid * 16;
      int logi = phys ^ (((phys >> 8) & 15) << 4);
      gl_lds16(Kp + (size_t)(k0 + (phys >> 8)) * 128 + ((logi & 255) >> 1), &Ks[buf][phys >> 1]);
    }
    #pragma unroll
    for (int i = 0; i < 2; ++i) {
      int phys = i * 8192 + tid * 16;
      int logi = phys ^ (((phys >> 7) & 7) << 4);
      gl_lds16(Vp + (size_t)(phys >> 7) * 2048 + k0 + ((logi & 127) >> 1), &Vs[buf][phys >> 1]);
    }
  };

  for (int half = 0; half < 2; ++half) {
    const int qt = half ? pr : 7 - pr;
    const int q0b = qt * 256;
    const int q0w = q0b + qoff;
    const int qg = q0w + l31;
    const int nkt = (qt + 1) * 4;

    bf16x8 qf[8];
    #pragma unroll
    for (int c = 0; c < 8; ++c) {
      bf16x8 t = *(const bf16x8*)&Qp[(size_t)qg * 128 + c * 16 + hi * 8];
      #pragma unroll
      for (int j = 0; j < 8; ++j) t[j] = (bf16_t)((float)t[j] * kscale);
      qf[c] = t;
    }

    f32x16 oa[4];
    #pragma unroll
    for (int nc = 0; nc < 4; ++nc)
      #pragma unroll
      for (int r = 0; r < 16; ++r) oa[nc][r] = 0.f;
    float m_old = -1e30f, lrow = 0.f;

    stage(0, 0);
    __syncthreads();

    for (int kt = 0; kt < nkt; ++kt) {
      const int k0 = kt * 64, cur = kt & 1;
      if (kt + 1 < nkt) stage(kt + 1, cur ^ 1);

      if (k0 <= q0w + 31) {
        f32x16 s0, s1;
        #pragma unroll
        for (int r = 0; r < 16; ++r) { s0[r] = 0.f; s1[r] = 0.f; }
        __builtin_amdgcn_s_setprio(1);
        #pragma unroll
        for (int c = 0; c < 8; ++c) {
          int lb0 = l31 * 256 + c * 32 + hi * 16;
          int pb0 = lb0 ^ (((lb0 >> 8) & 15) << 4);
          bf16x8 kf0 = *(const bf16x8*)&Ks[cur][pb0 >> 1];
          s0 = __builtin_amdgcn_mfma_f32_32x32x16_bf16(kf0, qf[c], s0, 0, 0, 0);
          int lb1 = (32 + l31) * 256 + c * 32 + hi * 16;
          int pb1 = lb1 ^ (((lb1 >> 8) & 15) << 4);
          bf16x8 kf1 = *(const bf16x8*)&Ks[cur][pb1 >> 1];
          s1 = __builtin_amdgcn_mfma_f32_32x32x16_bf16(kf1, qf[c], s1, 0, 0, 0);
        }
        __builtin_amdgcn_s_setprio(0);

        if (k0 + 63 > q0w) {
          #pragma unroll
          for (int r = 0; r < 16; ++r) {
            int key0 = k0 + ((r & 3) + 8 * (r >> 2)) + 4 * hi;
            if (key0 > qg) s0[r] = -1e30f;
            if (key0 + 32 > qg) s1[r] = -1e30f;
          }
        }

        float m8[8];
        #pragma unroll
        for (int j = 0; j < 8; ++j)
          m8[j] = fmaxf(fmaxf(s0[j], s0[j + 8]), fmaxf(s1[j], s1[j + 8]));
        float ma = fmaxf(fmaxf(m8[0], m8[4]), fmaxf(m8[1], m8[5]));
        float mb = fmaxf(fmaxf(m8[2], m8[6]), fmaxf(m8[3], m8[7]));
        float mh = fmaxf(ma, mb);
        float mfull = fmaxf(mh, __shfl_xor(mh, 32));
        float mn = fmaxf(m_old, mfull);
        bool nores = (mfull <= m_old);
        float sc = exp2f(m_old - mn);
        m_old = mn;

        if (!__all((int)nores)) {
          #pragma unroll
          for (int r = 0; r < 16; ++r) {
            int qi = (r & 3) + 8 * (r >> 2) + 4 * hi;
            float scv = __int_as_float(__builtin_amdgcn_ds_bpermute(qi << 2, __float_as_int(sc)));
            oa[0][r] *= scv; oa[1][r] *= scv; oa[2][r] *= scv; oa[3][r] *= scv;
          }
        }

        #pragma unroll
        for (int r = 0; r < 16; ++r) {
          s0[r] = exp2f(s0[r] - mn);
          s1[r] = exp2f(s1[r] - mn);
        }
        float rsA = 0.f, rsB = 0.f, rsC = 0.f, rsD = 0.f;
        #pragma unroll
        for (int r = 0; r < 16; r += 4) {
          rsA += s0[r];     rsB += s0[r + 1]; rsC += s0[r + 2]; rsD += s0[r + 3];
          rsA += s1[r];     rsB += s1[r + 1]; rsC += s1[r + 2]; rsD += s1[r + 3];
        }
        float rs = (rsA + rsB) + (rsC + rsD);
        rs += __shfl_xor(rs, 32);
        lrow = lrow * sc + rs;

        #pragma unroll
        for (int ks = 0; ks < 4; ++ks) {
          const int qi0 = (ks & 1) * 8;
          union { bf16_t hh[4]; int ii[2]; } ku, su;
          #pragma unroll
          for (int j = 0; j < 4; ++j) {
            float lo, hv;
            if (ks >> 1) { lo = s1[qi0 + j]; hv = s1[qi0 + 4 + j]; }
            else         { lo = s0[qi0 + j]; hv = s0[qi0 + 4 + j]; }
            ku.hh[j] = (bf16_t)(hi ? hv : lo);
            su.hh[j] = (bf16_t)(hi ? lo : hv);
          }
          int r0 = __shfl_xor(su.ii[0], 32), r1 = __shfl_xor(su.ii[1], 32);
          union { int ii[4]; bf16x8 v; } fa;
          fa.ii[0] = hi ? r0 : ku.ii[0];
          fa.ii[1] = hi ? r1 : ku.ii[1];
          fa.ii[2] = hi ? ku.ii[0] : r0;
          fa.ii[3] = hi ? ku.ii[1] : r1;
          __builtin_amdgcn_s_setprio(1);
          #pragma unroll
          for (int nc = 0; nc < 4; ++nc) {
            int lb = (nc * 32 + l31) * 128 + ks * 32 + hi * 16;
            int pb = lb ^ (((lb >> 7) & 7) << 4);
            bf16x8 vf = *(const bf16x8*)&Vs[cur][pb >> 1];
            oa[nc] = __builtin_amdgcn_mfma_f32_32x32x16_bf16(fa.v, vf, oa[nc], 0, 0, 0);
          }
          __builtin_amdgcn_s_setprio(0);
        }
      }
      __syncthreads();
    }

    float inv = 1.0f / lrow;
    bf16_t* Op = Oout + ((size_t)(b * 2048 + q0w)) * 4096 + (size_t)h * 128;
    #pragma unroll
    for (int r = 0; r < 16; ++r) {
      int qi = (r & 3) + 8 * (r >> 2) + 4 * hi;
      float iv = __int_as_float(__builtin_amdgcn_ds_bpermute(qi << 2, __float_as_int(inv)));
      #pragma unroll
      for (int nc = 0; nc < 4; ++nc)
        Op[(size_t)qi * 4096 + nc * 32 + l31] = (bf16_t)(oa[nc][r] * iv);
    }
  }
}

extern "C" void kernel_launch(void* const* d_in, const int* in_sizes, int n_in,
                              void* d_out, int out_size, void* d_ws, size_t ws_size,
                              hipStream_t stream) {
  const float* x    = (const float*)d_in[0];
  const float* cosT = (const float*)d_in[1];
  const float* sinT = (const float*)d_in[2];
  const float* wq   = (const float*)d_in[3];
  const float* wk   = (const float*)d_in[4];
  const float* wv   = (const float*)d_in[5];
  const float* wo   = (const float*)d_in[6];
  float* out = (float*)d_out;
  char* ws = (char*)d_ws;

  bf16_t* wqkvT = (bf16_t*)(ws + 0);           // 6144*4096*2
  bf16_t* woT   = wqkvT;                       // reused after QKV GEMM
  bf16_t* xb    = (bf16_t*)(ws + 50331648);    // 4096*4096*2
  bf16_t* Qb    = xb;                          // reused after QKV GEMM
  bf16_t* qkv   = (bf16_t*)(ws + 83886080);    // 4096*6144*2
  bf16_t* attn_out = qkv;                      // reused after rope/transpose_v
  bf16_t* Kb    = (bf16_t*)(ws + 134217728);
  bf16_t* Vt    = (bf16_t*)(ws + 142606336);

  convert_f32_bf16<<<16384, 256, 0, stream>>>(x, xb, 4194304);
  transpose_convert<<<dim3(128, 128), 256, 0, stream>>>(wq, wqkvT, 4096);
  transpose_convert<<<dim3(32, 128), 256, 0, stream>>>(wk, wqkvT + (size_t)4096 * 4096, 1024);
  transpose_convert<<<dim3(32, 128), 256, 0, stream>>>(wv, wqkvT + (size_t)5120 * 4096, 1024);

  gemm192<<<dim3(16, 32), 512, 0, stream>>>(xb, wqkvT, qkv, 4096, 6144, 4096);

  transpose_convert<<<dim3(128, 128), 256, 0, stream>>>(wo, woT, 4096);  // wqkvT now dead
  rope_qk<<<10240, 256, 0, stream>>>(qkv, cosT, sinT, Qb, Kb);           // xb now dead
  transpose_v<<<dim3(64, 4, 16), 256, 0, stream>>>(qkv, Vt);

  attn_kernel<<<dim3(4, 64), 512, 0, stream>>>(Qb, Kb, Vt, attn_out);    // qkv now dead

  gemm256j<<<dim3(16, 16), 512, 0, stream>>>(attn_out, woT, out, 4096, 4096, 4096);
}

// Round 14
// 541.552 us; speedup vs baseline: 1.0792x; 1.0065x over previous
//
#include <hip/hip_runtime.h>

typedef __bf16 bf16_t;
typedef __bf16 bf16x8 __attribute__((ext_vector_type(8)));
typedef __bf16 bf16x4 __attribute__((ext_vector_type(4)));
typedef float  f32x4  __attribute__((ext_vector_type(4)));
typedef float  f32x16 __attribute__((ext_vector_type(16)));

#define NB   2
#define NS   2048
#define ND   4096
#define NH   32
#define NKVH 8
#define NHD  128

#define BAR()    asm volatile("s_barrier" ::: "memory")
#define LGKM0()  asm volatile("s_waitcnt lgkmcnt(0)" ::: "memory")
#define VMCNT6() asm volatile("s_waitcnt vmcnt(6)" ::: "memory")
#define VMCNT5() asm volatile("s_waitcnt vmcnt(5)" ::: "memory")
#define VMCNT0() asm volatile("s_waitcnt vmcnt(0)" ::: "memory")

__device__ __forceinline__ void gl_lds16(const bf16_t* g, bf16_t* l) {
  __builtin_amdgcn_global_load_lds(
      (const __attribute__((address_space(1))) void*)g,
      (__attribute__((address_space(3))) void*)l, 16, 0, 0);
}

// ---------------- convert x fp32 -> bf16 ----------------
__global__ void convert_f32_bf16(const float* __restrict__ in, bf16_t* __restrict__ out, int n4) {
  int i = blockIdx.x * 256 + threadIdx.x;
  if (i < n4) {
    f32x4 v = *(const f32x4*)&in[(size_t)i * 4];
    bf16x4 o;
    #pragma unroll
    for (int j = 0; j < 4; ++j) o[j] = (bf16_t)v[j];
    *(bf16x4*)&out[(size_t)i * 4] = o;
  }
}

// ------------- transpose-convert W[4096][Nin] fp32 -> Wt[Nin][4096] bf16 -------------
__global__ void transpose_convert(const float* __restrict__ in, bf16_t* __restrict__ out, int Nin) {
  __shared__ float t[32][33];
  int tx = threadIdx.x & 31, ty = threadIdx.x >> 5;
  int n0 = blockIdx.x * 32, k0 = blockIdx.y * 32;
  #pragma unroll
  for (int i = 0; i < 4; ++i)
    t[ty + i * 8][tx] = in[(size_t)(k0 + ty + i * 8) * Nin + n0 + tx];
  __syncthreads();
  #pragma unroll
  for (int i = 0; i < 4; ++i)
    out[(size_t)(n0 + ty + i * 8) * 4096 + k0 + tx] = (bf16_t)t[tx][ty + i * 8];
}

// ============ 256x192 GEMM for QKV: 2-PHASE schedule (R12-proven) ============
__global__ __launch_bounds__(512, 2) void gemm192(const bf16_t* __restrict__ A,
                                                  const bf16_t* __restrict__ Bt,
                                                  bf16_t* __restrict__ C, int M, int N, int K) {
  __shared__ __align__(16) bf16_t As[2][2][128 * 64];
  __shared__ __align__(16) bf16_t Bs[2][192 * 64];
  const int tid = threadIdx.x, lane = tid & 63, wid = tid >> 6;
  const int l15 = lane & 15, l4 = lane >> 4;
  const int wm = wid >> 2, wn = wid & 3;

  const int gx = gridDim.x;
  const int nwg = gx * gridDim.y;
  const int id = blockIdx.y * gx + blockIdx.x;
  const int wg = (id & 7) * (nwg >> 3) + (id >> 3);
  const int bx = wg % gx, by = wg / gx;
  const int row0 = bx * 256, col0 = by * 192;

  const bf16_t* Ab = A + (size_t)row0 * K;
  const bf16_t* Bb = Bt + (size_t)col0 * K;

  auto stA = [&](int t, int h, int buf) {
    #pragma unroll
    for (int i = 0; i < 2; ++i) {
      int phys = i * 8192 + tid * 16;
      int logi = phys ^ (((phys >> 8) & 7) << 4);
      gl_lds16(Ab + (size_t)(h * 128 + (logi >> 7)) * K + t * 64 + ((logi & 127) >> 1),
               &As[buf][h][phys >> 1]);
    }
  };
  auto stB = [&](int t, int buf) {
    #pragma unroll
    for (int i = 0; i < 3; ++i) {
      int phys = i * 8192 + tid * 16;
      int logi = phys ^ (((phys >> 8) & 7) << 4);
      gl_lds16(Bb + (size_t)(logi >> 7) * K + t * 64 + ((logi & 127) >> 1),
               &Bs[buf][phys >> 1]);
    }
  };

  f32x4 acc[8][3];
  #pragma unroll
  for (int m = 0; m < 8; ++m)
    #pragma unroll
    for (int n = 0; n < 3; ++n)
      #pragma unroll
      for (int j = 0; j < 4; ++j) acc[m][n][j] = 0.f;

  const int nt = K >> 6;
  stA(0, 0, 0); stA(0, 1, 0); stB(0, 0);
  stA(1, 0, 1); stB(1, 1);
  VMCNT5();
  BAR();

  auto ardA = [&](int buf, int mh, int kh, int mf) -> bf16x8 {
    int lb = (mh * 64 + mf * 16 + l15) * 128 + kh * 64 + l4 * 16;
    return *(const bf16x8*)&As[buf][wm][(lb ^ (((lb >> 8) & 7) << 4)) >> 1];
  };
  auto brdB = [&](int buf, int kh, int nf) -> bf16x8 {
    int lb = (wn * 48 + nf * 16 + l15) * 128 + kh * 64 + l4 * 16;
    return *(const bf16x8*)&Bs[buf][(lb ^ (((lb >> 8) & 7) << 4)) >> 1];
  };

  #pragma unroll 2
  for (int t = 0; t < nt; ++t) {
    const int cur = t & 1, nxt = cur ^ 1;
    bf16x8 a00[4], a01[4], a10[4], a11[4], b0[3], b1[3];

    // ---- P0: read a00,a01,b0,b1 (14); stage Ah1(t+1)->nxt; MFMA mh0 (24) ----
    #pragma unroll
    for (int mf = 0; mf < 4; ++mf) a00[mf] = ardA(cur, 0, 0, mf);
    #pragma unroll
    for (int nf = 0; nf < 3; ++nf) b0[nf] = brdB(cur, 0, nf);
    #pragma unroll
    for (int mf = 0; mf < 4; ++mf) a01[mf] = ardA(cur, 0, 1, mf);
    #pragma unroll
    for (int nf = 0; nf < 3; ++nf) b1[nf] = brdB(cur, 1, nf);
    if (t + 1 < nt) stA(t + 1, 1, nxt);
    BAR();
    LGKM0();
    __builtin_amdgcn_s_setprio(1);
    #pragma unroll
    for (int mf = 0; mf < 4; ++mf)
      #pragma unroll
      for (int nf = 0; nf < 3; ++nf)
        acc[mf][nf] = __builtin_amdgcn_mfma_f32_16x16x32_bf16(a00[mf], b0[nf], acc[mf][nf], 0, 0, 0);
    #pragma unroll
    for (int mf = 0; mf < 4; ++mf)
      #pragma unroll
      for (int nf = 0; nf < 3; ++nf)
        acc[mf][nf] = __builtin_amdgcn_mfma_f32_16x16x32_bf16(a01[mf], b1[nf], acc[mf][nf], 0, 0, 0);
    __builtin_amdgcn_s_setprio(0);
    BAR();

    // ---- P1: read a10,a11 (8); stage Ah0+B(t+2)->cur; MFMA mh1 (24); vmcnt(5) ----
    #pragma unroll
    for (int mf = 0; mf < 4; ++mf) a10[mf] = ardA(cur, 1, 0, mf);
    #pragma unroll
    for (int mf = 0; mf < 4; ++mf) a11[mf] = ardA(cur, 1, 1, mf);
    if (t + 2 < nt) { stA(t + 2, 0, cur); stB(t + 2, cur); }
    BAR();
    LGKM0();
    __builtin_amdgcn_s_setprio(1);
    #pragma unroll
    for (int mf = 0; mf < 4; ++mf)
      #pragma unroll
      for (int nf = 0; nf < 3; ++nf)
        acc[4 + mf][nf] = __builtin_amdgcn_mfma_f32_16x16x32_bf16(a10[mf], b0[nf], acc[4 + mf][nf], 0, 0, 0);
    #pragma unroll
    for (int mf = 0; mf < 4; ++mf)
      #pragma unroll
      for (int nf = 0; nf < 3; ++nf)
        acc[4 + mf][nf] = __builtin_amdgcn_mfma_f32_16x16x32_bf16(a11[mf], b1[nf], acc[4 + mf][nf], 0, 0, 0);
    __builtin_amdgcn_s_setprio(0);
    if (t + 2 < nt) { VMCNT5(); } else { VMCNT0(); }
    BAR();
  }

  #pragma unroll
  for (int mh = 0; mh < 2; ++mh)
    #pragma unroll
    for (int mf = 0; mf < 4; ++mf)
      #pragma unroll
      for (int nf = 0; nf < 3; ++nf)
        #pragma unroll
        for (int r = 0; r < 4; ++r) {
          size_t row = (size_t)row0 + wm * 128 + mh * 64 + mf * 16 + l4 * 4 + r;
          size_t col = (size_t)col0 + wn * 48 + nf * 16 + l15;
          C[row * N + col] = (bf16_t)acc[mh * 4 + mf][nf][r];
        }
}

// ============ 256x256 GEMM for WO: 2-PHASE schedule (R13-proven) ============
__global__ __launch_bounds__(512, 2) void gemm256j(const bf16_t* __restrict__ A,
                                                   const bf16_t* __restrict__ Bt,
                                                   float* __restrict__ C, int M, int N, int K) {
  __shared__ __align__(16) bf16_t As[2][2][128 * 64];
  __shared__ __align__(16) bf16_t Bs[2][256 * 64];
  const int tid = threadIdx.x, lane = tid & 63, wid = tid >> 6;
  const int l15 = lane & 15, l4 = lane >> 4;
  const int wm = wid >> 2, wn = wid & 3;

  const int gx = gridDim.x;
  const int nwg = gx * gridDim.y;
  const int id = blockIdx.y * gx + blockIdx.x;
  const int wg = (id & 7) * (nwg >> 3) + (id >> 3);
  const int bx = wg % gx, by = wg / gx;
  const int row0 = bx * 256, col0 = by * 256;

  const bf16_t* Ab = A + (size_t)row0 * K;
  const bf16_t* Bb = Bt + (size_t)col0 * K;

  auto stA = [&](int t, int h, int buf) {
    #pragma unroll
    for (int i = 0; i < 2; ++i) {
      int phys = i * 8192 + tid * 16;
      int logi = phys ^ (((phys >> 8) & 7) << 4);
      gl_lds16(Ab + (size_t)(h * 128 + (logi >> 7)) * K + t * 64 + ((logi & 127) >> 1),
               &As[buf][h][phys >> 1]);
    }
  };
  auto stB = [&](int t, int buf) {
    #pragma unroll
    for (int i = 0; i < 4; ++i) {
      int phys = i * 8192 + tid * 16;
      int logi = phys ^ (((phys >> 8) & 7) << 4);
      gl_lds16(Bb + (size_t)(logi >> 7) * K + t * 64 + ((logi & 127) >> 1),
               &Bs[buf][phys >> 1]);
    }
  };

  f32x4 acc[8][4];
  #pragma unroll
  for (int m = 0; m < 8; ++m)
    #pragma unroll
    for (int n = 0; n < 4; ++n)
      #pragma unroll
      for (int j = 0; j < 4; ++j) acc[m][n][j] = 0.f;

  const int nt = K >> 6;
  stA(0, 0, 0); stA(0, 1, 0); stB(0, 0);
  stA(1, 0, 1); stB(1, 1);
  VMCNT6();
  BAR();

  auto ardA = [&](int buf, int mh, int kh, int mf) -> bf16x8 {
    int lb = (mh * 64 + mf * 16 + l15) * 128 + kh * 64 + l4 * 16;
    return *(const bf16x8*)&As[buf][wm][(lb ^ (((lb >> 8) & 7) << 4)) >> 1];
  };
  auto brdB = [&](int buf, int kh, int nf) -> bf16x8 {
    int lb = (wn * 64 + nf * 16 + l15) * 128 + kh * 64 + l4 * 16;
    return *(const bf16x8*)&Bs[buf][(lb ^ (((lb >> 8) & 7) << 4)) >> 1];
  };

  #pragma unroll 2
  for (int t = 0; t < nt; ++t) {
    const int cur = t & 1, nxt = cur ^ 1;
    bf16x8 a00[4], a01[4], a10[4], a11[4], b0[4], b1[4];

    // ---- P0: read a00,b0,a01,b1 (16); stage Ah1(t+1)->nxt; MFMA mh0 (32) ----
    #pragma unroll
    for (int mf = 0; mf < 4; ++mf) a00[mf] = ardA(cur, 0, 0, mf);
    #pragma unroll
    for (int nf = 0; nf < 4; ++nf) b0[nf] = brdB(cur, 0, nf);
    #pragma unroll
    for (int mf = 0; mf < 4; ++mf) a01[mf] = ardA(cur, 0, 1, mf);
    #pragma unroll
    for (int nf = 0; nf < 4; ++nf) b1[nf] = brdB(cur, 1, nf);
    if (t + 1 < nt) stA(t + 1, 1, nxt);
    BAR();
    LGKM0();
    __builtin_amdgcn_s_setprio(1);
    #pragma unroll
    for (int mf = 0; mf < 4; ++mf)
      #pragma unroll
      for (int nf = 0; nf < 4; ++nf)
        acc[mf][nf] = __builtin_amdgcn_mfma_f32_16x16x32_bf16(a00[mf], b0[nf], acc[mf][nf], 0, 0, 0);
    #pragma unroll
    for (int mf = 0; mf < 4; ++mf)
      #pragma unroll
      for (int nf = 0; nf < 4; ++nf)
        acc[mf][nf] = __builtin_amdgcn_mfma_f32_16x16x32_bf16(a01[mf], b1[nf], acc[mf][nf], 0, 0, 0);
    __builtin_amdgcn_s_setprio(0);
    BAR();

    // ---- P1: read a10,a11 (8); stage Ah0+B(t+2)->cur; MFMA mh1 (32); vmcnt(6) ----
    #pragma unroll
    for (int mf = 0; mf < 4; ++mf) a10[mf] = ardA(cur, 1, 0, mf);
    #pragma unroll
    for (int mf = 0; mf < 4; ++mf) a11[mf] = ardA(cur, 1, 1, mf);
    if (t + 2 < nt) { stA(t + 2, 0, cur); stB(t + 2, cur); }
    BAR();
    LGKM0();
    __builtin_amdgcn_s_setprio(1);
    #pragma unroll
    for (int mf = 0; mf < 4; ++mf)
      #pragma unroll
      for (int nf = 0; nf < 4; ++nf)
        acc[4 + mf][nf] = __builtin_amdgcn_mfma_f32_16x16x32_bf16(a10[mf], b0[nf], acc[4 + mf][nf], 0, 0, 0);
    #pragma unroll
    for (int mf = 0; mf < 4; ++mf)
      #pragma unroll
      for (int nf = 0; nf < 4; ++nf)
        acc[4 + mf][nf] = __builtin_amdgcn_mfma_f32_16x16x32_bf16(a11[mf], b1[nf], acc[4 + mf][nf], 0, 0, 0);
    __builtin_amdgcn_s_setprio(0);
    if (t + 2 < nt) { VMCNT6(); } else { VMCNT0(); }
    BAR();
  }

  #pragma unroll
  for (int mh = 0; mh < 2; ++mh)
    #pragma unroll
    for (int mf = 0; mf < 4; ++mf)
      #pragma unroll
      for (int nf = 0; nf < 4; ++nf)
        #pragma unroll
        for (int r = 0; r < 4; ++r) {
          size_t row = (size_t)row0 + wm * 128 + mh * 64 + mf * 16 + l4 * 4 + r;
          size_t col = (size_t)col0 + wn * 64 + nf * 16 + l15;
          C[row * N + col] = acc[mh * 4 + mf][nf][r];
        }
}

// ---------------- RoPE on Q and K, reshape to [b][h][s][hd] ----------------
__global__ void rope_qk(const bf16_t* __restrict__ qkv, const float* __restrict__ cosT,
                        const float* __restrict__ sinT, bf16_t* __restrict__ Q,
                        bf16_t* __restrict__ Kout) {
  int it = blockIdx.x * 256 + threadIdx.x;
  int chunk = it & 15;
  int hs = (it >> 4) % 40;
  int m = (it >> 4) / 40;
  int b = m >> 11, srow = m & 2047;

  bf16x8 v = *(const bf16x8*)&qkv[(size_t)m * 6144 + hs * 128 + chunk * 8];
  f32x4 c4 = *(const f32x4*)&cosT[(size_t)srow * 64 + chunk * 4];
  f32x4 s4 = *(const f32x4*)&sinT[(size_t)srow * 64 + chunk * 4];
  bf16x8 o;
  #pragma unroll
  for (int j = 0; j < 4; ++j) {
    float t1 = (float)v[2 * j], t2 = (float)v[2 * j + 1];
    o[2 * j]     = (bf16_t)(t1 * c4[j] - t2 * s4[j]);
    o[2 * j + 1] = (bf16_t)(t1 * s4[j] + t2 * c4[j]);
  }
  bf16_t* dst;
  if (hs < 32) dst = Q + (((size_t)(b * 32 + hs)) * 2048 + srow) * 128 + chunk * 8;
  else         dst = Kout + (((size_t)(b * 8 + (hs - 32))) * 2048 + srow) * 128 + chunk * 8;
  *(bf16x8*)dst = o;
}

// ---------------- transpose V section of qkv -> Vt[b*8+kv][128][2048] ----------------
__global__ void transpose_v(const bf16_t* __restrict__ qkv, bf16_t* __restrict__ Vt) {
  __shared__ bf16_t t[32][33];
  int tx = threadIdx.x & 31, ty = threadIdx.x >> 5;
  int s0 = blockIdx.x * 32, d0 = blockIdx.y * 32, g = blockIdx.z;
  int b = g >> 3, kv = g & 7;
  const bf16_t* src = qkv + (size_t)(b * 2048) * 6144 + 5120 + kv * 128;
  #pragma unroll
  for (int i = 0; i < 4; ++i)
    t[ty + i * 8][tx] = src[(size_t)(s0 + ty + i * 8) * 6144 + d0 + tx];
  __syncthreads();
  bf16_t* dst = Vt + (size_t)g * 128 * 2048;
  #pragma unroll
  for (int i = 0; i < 4; ++i)
    dst[(size_t)(d0 + ty + i * 8) * 2048 + s0 + tx] = t[tx][ty + i * 8];
}

// ---------------- causal flash attention: 4-wave blocks, 2 blocks/CU (R14) ----------------
// Q-tile 128 rows (4 waves x 32), KVBLK=64, pairs {15-p, p} p=0..7 -> 512 blocks
// = 2/CU, uniform 34 KV-tiles/block. Same swapped-QK in-register softmax as R13.
__global__ __launch_bounds__(256, 2) void attn_kernel(const bf16_t* __restrict__ Q,
                                                      const bf16_t* __restrict__ Kc,
                                                      const bf16_t* __restrict__ Vt,
                                                      bf16_t* __restrict__ Oout) {
  __shared__ __align__(16) bf16_t Ks[2][64 * 128];
  __shared__ __align__(16) bf16_t Vs[2][128 * 64];

  const int tid = threadIdx.x, wid = tid >> 6, lane = tid & 63;
  const int l31 = lane & 31, hi = lane >> 5;
  const int bh = blockIdx.y;
  const int b = bh >> 5, h = bh & 31, kv = h >> 2;
  const int pr = blockIdx.x;  // 0..7 ; pair {15-pr, pr} -> uniform 34 KV-tiles

  const bf16_t* Qp = Q + ((size_t)bh * 2048) * 128;
  const bf16_t* Kp = Kc + ((size_t)(b * 8 + kv) * 2048) * 128;
  const bf16_t* Vp = Vt + ((size_t)(b * 8 + kv) * 128) * 2048;

  const float kscale = 0.08838834764831845f * 1.44269504088896f;

  auto stage = [&](int kt, int buf) {
    const int k0 = kt * 64;
    #pragma unroll
    for (int i = 0; i < 4; ++i) {
      int phys = i * 4096 + tid * 16;
      int logi = phys ^ (((phys >> 8) & 15) << 4);
      gl_lds16(Kp + (size_t)(k0 + (phys >> 8)) * 128 + ((logi & 255) >> 1), &Ks[buf][phys >> 1]);
    }
    #pragma unroll
    for (int i = 0; i < 4; ++i) {
      int phys = i * 4096 + tid * 16;
      int logi = phys ^ (((phys >> 7) & 7) << 4);
      gl_lds16(Vp + (size_t)(phys >> 7) * 2048 + k0 + ((logi & 127) >> 1), &Vs[buf][phys >> 1]);
    }
  };

  for (int half = 0; half < 2; ++half) {
    const int qt = half ? pr : 15 - pr;
    const int q0b = qt * 128;
    const int q0w = q0b + wid * 32;
    const int qg = q0w + l31;
    const int nkt = (qt + 1) * 2;

    bf16x8 qf[8];
    #pragma unroll
    for (int c = 0; c < 8; ++c) {
      bf16x8 t = *(const bf16x8*)&Qp[(size_t)qg * 128 + c * 16 + hi * 8];
      #pragma unroll
      for (int j = 0; j < 8; ++j) t[j] = (bf16_t)((float)t[j] * kscale);
      qf[c] = t;
    }

    f32x16 oa[4];
    #pragma unroll
    for (int nc = 0; nc < 4; ++nc)
      #pragma unroll
      for (int r = 0; r < 16; ++r) oa[nc][r] = 0.f;
    float m_old = -1e30f, lrow = 0.f;

    stage(0, 0);
    __syncthreads();

    for (int kt = 0; kt < nkt; ++kt) {
      const int k0 = kt * 64, cur = kt & 1;
      if (kt + 1 < nkt) stage(kt + 1, cur ^ 1);

      if (k0 <= q0w + 31) {
        f32x16 s0, s1;
        #pragma unroll
        for (int r = 0; r < 16; ++r) { s0[r] = 0.f; s1[r] = 0.f; }
        __builtin_amdgcn_s_setprio(1);
        #pragma unroll
        for (int c = 0; c < 8; ++c) {
          int lb0 = l31 * 256 + c * 32 + hi * 16;
          int pb0 = lb0 ^ (((lb0 >> 8) & 15) << 4);
          bf16x8 kf0 = *(const bf16x8*)&Ks[cur][pb0 >> 1];
          s0 = __builtin_amdgcn_mfma_f32_32x32x16_bf16(kf0, qf[c], s0, 0, 0, 0);
          int lb1 = (32 + l31) * 256 + c * 32 + hi * 16;
          int pb1 = lb1 ^ (((lb1 >> 8) & 15) << 4);
          bf16x8 kf1 = *(const bf16x8*)&Ks[cur][pb1 >> 1];
          s1 = __builtin_amdgcn_mfma_f32_32x32x16_bf16(kf1, qf[c], s1, 0, 0, 0);
        }
        __builtin_amdgcn_s_setprio(0);

        if (k0 + 63 > q0w) {
          #pragma unroll
          for (int r = 0; r < 16; ++r) {
            int key0 = k0 + ((r & 3) + 8 * (r >> 2)) + 4 * hi;
            if (key0 > qg) s0[r] = -1e30f;
            if (key0 + 32 > qg) s1[r] = -1e30f;
          }
        }

        float m8[8];
        #pragma unroll
        for (int j = 0; j < 8; ++j)
          m8[j] = fmaxf(fmaxf(s0[j], s0[j + 8]), fmaxf(s1[j], s1[j + 8]));
        float ma = fmaxf(fmaxf(m8[0], m8[4]), fmaxf(m8[1], m8[5]));
        float mb = fmaxf(fmaxf(m8[2], m8[6]), fmaxf(m8[3], m8[7]));
        float mh = fmaxf(ma, mb);
        float mfull = fmaxf(mh, __shfl_xor(mh, 32));
        float mn = fmaxf(m_old, mfull);
        bool nores = (mfull <= m_old);
        float sc = exp2f(m_old - mn);
        m_old = mn;

        if (!__all((int)nores)) {
          #pragma unroll
          for (int r = 0; r < 16; ++r) {
            int qi = (r & 3) + 8 * (r >> 2) + 4 * hi;
            float scv = __int_as_float(__builtin_amdgcn_ds_bpermute(qi << 2, __float_as_int(sc)));
            oa[0][r] *= scv; oa[1][r] *= scv; oa[2][r] *= scv; oa[3][r] *= scv;
          }
        }

        #pragma unroll
        for (int r = 0; r < 16; ++r) {
          s0[r] = exp2f(s0[r] - mn);
          s1[r] = exp2f(s1[r] - mn);
        }
        float rsA = 0.f, rsB = 0.f, rsC = 0.f, rsD = 0.f;
        #pragma unroll
        for (int r = 0; r < 16; r += 4) {
          rsA += s0[r];     rsB += s0[r + 1]; rsC += s0[r + 2]; rsD += s0[r + 3];
          rsA += s1[r];     rsB += s1[r + 1]; rsC += s1[r + 2]; rsD += s1[r + 3];
        }
        float rs = (rsA + rsB) + (rsC + rsD);
        rs += __shfl_xor(rs, 32);
        lrow = lrow * sc + rs;

        #pragma unroll
        for (int ks = 0; ks < 4; ++ks) {
          const int qi0 = (ks & 1) * 8;
          union { bf16_t hh[4]; int ii[2]; } ku, su;
          #pragma unroll
          for (int j = 0; j < 4; ++j) {
            float lo, hv;
            if (ks >> 1) { lo = s1[qi0 + j]; hv = s1[qi0 + 4 + j]; }
            else         { lo = s0[qi0 + j]; hv = s0[qi0 + 4 + j]; }
            ku.hh[j] = (bf16_t)(hi ? hv : lo);
            su.hh[j] = (bf16_t)(hi ? lo : hv);
          }
          int r0 = __shfl_xor(su.ii[0], 32), r1 = __shfl_xor(su.ii[1], 32);
          union { int ii[4]; bf16x8 v; } fa;
          fa.ii[0] = hi ? r0 : ku.ii[0];
          fa.ii[1] = hi ? r1 : ku.ii[1];
          fa.ii[2] = hi ? ku.ii[0] : r0;
          fa.ii[3] = hi ? ku.ii[1] : r1;
          __builtin_amdgcn_s_setprio(1);
          #pragma unroll
          for (int nc = 0; nc < 4; ++nc) {
            int lb = (nc * 32 + l31) * 128 + ks * 32 + hi * 16;
            int pb = lb ^ (((lb >> 7) & 7) << 4);
            bf16x8 vf = *(const bf16x8*)&Vs[cur][pb >> 1];
            oa[nc] = __builtin_amdgcn_mfma_f32_32x32x16_bf16(fa.v, vf, oa[nc], 0, 0, 0);
          }
          __builtin_amdgcn_s_setprio(0);
        }
      }
      __syncthreads();
    }

    float inv = 1.0f / lrow;
    bf16_t* Op = Oout + ((size_t)(b * 2048 + q0w)) * 4096 + (size_t)h * 128;
    #pragma unroll
    for (int r = 0; r < 16; ++r) {
      int qi = (r & 3) + 8 * (r >> 2) + 4 * hi;
      float iv = __int_as_float(__builtin_amdgcn_ds_bpermute(qi << 2, __float_as_int(inv)));
      #pragma unroll
      for (int nc = 0; nc < 4; ++nc)
        Op[(size_t)qi * 4096 + nc * 32 + l31] = (bf16_t)(oa[nc][r] * iv);
    }
  }
}

extern "C" void kernel_launch(void* const* d_in, const int* in_sizes, int n_in,
                              void* d_out, int out_size, void* d_ws, size_t ws_size,
                              hipStream_t stream) {
  const float* x    = (const float*)d_in[0];
  const float* cosT = (const float*)d_in[1];
  const float* sinT = (const float*)d_in[2];
  const float* wq   = (const float*)d_in[3];
  const float* wk   = (const float*)d_in[4];
  const float* wv   = (const float*)d_in[5];
  const float* wo   = (const float*)d_in[6];
  float* out = (float*)d_out;
  char* ws = (char*)d_ws;

  bf16_t* wqkvT = (bf16_t*)(ws + 0);           // 6144*4096*2
  bf16_t* woT   = wqkvT;                       // reused after QKV GEMM
  bf16_t* xb    = (bf16_t*)(ws + 50331648);    // 4096*4096*2
  bf16_t* Qb    = xb;                          // reused after QKV GEMM
  bf16_t* qkv   = (bf16_t*)(ws + 83886080);    // 4096*6144*2
  bf16_t* attn_out = qkv;                      // reused after rope/transpose_v
  bf16_t* Kb    = (bf16_t*)(ws + 134217728);
  bf16_t* Vt    = (bf16_t*)(ws + 142606336);

  convert_f32_bf16<<<16384, 256, 0, stream>>>(x, xb, 4194304);
  transpose_convert<<<dim3(128, 128), 256, 0, stream>>>(wq, wqkvT, 4096);
  transpose_convert<<<dim3(32, 128), 256, 0, stream>>>(wk, wqkvT + (size_t)4096 * 4096, 1024);
  transpose_convert<<<dim3(32, 128), 256, 0, stream>>>(wv, wqkvT + (size_t)5120 * 4096, 1024);

  gemm192<<<dim3(16, 32), 512, 0, stream>>>(xb, wqkvT, qkv, 4096, 6144, 4096);

  transpose_convert<<<dim3(128, 128), 256, 0, stream>>>(wo, woT, 4096);  // wqkvT now dead
  rope_qk<<<10240, 256, 0, stream>>>(qkv, cosT, sinT, Qb, Kb);           // xb now dead
  transpose_v<<<dim3(64, 4, 16), 256, 0, stream>>>(qkv, Vt);

  attn_kernel<<<dim3(8, 64), 256, 0, stream>>>(Qb, Kb, Vt, attn_out);    // qkv now dead

  gemm256j<<<dim3(16, 16), 512, 0, stream>>>(attn_out, woT, out, 4096, 4096, 4096);
}

// Round 15
// 526.820 us; speedup vs baseline: 1.1094x; 1.0280x over previous
//
#include <hip/hip_runtime.h>

typedef __bf16 bf16_t;
typedef __bf16 bf16x8 __attribute__((ext_vector_type(8)));
typedef __bf16 bf16x4 __attribute__((ext_vector_type(4)));
typedef float  f32x4  __attribute__((ext_vector_type(4)));
typedef float  f32x16 __attribute__((ext_vector_type(16)));

#define NB   2
#define NS   2048
#define ND   4096
#define NH   32
#define NKVH 8
#define NHD  128

#define BAR()     asm volatile("s_barrier" ::: "memory")
#define LGKM0()   asm volatile("s_waitcnt lgkmcnt(0)" ::: "memory")
#define VMCNT10() asm volatile("s_waitcnt vmcnt(10)" ::: "memory")
#define VMCNT6()  asm volatile("s_waitcnt vmcnt(6)" ::: "memory")
#define VMCNT0()  asm volatile("s_waitcnt vmcnt(0)" ::: "memory")

__device__ __forceinline__ void gl_lds16(const bf16_t* g, bf16_t* l) {
  __builtin_amdgcn_global_load_lds(
      (const __attribute__((address_space(1))) void*)g,
      (__attribute__((address_space(3))) void*)l, 16, 0, 0);
}

// ---------------- convert x fp32 -> bf16 ----------------
__global__ void convert_f32_bf16(const float* __restrict__ in, bf16_t* __restrict__ out, int n4) {
  int i = blockIdx.x * 256 + threadIdx.x;
  if (i < n4) {
    f32x4 v = *(const f32x4*)&in[(size_t)i * 4];
    bf16x4 o;
    #pragma unroll
    for (int j = 0; j < 4; ++j) o[j] = (bf16_t)v[j];
    *(bf16x4*)&out[(size_t)i * 4] = o;
  }
}

// ------------- transpose-convert W[4096][Nin] fp32 -> Wt[Nin][4096] bf16 -------------
__global__ void transpose_convert(const float* __restrict__ in, bf16_t* __restrict__ out, int Nin) {
  __shared__ float t[32][33];
  int tx = threadIdx.x & 31, ty = threadIdx.x >> 5;
  int n0 = blockIdx.x * 32, k0 = blockIdx.y * 32;
  #pragma unroll
  for (int i = 0; i < 4; ++i)
    t[ty + i * 8][tx] = in[(size_t)(k0 + ty + i * 8) * Nin + n0 + tx];
  __syncthreads();
  #pragma unroll
  for (int i = 0; i < 4; ++i)
    out[(size_t)(n0 + ty + i * 8) * 4096 + k0 + tx] = (bf16_t)t[tx][ty + i * 8];
}

// ============ 128x192 GEMM for QKV: 2-PHASE, 4 waves, 2 BLOCKS/CU (R15) ============
// Grid 32x32 = 1024 blocks = exactly 2 rounds at 2 blocks/CU. bf16 out.
// 256 thr = 4 waves; wave out = 128 rows x 48 cols (acc[8][3], 16x16x32 MFMA).
// LDS: As[2][128*64] (32KB) + Bs[2][192*64] (48KB) = 80KB -> two blocks co-resident;
// their barrier phases interleave, hiding read/stage/drain stalls under MFMA.
// P0: read a(mf0-3,kh0/1)=8 + b=6; BAR; LGKM0; 24 MFMA; BAR
// P1: read a(mf4-7)=8; stage A(t+2)+B(t+2)->cur (10); BAR; LGKM0; 24 MFMA; vmcnt(10); BAR
// RACE: stages->cur @P1: rows 0-63 of A and all B last read @P0 (1 BAR); rows 64-127
// read same-phase before stage issue (R8/R12-proven latency-gap pattern).
// vmcnt FIFO: enter 10 [A(t+1),B(t+1)]; +10 @P1 = 20; vmcnt(10) drains tile t+1.
__global__ __launch_bounds__(256, 2) void gemm192(const bf16_t* __restrict__ A,
                                                  const bf16_t* __restrict__ Bt,
                                                  bf16_t* __restrict__ C, int M, int N, int K) {
  __shared__ __align__(16) bf16_t As[2][128 * 64];
  __shared__ __align__(16) bf16_t Bs[2][192 * 64];
  const int tid = threadIdx.x, lane = tid & 63, wn = tid >> 6;
  const int l15 = lane & 15, l4 = lane >> 4;

  // T1: bijective XCD swizzle (1024 % 8 == 0)
  const int gx = gridDim.x;
  const int nwg = gx * gridDim.y;
  const int id = blockIdx.y * gx + blockIdx.x;
  const int wg = (id & 7) * (nwg >> 3) + (id >> 3);
  const int bx = wg % gx, by = wg / gx;
  const int row0 = bx * 128, col0 = by * 192;

  const bf16_t* Ab = A + (size_t)row0 * K;
  const bf16_t* Bb = Bt + (size_t)col0 * K;

  auto stA = [&](int t, int buf) {  // 16KB: 4 gl_lds16/thread
    #pragma unroll
    for (int i = 0; i < 4; ++i) {
      int phys = i * 4096 + tid * 16;
      int logi = phys ^ (((phys >> 8) & 7) << 4);
      gl_lds16(Ab + (size_t)(logi >> 7) * K + t * 64 + ((logi & 127) >> 1),
               &As[buf][phys >> 1]);
    }
  };
  auto stB = [&](int t, int buf) {  // 24KB: 6 gl_lds16/thread
    #pragma unroll
    for (int i = 0; i < 6; ++i) {
      int phys = i * 4096 + tid * 16;
      int logi = phys ^ (((phys >> 8) & 7) << 4);
      gl_lds16(Bb + (size_t)(logi >> 7) * K + t * 64 + ((logi & 127) >> 1),
               &Bs[buf][phys >> 1]);
    }
  };

  f32x4 acc[8][3];
  #pragma unroll
  for (int m = 0; m < 8; ++m)
    #pragma unroll
    for (int n = 0; n < 3; ++n)
      #pragma unroll
      for (int j = 0; j < 4; ++j) acc[m][n][j] = 0.f;

  const int nt = K >> 6;
  stA(0, 0); stB(0, 0);
  stA(1, 1); stB(1, 1);
  VMCNT10();  // drain tile0's 10; tile1's 10 in flight
  BAR();

  auto ardA = [&](int buf, int mf, int kh) -> bf16x8 {
    int lb = (mf * 16 + l15) * 128 + kh * 64 + l4 * 16;
    return *(const bf16x8*)&As[buf][(lb ^ (((lb >> 8) & 7) << 4)) >> 1];
  };
  auto brdB = [&](int buf, int kh, int nf) -> bf16x8 {
    int lb = (wn * 48 + nf * 16 + l15) * 128 + kh * 64 + l4 * 16;
    return *(const bf16x8*)&Bs[buf][(lb ^ (((lb >> 8) & 7) << 4)) >> 1];
  };

  #pragma unroll 2
  for (int t = 0; t < nt; ++t) {
    const int cur = t & 1;
    bf16x8 a0[4][2], a1[4][2], b0[3], b1[3];

    // ---- P0: read a(mf0-3)+b (14); MFMA mf0-3 (24) ----
    #pragma unroll
    for (int mf = 0; mf < 4; ++mf)
      #pragma unroll
      for (int kh = 0; kh < 2; ++kh) a0[mf][kh] = ardA(cur, mf, kh);
    #pragma unroll
    for (int nf = 0; nf < 3; ++nf) b0[nf] = brdB(cur, 0, nf);
    #pragma unroll
    for (int nf = 0; nf < 3; ++nf) b1[nf] = brdB(cur, 1, nf);
    BAR();
    LGKM0();
    __builtin_amdgcn_s_setprio(1);
    #pragma unroll
    for (int mf = 0; mf < 4; ++mf)
      #pragma unroll
      for (int nf = 0; nf < 3; ++nf) {
        acc[mf][nf] = __builtin_amdgcn_mfma_f32_16x16x32_bf16(a0[mf][0], b0[nf], acc[mf][nf], 0, 0, 0);
        acc[mf][nf] = __builtin_amdgcn_mfma_f32_16x16x32_bf16(a0[mf][1], b1[nf], acc[mf][nf], 0, 0, 0);
      }
    __builtin_amdgcn_s_setprio(0);
    BAR();

    // ---- P1: read a(mf4-7) (8); stage A(t+2)+B(t+2)->cur; MFMA mf4-7 (24); vmcnt(10) ----
    #pragma unroll
    for (int mf = 0; mf < 4; ++mf)
      #pragma unroll
      for (int kh = 0; kh < 2; ++kh) a1[mf][kh] = ardA(cur, 4 + mf, kh);
    if (t + 2 < nt) { stA(t + 2, cur); stB(t + 2, cur); }
    BAR();
    LGKM0();
    __builtin_amdgcn_s_setprio(1);
    #pragma unroll
    for (int mf = 0; mf < 4; ++mf)
      #pragma unroll
      for (int nf = 0; nf < 3; ++nf) {
        acc[4 + mf][nf] = __builtin_amdgcn_mfma_f32_16x16x32_bf16(a1[mf][0], b0[nf], acc[4 + mf][nf], 0, 0, 0);
        acc[4 + mf][nf] = __builtin_amdgcn_mfma_f32_16x16x32_bf16(a1[mf][1], b1[nf], acc[4 + mf][nf], 0, 0, 0);
      }
    __builtin_amdgcn_s_setprio(0);
    if (t + 2 < nt) { VMCNT10(); } else { VMCNT0(); }
    BAR();
  }

  #pragma unroll
  for (int mf = 0; mf < 8; ++mf)
    #pragma unroll
    for (int nf = 0; nf < 3; ++nf)
      #pragma unroll
      for (int r = 0; r < 4; ++r) {
        size_t row = (size_t)row0 + mf * 16 + l4 * 4 + r;
        size_t col = (size_t)col0 + wn * 48 + nf * 16 + l15;
        C[row * N + col] = (bf16_t)acc[mf][nf][r];
      }
}

// ============ 256x256 GEMM for WO: 2-PHASE schedule (R13-proven) ============
__global__ __launch_bounds__(512, 2) void gemm256j(const bf16_t* __restrict__ A,
                                                   const bf16_t* __restrict__ Bt,
                                                   float* __restrict__ C, int M, int N, int K) {
  __shared__ __align__(16) bf16_t As[2][2][128 * 64];
  __shared__ __align__(16) bf16_t Bs[2][256 * 64];
  const int tid = threadIdx.x, lane = tid & 63, wid = tid >> 6;
  const int l15 = lane & 15, l4 = lane >> 4;
  const int wm = wid >> 2, wn = wid & 3;

  const int gx = gridDim.x;
  const int nwg = gx * gridDim.y;
  const int id = blockIdx.y * gx + blockIdx.x;
  const int wg = (id & 7) * (nwg >> 3) + (id >> 3);
  const int bx = wg % gx, by = wg / gx;
  const int row0 = bx * 256, col0 = by * 256;

  const bf16_t* Ab = A + (size_t)row0 * K;
  const bf16_t* Bb = Bt + (size_t)col0 * K;

  auto stA = [&](int t, int h, int buf) {
    #pragma unroll
    for (int i = 0; i < 2; ++i) {
      int phys = i * 8192 + tid * 16;
      int logi = phys ^ (((phys >> 8) & 7) << 4);
      gl_lds16(Ab + (size_t)(h * 128 + (logi >> 7)) * K + t * 64 + ((logi & 127) >> 1),
               &As[buf][h][phys >> 1]);
    }
  };
  auto stB = [&](int t, int buf) {
    #pragma unroll
    for (int i = 0; i < 4; ++i) {
      int phys = i * 8192 + tid * 16;
      int logi = phys ^ (((phys >> 8) & 7) << 4);
      gl_lds16(Bb + (size_t)(logi >> 7) * K + t * 64 + ((logi & 127) >> 1),
               &Bs[buf][phys >> 1]);
    }
  };

  f32x4 acc[8][4];
  #pragma unroll
  for (int m = 0; m < 8; ++m)
    #pragma unroll
    for (int n = 0; n < 4; ++n)
      #pragma unroll
      for (int j = 0; j < 4; ++j) acc[m][n][j] = 0.f;

  const int nt = K >> 6;
  stA(0, 0, 0); stA(0, 1, 0); stB(0, 0);
  stA(1, 0, 1); stB(1, 1);
  VMCNT6();
  BAR();

  auto ardA = [&](int buf, int mh, int kh, int mf) -> bf16x8 {
    int lb = (mh * 64 + mf * 16 + l15) * 128 + kh * 64 + l4 * 16;
    return *(const bf16x8*)&As[buf][wm][(lb ^ (((lb >> 8) & 7) << 4)) >> 1];
  };
  auto brdB = [&](int buf, int kh, int nf) -> bf16x8 {
    int lb = (wn * 64 + nf * 16 + l15) * 128 + kh * 64 + l4 * 16;
    return *(const bf16x8*)&Bs[buf][(lb ^ (((lb >> 8) & 7) << 4)) >> 1];
  };

  #pragma unroll 2
  for (int t = 0; t < nt; ++t) {
    const int cur = t & 1, nxt = cur ^ 1;
    bf16x8 a00[4], a01[4], a10[4], a11[4], b0[4], b1[4];

    // ---- P0: read a00,b0,a01,b1 (16); stage Ah1(t+1)->nxt; MFMA mh0 (32) ----
    #pragma unroll
    for (int mf = 0; mf < 4; ++mf) a00[mf] = ardA(cur, 0, 0, mf);
    #pragma unroll
    for (int nf = 0; nf < 4; ++nf) b0[nf] = brdB(cur, 0, nf);
    #pragma unroll
    for (int mf = 0; mf < 4; ++mf) a01[mf] = ardA(cur, 0, 1, mf);
    #pragma unroll
    for (int nf = 0; nf < 4; ++nf) b1[nf] = brdB(cur, 1, nf);
    if (t + 1 < nt) stA(t + 1, 1, nxt);
    BAR();
    LGKM0();
    __builtin_amdgcn_s_setprio(1);
    #pragma unroll
    for (int mf = 0; mf < 4; ++mf)
      #pragma unroll
      for (int nf = 0; nf < 4; ++nf)
        acc[mf][nf] = __builtin_amdgcn_mfma_f32_16x16x32_bf16(a00[mf], b0[nf], acc[mf][nf], 0, 0, 0);
    #pragma unroll
    for (int mf = 0; mf < 4; ++mf)
      #pragma unroll
      for (int nf = 0; nf < 4; ++nf)
        acc[mf][nf] = __builtin_amdgcn_mfma_f32_16x16x32_bf16(a01[mf], b1[nf], acc[mf][nf], 0, 0, 0);
    __builtin_amdgcn_s_setprio(0);
    BAR();

    // ---- P1: read a10,a11 (8); stage Ah0+B(t+2)->cur; MFMA mh1 (32); vmcnt(6) ----
    #pragma unroll
    for (int mf = 0; mf < 4; ++mf) a10[mf] = ardA(cur, 1, 0, mf);
    #pragma unroll
    for (int mf = 0; mf < 4; ++mf) a11[mf] = ardA(cur, 1, 1, mf);
    if (t + 2 < nt) { stA(t + 2, 0, cur); stB(t + 2, cur); }
    BAR();
    LGKM0();
    __builtin_amdgcn_s_setprio(1);
    #pragma unroll
    for (int mf = 0; mf < 4; ++mf)
      #pragma unroll
      for (int nf = 0; nf < 4; ++nf)
        acc[4 + mf][nf] = __builtin_amdgcn_mfma_f32_16x16x32_bf16(a10[mf], b0[nf], acc[4 + mf][nf], 0, 0, 0);
    #pragma unroll
    for (int mf = 0; mf < 4; ++mf)
      #pragma unroll
      for (int nf = 0; nf < 4; ++nf)
        acc[4 + mf][nf] = __builtin_amdgcn_mfma_f32_16x16x32_bf16(a11[mf], b1[nf], acc[4 + mf][nf], 0, 0, 0);
    __builtin_amdgcn_s_setprio(0);
    if (t + 2 < nt) { VMCNT6(); } else { VMCNT0(); }
    BAR();
  }

  #pragma unroll
  for (int mh = 0; mh < 2; ++mh)
    #pragma unroll
    for (int mf = 0; mf < 4; ++mf)
      #pragma unroll
      for (int nf = 0; nf < 4; ++nf)
        #pragma unroll
        for (int r = 0; r < 4; ++r) {
          size_t row = (size_t)row0 + wm * 128 + mh * 64 + mf * 16 + l4 * 4 + r;
          size_t col = (size_t)col0 + wn * 64 + nf * 16 + l15;
          C[row * N + col] = acc[mh * 4 + mf][nf][r];
        }
}

// ---------------- RoPE on Q and K, reshape to [b][h][s][hd] ----------------
__global__ void rope_qk(const bf16_t* __restrict__ qkv, const float* __restrict__ cosT,
                        const float* __restrict__ sinT, bf16_t* __restrict__ Q,
                        bf16_t* __restrict__ Kout) {
  int it = blockIdx.x * 256 + threadIdx.x;
  int chunk = it & 15;
  int hs = (it >> 4) % 40;
  int m = (it >> 4) / 40;
  int b = m >> 11, srow = m & 2047;

  bf16x8 v = *(const bf16x8*)&qkv[(size_t)m * 6144 + hs * 128 + chunk * 8];
  f32x4 c4 = *(const f32x4*)&cosT[(size_t)srow * 64 + chunk * 4];
  f32x4 s4 = *(const f32x4*)&sinT[(size_t)srow * 64 + chunk * 4];
  bf16x8 o;
  #pragma unroll
  for (int j = 0; j < 4; ++j) {
    float t1 = (float)v[2 * j], t2 = (float)v[2 * j + 1];
    o[2 * j]     = (bf16_t)(t1 * c4[j] - t2 * s4[j]);
    o[2 * j + 1] = (bf16_t)(t1 * s4[j] + t2 * c4[j]);
  }
  bf16_t* dst;
  if (hs < 32) dst = Q + (((size_t)(b * 32 + hs)) * 2048 + srow) * 128 + chunk * 8;
  else         dst = Kout + (((size_t)(b * 8 + (hs - 32))) * 2048 + srow) * 128 + chunk * 8;
  *(bf16x8*)dst = o;
}

// ---------------- transpose V section of qkv -> Vt[b*8+kv][128][2048] ----------------
__global__ void transpose_v(const bf16_t* __restrict__ qkv, bf16_t* __restrict__ Vt) {
  __shared__ bf16_t t[32][33];
  int tx = threadIdx.x & 31, ty = threadIdx.x >> 5;
  int s0 = blockIdx.x * 32, d0 = blockIdx.y * 32, g = blockIdx.z;
  int b = g >> 3, kv = g & 7;
  const bf16_t* src = qkv + (size_t)(b * 2048) * 6144 + 5120 + kv * 128;
  #pragma unroll
  for (int i = 0; i < 4; ++i)
    t[ty + i * 8][tx] = src[(size_t)(s0 + ty + i * 8) * 6144 + d0 + tx];
  __syncthreads();
  bf16_t* dst = Vt + (size_t)g * 128 * 2048;
  #pragma unroll
  for (int i = 0; i < 4; ++i)
    dst[(size_t)(d0 + ty + i * 8) * 2048 + s0 + tx] = t[tx][ty + i * 8];
}

// ---------------- causal flash attention: 4-wave blocks, 2 blocks/CU (R14-passing) ----------------
__global__ __launch_bounds__(256, 2) void attn_kernel(const bf16_t* __restrict__ Q,
                                                      const bf16_t* __restrict__ Kc,
                                                      const bf16_t* __restrict__ Vt,
                                                      bf16_t* __restrict__ Oout) {
  __shared__ __align__(16) bf16_t Ks[2][64 * 128];
  __shared__ __align__(16) bf16_t Vs[2][128 * 64];

  const int tid = threadIdx.x, wid = tid >> 6, lane = tid & 63;
  const int l31 = lane & 31, hi = lane >> 5;
  const int bh = blockIdx.y;
  const int b = bh >> 5, h = bh & 31, kv = h >> 2;
  const int pr = blockIdx.x;  // 0..7 ; pair {15-pr, pr} -> uniform 34 KV-tiles

  const bf16_t* Qp = Q + ((size_t)bh * 2048) * 128;
  const bf16_t* Kp = Kc + ((size_t)(b * 8 + kv) * 2048) * 128;
  const bf16_t* Vp = Vt + ((size_t)(b * 8 + kv) * 128) * 2048;

  const float kscale = 0.08838834764831845f * 1.44269504088896f;

  auto stage = [&](int kt, int buf) {
    const int k0 = kt * 64;
    #pragma unroll
    for (int i = 0; i < 4; ++i) {
      int phys = i * 4096 + tid * 16;
      int logi = phys ^ (((phys >> 8) & 15) << 4);
      gl_lds16(Kp + (size_t)(k0 + (phys >> 8)) * 128 + ((logi & 255) >> 1), &Ks[buf][phys >> 1]);
    }
    #pragma unroll
    for (int i = 0; i < 4; ++i) {
      int phys = i * 4096 + tid * 16;
      int logi = phys ^ (((phys >> 7) & 7) << 4);
      gl_lds16(Vp + (size_t)(phys >> 7) * 2048 + k0 + ((logi & 127) >> 1), &Vs[buf][phys >> 1]);
    }
  };

  for (int half = 0; half < 2; ++half) {
    const int qt = half ? pr : 15 - pr;
    const int q0b = qt * 128;
    const int q0w = q0b + wid * 32;
    const int qg = q0w + l31;
    const int nkt = (qt + 1) * 2;

    bf16x8 qf[8];
    #pragma unroll
    for (int c = 0; c < 8; ++c) {
      bf16x8 t = *(const bf16x8*)&Qp[(size_t)qg * 128 + c * 16 + hi * 8];
      #pragma unroll
      for (int j = 0; j < 8; ++j) t[j] = (bf16_t)((float)t[j] * kscale);
      qf[c] = t;
    }

    f32x16 oa[4];
    #pragma unroll
    for (int nc = 0; nc < 4; ++nc)
      #pragma unroll
      for (int r = 0; r < 16; ++r) oa[nc][r] = 0.f;
    float m_old = -1e30f, lrow = 0.f;

    stage(0, 0);
    __syncthreads();

    for (int kt = 0; kt < nkt; ++kt) {
      const int k0 = kt * 64, cur = kt & 1;
      if (kt + 1 < nkt) stage(kt + 1, cur ^ 1);

      if (k0 <= q0w + 31) {
        f32x16 s0, s1;
        #pragma unroll
        for (int r = 0; r < 16; ++r) { s0[r] = 0.f; s1[r] = 0.f; }
        __builtin_amdgcn_s_setprio(1);
        #pragma unroll
        for (int c = 0; c < 8; ++c) {
          int lb0 = l31 * 256 + c * 32 + hi * 16;
          int pb0 = lb0 ^ (((lb0 >> 8) & 15) << 4);
          bf16x8 kf0 = *(const bf16x8*)&Ks[cur][pb0 >> 1];
          s0 = __builtin_amdgcn_mfma_f32_32x32x16_bf16(kf0, qf[c], s0, 0, 0, 0);
          int lb1 = (32 + l31) * 256 + c * 32 + hi * 16;
          int pb1 = lb1 ^ (((lb1 >> 8) & 15) << 4);
          bf16x8 kf1 = *(const bf16x8*)&Ks[cur][pb1 >> 1];
          s1 = __builtin_amdgcn_mfma_f32_32x32x16_bf16(kf1, qf[c], s1, 0, 0, 0);
        }
        __builtin_amdgcn_s_setprio(0);

        if (k0 + 63 > q0w) {
          #pragma unroll
          for (int r = 0; r < 16; ++r) {
            int key0 = k0 + ((r & 3) + 8 * (r >> 2)) + 4 * hi;
            if (key0 > qg) s0[r] = -1e30f;
            if (key0 + 32 > qg) s1[r] = -1e30f;
          }
        }

        float m8[8];
        #pragma unroll
        for (int j = 0; j < 8; ++j)
          m8[j] = fmaxf(fmaxf(s0[j], s0[j + 8]), fmaxf(s1[j], s1[j + 8]));
        float ma = fmaxf(fmaxf(m8[0], m8[4]), fmaxf(m8[1], m8[5]));
        float mb = fmaxf(fmaxf(m8[2], m8[6]), fmaxf(m8[3], m8[7]));
        float mh = fmaxf(ma, mb);
        float mfull = fmaxf(mh, __shfl_xor(mh, 32));
        float mn = fmaxf(m_old, mfull);
        bool nores = (mfull <= m_old);
        float sc = exp2f(m_old - mn);
        m_old = mn;

        if (!__all((int)nores)) {
          #pragma unroll
          for (int r = 0; r < 16; ++r) {
            int qi = (r & 3) + 8 * (r >> 2) + 4 * hi;
            float scv = __int_as_float(__builtin_amdgcn_ds_bpermute(qi << 2, __float_as_int(sc)));
            oa[0][r] *= scv; oa[1][r] *= scv; oa[2][r] *= scv; oa[3][r] *= scv;
          }
        }

        #pragma unroll
        for (int r = 0; r < 16; ++r) {
          s0[r] = exp2f(s0[r] - mn);
          s1[r] = exp2f(s1[r] - mn);
        }
        float rsA = 0.f, rsB = 0.f, rsC = 0.f, rsD = 0.f;
        #pragma unroll
        for (int r = 0; r < 16; r += 4) {
          rsA += s0[r];     rsB += s0[r + 1]; rsC += s0[r + 2]; rsD += s0[r + 3];
          rsA += s1[r];     rsB += s1[r + 1]; rsC += s1[r + 2]; rsD += s1[r + 3];
        }
        float rs = (rsA + rsB) + (rsC + rsD);
        rs += __shfl_xor(rs, 32);
        lrow = lrow * sc + rs;

        #pragma unroll
        for (int ks = 0; ks < 4; ++ks) {
          const int qi0 = (ks & 1) * 8;
          union { bf16_t hh[4]; int ii[2]; } ku, su;
          #pragma unroll
          for (int j = 0; j < 4; ++j) {
            float lo, hv;
            if (ks >> 1) { lo = s1[qi0 + j]; hv = s1[qi0 + 4 + j]; }
            else         { lo = s0[qi0 + j]; hv = s0[qi0 + 4 + j]; }
            ku.hh[j] = (bf16_t)(hi ? hv : lo);
            su.hh[j] = (bf16_t)(hi ? lo : hv);
          }
          int r0 = __shfl_xor(su.ii[0], 32), r1 = __shfl_xor(su.ii[1], 32);
          union { int ii[4]; bf16x8 v; } fa;
          fa.ii[0] = hi ? r0 : ku.ii[0];
          fa.ii[1] = hi ? r1 : ku.ii[1];
          fa.ii[2] = hi ? ku.ii[0] : r0;
          fa.ii[3] = hi ? ku.ii[1] : r1;
          __builtin_amdgcn_s_setprio(1);
          #pragma unroll
          for (int nc = 0; nc < 4; ++nc) {
            int lb = (nc * 32 + l31) * 128 + ks * 32 + hi * 16;
            int pb = lb ^ (((lb >> 7) & 7) << 4);
            bf16x8 vf = *(const bf16x8*)&Vs[cur][pb >> 1];
            oa[nc] = __builtin_amdgcn_mfma_f32_32x32x16_bf16(fa.v, vf, oa[nc], 0, 0, 0);
          }
          __builtin_amdgcn_s_setprio(0);
        }
      }
      __syncthreads();
    }

    float inv = 1.0f / lrow;
    bf16_t* Op = Oout + ((size_t)(b * 2048 + q0w)) * 4096 + (size_t)h * 128;
    #pragma unroll
    for (int r = 0; r < 16; ++r) {
      int qi = (r & 3) + 8 * (r >> 2) + 4 * hi;
      float iv = __int_as_float(__builtin_amdgcn_ds_bpermute(qi << 2, __float_as_int(inv)));
      #pragma unroll
      for (int nc = 0; nc < 4; ++nc)
        Op[(size_t)qi * 4096 + nc * 32 + l31] = (bf16_t)(oa[nc][r] * iv);
    }
  }
}

extern "C" void kernel_launch(void* const* d_in, const int* in_sizes, int n_in,
                              void* d_out, int out_size, void* d_ws, size_t ws_size,
                              hipStream_t stream) {
  const float* x    = (const float*)d_in[0];
  const float* cosT = (const float*)d_in[1];
  const float* sinT = (const float*)d_in[2];
  const float* wq   = (const float*)d_in[3];
  const float* wk   = (const float*)d_in[4];
  const float* wv   = (const float*)d_in[5];
  const float* wo   = (const float*)d_in[6];
  float* out = (float*)d_out;
  char* ws = (char*)d_ws;

  bf16_t* wqkvT = (bf16_t*)(ws + 0);           // 6144*4096*2
  bf16_t* woT   = wqkvT;                       // reused after QKV GEMM
  bf16_t* xb    = (bf16_t*)(ws + 50331648);    // 4096*4096*2
  bf16_t* Qb    = xb;                          // reused after QKV GEMM
  bf16_t* qkv   = (bf16_t*)(ws + 83886080);    // 4096*6144*2
  bf16_t* attn_out = qkv;                      // reused after rope/transpose_v
  bf16_t* Kb    = (bf16_t*)(ws + 134217728);
  bf16_t* Vt    = (bf16_t*)(ws + 142606336);

  convert_f32_bf16<<<16384, 256, 0, stream>>>(x, xb, 4194304);
  transpose_convert<<<dim3(128, 128), 256, 0, stream>>>(wq, wqkvT, 4096);
  transpose_convert<<<dim3(32, 128), 256, 0, stream>>>(wk, wqkvT + (size_t)4096 * 4096, 1024);
  transpose_convert<<<dim3(32, 128), 256, 0, stream>>>(wv, wqkvT + (size_t)5120 * 4096, 1024);

  gemm192<<<dim3(32, 32), 256, 0, stream>>>(xb, wqkvT, qkv, 4096, 6144, 4096);

  transpose_convert<<<dim3(128, 128), 256, 0, stream>>>(wo, woT, 4096);  // wqkvT now dead
  rope_qk<<<10240, 256, 0, stream>>>(qkv, cosT, sinT, Qb, Kb);           // xb now dead
  transpose_v<<<dim3(64, 4, 16), 256, 0, stream>>>(qkv, Vt);

  attn_kernel<<<dim3(8, 64), 256, 0, stream>>>(Qb, Kb, Vt, attn_out);    // qkv now dead

  gemm256j<<<dim3(16, 16), 512, 0, stream>>>(attn_out, woT, out, 4096, 4096, 4096);
}

// Round 16
// 513.249 us; speedup vs baseline: 1.1387x; 1.0264x over previous
//
#include <hip/hip_runtime.h>

typedef __bf16 bf16_t;
typedef __bf16 bf16x8 __attribute__((ext_vector_type(8)));
typedef __bf16 bf16x4 __attribute__((ext_vector_type(4)));
typedef float  f32x4  __attribute__((ext_vector_type(4)));
typedef float  f32x16 __attribute__((ext_vector_type(16)));

#define NB   2
#define NS   2048
#define ND   4096
#define NH   32
#define NKVH 8
#define NHD  128

#define BAR()     asm volatile("s_barrier" ::: "memory")
#define LGKM0()   asm volatile("s_waitcnt lgkmcnt(0)" ::: "memory")
#define VMCNT10() asm volatile("s_waitcnt vmcnt(10)" ::: "memory")
#define VMCNT6()  asm volatile("s_waitcnt vmcnt(6)" ::: "memory")
#define VMCNT0()  asm volatile("s_waitcnt vmcnt(0)" ::: "memory")

__device__ __forceinline__ void gl_lds16(const bf16_t* g, bf16_t* l) {
  __builtin_amdgcn_global_load_lds(
      (const __attribute__((address_space(1))) void*)g,
      (__attribute__((address_space(3))) void*)l, 16, 0, 0);
}

// ---------------- convert x fp32 -> bf16 ----------------
__global__ void convert_f32_bf16(const float* __restrict__ in, bf16_t* __restrict__ out, int n4) {
  int i = blockIdx.x * 256 + threadIdx.x;
  if (i < n4) {
    f32x4 v = *(const f32x4*)&in[(size_t)i * 4];
    bf16x4 o;
    #pragma unroll
    for (int j = 0; j < 4; ++j) o[j] = (bf16_t)v[j];
    *(bf16x4*)&out[(size_t)i * 4] = o;
  }
}

// ------------- transpose-convert W[4096][Nin] fp32 -> Wt[Nin][4096] bf16 -------------
__global__ void transpose_convert(const float* __restrict__ in, bf16_t* __restrict__ out, int Nin) {
  __shared__ float t[32][33];
  int tx = threadIdx.x & 31, ty = threadIdx.x >> 5;
  int n0 = blockIdx.x * 32, k0 = blockIdx.y * 32;
  #pragma unroll
  for (int i = 0; i < 4; ++i)
    t[ty + i * 8][tx] = in[(size_t)(k0 + ty + i * 8) * Nin + n0 + tx];
  __syncthreads();
  #pragma unroll
  for (int i = 0; i < 4; ++i)
    out[(size_t)(n0 + ty + i * 8) * 4096 + k0 + tx] = (bf16_t)t[tx][ty + i * 8];
}

// ============ 128x192 GEMM for QKV: 2-PHASE, 2x2 wave grid, 2 BLOCKS/CU (R16) ============
// Grid 32x32 = 1024 blocks = exactly 2 rounds at 2 blocks/CU. bf16 out.
// 256 thr = 4 waves in 2m x 2n grid; wave out = 64 rows x 96 cols (acc[4][6]).
// vs R15 (wave=128x48): A read redundancy 4x->2x, block LDS reads 88->80 frags,
// and ALL A reads land in P0 -> A stage at P1 is a full barrier after last reader.
// P0: read a(all 8: 4mf x 2kh) + b(kh0: 6); BAR; LGKM0; 24 MFMA (kh0); BAR
// P1: read b(kh1: 6); stage A(t+2)+B(t+2)->cur (10); BAR; LGKM0; 24 MFMA (kh1); vmcnt(10); BAR
// RACE: A[cur] last read @P0 (1 BAR before stage); B[cur] kh1 read @P1 before stage
// issue in program order (R8/R12-proven same-phase latency-gap pattern).
// vmcnt FIFO: enter 10 [t+1 A,B]; +10 @P1 = 20; vmcnt(10) drains tile t+1.
__global__ __launch_bounds__(256, 2) void gemm192(const bf16_t* __restrict__ A,
                                                  const bf16_t* __restrict__ Bt,
                                                  bf16_t* __restrict__ C, int M, int N, int K) {
  __shared__ __align__(16) bf16_t As[2][128 * 64];
  __shared__ __align__(16) bf16_t Bs[2][192 * 64];
  const int tid = threadIdx.x, lane = tid & 63, wid = tid >> 6;
  const int l15 = lane & 15, l4 = lane >> 4;
  const int wm = wid >> 1, wn = wid & 1;

  // T1: bijective XCD swizzle (1024 % 8 == 0)
  const int gx = gridDim.x;
  const int nwg = gx * gridDim.y;
  const int id = blockIdx.y * gx + blockIdx.x;
  const int wg = (id & 7) * (nwg >> 3) + (id >> 3);
  const int bx = wg % gx, by = wg / gx;
  const int row0 = bx * 128, col0 = by * 192;

  const bf16_t* Ab = A + (size_t)row0 * K;
  const bf16_t* Bb = Bt + (size_t)col0 * K;

  auto stA = [&](int t, int buf) {  // 16KB: 4 gl_lds16/thread
    #pragma unroll
    for (int i = 0; i < 4; ++i) {
      int phys = i * 4096 + tid * 16;
      int logi = phys ^ (((phys >> 8) & 7) << 4);
      gl_lds16(Ab + (size_t)(logi >> 7) * K + t * 64 + ((logi & 127) >> 1),
               &As[buf][phys >> 1]);
    }
  };
  auto stB = [&](int t, int buf) {  // 24KB: 6 gl_lds16/thread
    #pragma unroll
    for (int i = 0; i < 6; ++i) {
      int phys = i * 4096 + tid * 16;
      int logi = phys ^ (((phys >> 8) & 7) << 4);
      gl_lds16(Bb + (size_t)(logi >> 7) * K + t * 64 + ((logi & 127) >> 1),
               &Bs[buf][phys >> 1]);
    }
  };

  f32x4 acc[4][6];
  #pragma unroll
  for (int m = 0; m < 4; ++m)
    #pragma unroll
    for (int n = 0; n < 6; ++n)
      #pragma unroll
      for (int j = 0; j < 4; ++j) acc[m][n][j] = 0.f;

  const int nt = K >> 6;
  stA(0, 0); stB(0, 0);
  stA(1, 1); stB(1, 1);
  VMCNT10();  // drain tile0's 10; tile1's 10 in flight
  BAR();

  auto ardA = [&](int buf, int mf, int kh) -> bf16x8 {
    int lb = (wm * 64 + mf * 16 + l15) * 128 + kh * 64 + l4 * 16;
    return *(const bf16x8*)&As[buf][(lb ^ (((lb >> 8) & 7) << 4)) >> 1];
  };
  auto brdB = [&](int buf, int kh, int nf) -> bf16x8 {
    int lb = (wn * 96 + nf * 16 + l15) * 128 + kh * 64 + l4 * 16;
    return *(const bf16x8*)&Bs[buf][(lb ^ (((lb >> 8) & 7) << 4)) >> 1];
  };

  #pragma unroll 2
  for (int t = 0; t < nt; ++t) {
    const int cur = t & 1;
    bf16x8 a[4][2], b0[6], b1[6];

    // ---- P0: read a (8) + b(kh0) (6); MFMA kh0 (24) ----
    #pragma unroll
    for (int mf = 0; mf < 4; ++mf)
      #pragma unroll
      for (int kh = 0; kh < 2; ++kh) a[mf][kh] = ardA(cur, mf, kh);
    #pragma unroll
    for (int nf = 0; nf < 6; ++nf) b0[nf] = brdB(cur, 0, nf);
    BAR();
    LGKM0();
    __builtin_amdgcn_s_setprio(1);
    #pragma unroll
    for (int mf = 0; mf < 4; ++mf)
      #pragma unroll
      for (int nf = 0; nf < 6; ++nf)
        acc[mf][nf] = __builtin_amdgcn_mfma_f32_16x16x32_bf16(a[mf][0], b0[nf], acc[mf][nf], 0, 0, 0);
    __builtin_amdgcn_s_setprio(0);
    BAR();

    // ---- P1: read b(kh1) (6); stage A(t+2)+B(t+2)->cur; MFMA kh1 (24); vmcnt(10) ----
    #pragma unroll
    for (int nf = 0; nf < 6; ++nf) b1[nf] = brdB(cur, 1, nf);
    if (t + 2 < nt) { stA(t + 2, cur); stB(t + 2, cur); }
    BAR();
    LGKM0();
    __builtin_amdgcn_s_setprio(1);
    #pragma unroll
    for (int mf = 0; mf < 4; ++mf)
      #pragma unroll
      for (int nf = 0; nf < 6; ++nf)
        acc[mf][nf] = __builtin_amdgcn_mfma_f32_16x16x32_bf16(a[mf][1], b1[nf], acc[mf][nf], 0, 0, 0);
    __builtin_amdgcn_s_setprio(0);
    if (t + 2 < nt) { VMCNT10(); } else { VMCNT0(); }
    BAR();
  }

  #pragma unroll
  for (int mf = 0; mf < 4; ++mf)
    #pragma unroll
    for (int nf = 0; nf < 6; ++nf)
      #pragma unroll
      for (int r = 0; r < 4; ++r) {
        size_t row = (size_t)row0 + wm * 64 + mf * 16 + l4 * 4 + r;
        size_t col = (size_t)col0 + wn * 96 + nf * 16 + l15;
        C[row * N + col] = (bf16_t)acc[mf][nf][r];
      }
}

// ============ 256x256 GEMM for WO: 2-PHASE schedule (R13-proven) ============
__global__ __launch_bounds__(512, 2) void gemm256j(const bf16_t* __restrict__ A,
                                                   const bf16_t* __restrict__ Bt,
                                                   float* __restrict__ C, int M, int N, int K) {
  __shared__ __align__(16) bf16_t As[2][2][128 * 64];
  __shared__ __align__(16) bf16_t Bs[2][256 * 64];
  const int tid = threadIdx.x, lane = tid & 63, wid = tid >> 6;
  const int l15 = lane & 15, l4 = lane >> 4;
  const int wm = wid >> 2, wn = wid & 3;

  const int gx = gridDim.x;
  const int nwg = gx * gridDim.y;
  const int id = blockIdx.y * gx + blockIdx.x;
  const int wg = (id & 7) * (nwg >> 3) + (id >> 3);
  const int bx = wg % gx, by = wg / gx;
  const int row0 = bx * 256, col0 = by * 256;

  const bf16_t* Ab = A + (size_t)row0 * K;
  const bf16_t* Bb = Bt + (size_t)col0 * K;

  auto stA = [&](int t, int h, int buf) {
    #pragma unroll
    for (int i = 0; i < 2; ++i) {
      int phys = i * 8192 + tid * 16;
      int logi = phys ^ (((phys >> 8) & 7) << 4);
      gl_lds16(Ab + (size_t)(h * 128 + (logi >> 7)) * K + t * 64 + ((logi & 127) >> 1),
               &As[buf][h][phys >> 1]);
    }
  };
  auto stB = [&](int t, int buf) {
    #pragma unroll
    for (int i = 0; i < 4; ++i) {
      int phys = i * 8192 + tid * 16;
      int logi = phys ^ (((phys >> 8) & 7) << 4);
      gl_lds16(Bb + (size_t)(logi >> 7) * K + t * 64 + ((logi & 127) >> 1),
               &Bs[buf][phys >> 1]);
    }
  };

  f32x4 acc[8][4];
  #pragma unroll
  for (int m = 0; m < 8; ++m)
    #pragma unroll
    for (int n = 0; n < 4; ++n)
      #pragma unroll
      for (int j = 0; j < 4; ++j) acc[m][n][j] = 0.f;

  const int nt = K >> 6;
  stA(0, 0, 0); stA(0, 1, 0); stB(0, 0);
  stA(1, 0, 1); stB(1, 1);
  VMCNT6();
  BAR();

  auto ardA = [&](int buf, int mh, int kh, int mf) -> bf16x8 {
    int lb = (mh * 64 + mf * 16 + l15) * 128 + kh * 64 + l4 * 16;
    return *(const bf16x8*)&As[buf][wm][(lb ^ (((lb >> 8) & 7) << 4)) >> 1];
  };
  auto brdB = [&](int buf, int kh, int nf) -> bf16x8 {
    int lb = (wn * 64 + nf * 16 + l15) * 128 + kh * 64 + l4 * 16;
    return *(const bf16x8*)&Bs[buf][(lb ^ (((lb >> 8) & 7) << 4)) >> 1];
  };

  #pragma unroll 2
  for (int t = 0; t < nt; ++t) {
    const int cur = t & 1, nxt = cur ^ 1;
    bf16x8 a00[4], a01[4], a10[4], a11[4], b0[4], b1[4];

    // ---- P0: read a00,b0,a01,b1 (16); stage Ah1(t+1)->nxt; MFMA mh0 (32) ----
    #pragma unroll
    for (int mf = 0; mf < 4; ++mf) a00[mf] = ardA(cur, 0, 0, mf);
    #pragma unroll
    for (int nf = 0; nf < 4; ++nf) b0[nf] = brdB(cur, 0, nf);
    #pragma unroll
    for (int mf = 0; mf < 4; ++mf) a01[mf] = ardA(cur, 0, 1, mf);
    #pragma unroll
    for (int nf = 0; nf < 4; ++nf) b1[nf] = brdB(cur, 1, nf);
    if (t + 1 < nt) stA(t + 1, 1, nxt);
    BAR();
    LGKM0();
    __builtin_amdgcn_s_setprio(1);
    #pragma unroll
    for (int mf = 0; mf < 4; ++mf)
      #pragma unroll
      for (int nf = 0; nf < 4; ++nf)
        acc[mf][nf] = __builtin_amdgcn_mfma_f32_16x16x32_bf16(a00[mf], b0[nf], acc[mf][nf], 0, 0, 0);
    #pragma unroll
    for (int mf = 0; mf < 4; ++mf)
      #pragma unroll
      for (int nf = 0; nf < 4; ++nf)
        acc[mf][nf] = __builtin_amdgcn_mfma_f32_16x16x32_bf16(a01[mf], b1[nf], acc[mf][nf], 0, 0, 0);
    __builtin_amdgcn_s_setprio(0);
    BAR();

    // ---- P1: read a10,a11 (8); stage Ah0+B(t+2)->cur; MFMA mh1 (32); vmcnt(6) ----
    #pragma unroll
    for (int mf = 0; mf < 4; ++mf) a10[mf] = ardA(cur, 1, 0, mf);
    #pragma unroll
    for (int mf = 0; mf < 4; ++mf) a11[mf] = ardA(cur, 1, 1, mf);
    if (t + 2 < nt) { stA(t + 2, 0, cur); stB(t + 2, cur); }
    BAR();
    LGKM0();
    __builtin_amdgcn_s_setprio(1);
    #pragma unroll
    for (int mf = 0; mf < 4; ++mf)
      #pragma unroll
      for (int nf = 0; nf < 4; ++nf)
        acc[4 + mf][nf] = __builtin_amdgcn_mfma_f32_16x16x32_bf16(a10[mf], b0[nf], acc[4 + mf][nf], 0, 0, 0);
    #pragma unroll
    for (int mf = 0; mf < 4; ++mf)
      #pragma unroll
      for (int nf = 0; nf < 4; ++nf)
        acc[4 + mf][nf] = __builtin_amdgcn_mfma_f32_16x16x32_bf16(a11[mf], b1[nf], acc[4 + mf][nf], 0, 0, 0);
    __builtin_amdgcn_s_setprio(0);
    if (t + 2 < nt) { VMCNT6(); } else { VMCNT0(); }
    BAR();
  }

  #pragma unroll
  for (int mh = 0; mh < 2; ++mh)
    #pragma unroll
    for (int mf = 0; mf < 4; ++mf)
      #pragma unroll
      for (int nf = 0; nf < 4; ++nf)
        #pragma unroll
        for (int r = 0; r < 4; ++r) {
          size_t row = (size_t)row0 + wm * 128 + mh * 64 + mf * 16 + l4 * 4 + r;
          size_t col = (size_t)col0 + wn * 64 + nf * 16 + l15;
          C[row * N + col] = acc[mh * 4 + mf][nf][r];
        }
}

// ---------------- RoPE on Q and K, reshape to [b][h][s][hd] ----------------
__global__ void rope_qk(const bf16_t* __restrict__ qkv, const float* __restrict__ cosT,
                        const float* __restrict__ sinT, bf16_t* __restrict__ Q,
                        bf16_t* __restrict__ Kout) {
  int it = blockIdx.x * 256 + threadIdx.x;
  int chunk = it & 15;
  int hs = (it >> 4) % 40;
  int m = (it >> 4) / 40;
  int b = m >> 11, srow = m & 2047;

  bf16x8 v = *(const bf16x8*)&qkv[(size_t)m * 6144 + hs * 128 + chunk * 8];
  f32x4 c4 = *(const f32x4*)&cosT[(size_t)srow * 64 + chunk * 4];
  f32x4 s4 = *(const f32x4*)&sinT[(size_t)srow * 64 + chunk * 4];
  bf16x8 o;
  #pragma unroll
  for (int j = 0; j < 4; ++j) {
    float t1 = (float)v[2 * j], t2 = (float)v[2 * j + 1];
    o[2 * j]     = (bf16_t)(t1 * c4[j] - t2 * s4[j]);
    o[2 * j + 1] = (bf16_t)(t1 * s4[j] + t2 * c4[j]);
  }
  bf16_t* dst;
  if (hs < 32) dst = Q + (((size_t)(b * 32 + hs)) * 2048 + srow) * 128 + chunk * 8;
  else         dst = Kout + (((size_t)(b * 8 + (hs - 32))) * 2048 + srow) * 128 + chunk * 8;
  *(bf16x8*)dst = o;
}

// ---------------- transpose V section of qkv -> Vt[b*8+kv][128][2048] ----------------
__global__ void transpose_v(const bf16_t* __restrict__ qkv, bf16_t* __restrict__ Vt) {
  __shared__ bf16_t t[32][33];
  int tx = threadIdx.x & 31, ty = threadIdx.x >> 5;
  int s0 = blockIdx.x * 32, d0 = blockIdx.y * 32, g = blockIdx.z;
  int b = g >> 3, kv = g & 7;
  const bf16_t* src = qkv + (size_t)(b * 2048) * 6144 + 5120 + kv * 128;
  #pragma unroll
  for (int i = 0; i < 4; ++i)
    t[ty + i * 8][tx] = src[(size_t)(s0 + ty + i * 8) * 6144 + d0 + tx];
  __syncthreads();
  bf16_t* dst = Vt + (size_t)g * 128 * 2048;
  #pragma unroll
  for (int i = 0; i < 4; ++i)
    dst[(size_t)(d0 + ty + i * 8) * 2048 + s0 + tx] = t[tx][ty + i * 8];
}

// ---------------- causal flash attention: 4-wave blocks, 2 blocks/CU + T13 defer-max ----------------
__global__ __launch_bounds__(256, 2) void attn_kernel(const bf16_t* __restrict__ Q,
                                                      const bf16_t* __restrict__ Kc,
                                                      const bf16_t* __restrict__ Vt,
                                                      bf16_t* __restrict__ Oout) {
  __shared__ __align__(16) bf16_t Ks[2][64 * 128];
  __shared__ __align__(16) bf16_t Vs[2][128 * 64];

  const int tid = threadIdx.x, wid = tid >> 6, lane = tid & 63;
  const int l31 = lane & 31, hi = lane >> 5;
  const int bh = blockIdx.y;
  const int b = bh >> 5, h = bh & 31, kv = h >> 2;
  const int pr = blockIdx.x;  // 0..7 ; pair {15-pr, pr} -> uniform 34 KV-tiles

  const bf16_t* Qp = Q + ((size_t)bh * 2048) * 128;
  const bf16_t* Kp = Kc + ((size_t)(b * 8 + kv) * 2048) * 128;
  const bf16_t* Vp = Vt + ((size_t)(b * 8 + kv) * 128) * 2048;

  const float kscale = 0.08838834764831845f * 1.44269504088896f;

  auto stage = [&](int kt, int buf) {
    const int k0 = kt * 64;
    #pragma unroll
    for (int i = 0; i < 4; ++i) {
      int phys = i * 4096 + tid * 16;
      int logi = phys ^ (((phys >> 8) & 15) << 4);
      gl_lds16(Kp + (size_t)(k0 + (phys >> 8)) * 128 + ((logi & 255) >> 1), &Ks[buf][phys >> 1]);
    }
    #pragma unroll
    for (int i = 0; i < 4; ++i) {
      int phys = i * 4096 + tid * 16;
      int logi = phys ^ (((phys >> 7) & 7) << 4);
      gl_lds16(Vp + (size_t)(phys >> 7) * 2048 + k0 + ((logi & 127) >> 1), &Vs[buf][phys >> 1]);
    }
  };

  for (int half = 0; half < 2; ++half) {
    const int qt = half ? pr : 15 - pr;
    const int q0b = qt * 128;
    const int q0w = q0b + wid * 32;
    const int qg = q0w + l31;
    const int nkt = (qt + 1) * 2;

    bf16x8 qf[8];
    #pragma unroll
    for (int c = 0; c < 8; ++c) {
      bf16x8 t = *(const bf16x8*)&Qp[(size_t)qg * 128 + c * 16 + hi * 8];
      #pragma unroll
      for (int j = 0; j < 8; ++j) t[j] = (bf16_t)((float)t[j] * kscale);
      qf[c] = t;
    }

    f32x16 oa[4];
    #pragma unroll
    for (int nc = 0; nc < 4; ++nc)
      #pragma unroll
      for (int r = 0; r < 16; ++r) oa[nc][r] = 0.f;
    float m_old = -1e30f, lrow = 0.f;

    stage(0, 0);
    __syncthreads();

    for (int kt = 0; kt < nkt; ++kt) {
      const int k0 = kt * 64, cur = kt & 1;
      if (kt + 1 < nkt) stage(kt + 1, cur ^ 1);

      if (k0 <= q0w + 31) {
        f32x16 s0, s1;
        #pragma unroll
        for (int r = 0; r < 16; ++r) { s0[r] = 0.f; s1[r] = 0.f; }
        __builtin_amdgcn_s_setprio(1);
        #pragma unroll
        for (int c = 0; c < 8; ++c) {
          int lb0 = l31 * 256 + c * 32 + hi * 16;
          int pb0 = lb0 ^ (((lb0 >> 8) & 15) << 4);
          bf16x8 kf0 = *(const bf16x8*)&Ks[cur][pb0 >> 1];
          s0 = __builtin_amdgcn_mfma_f32_32x32x16_bf16(kf0, qf[c], s0, 0, 0, 0);
          int lb1 = (32 + l31) * 256 + c * 32 + hi * 16;
          int pb1 = lb1 ^ (((lb1 >> 8) & 15) << 4);
          bf16x8 kf1 = *(const bf16x8*)&Ks[cur][pb1 >> 1];
          s1 = __builtin_amdgcn_mfma_f32_32x32x16_bf16(kf1, qf[c], s1, 0, 0, 0);
        }
        __builtin_amdgcn_s_setprio(0);

        if (k0 + 63 > q0w) {
          #pragma unroll
          for (int r = 0; r < 16; ++r) {
            int key0 = k0 + ((r & 3) + 8 * (r >> 2)) + 4 * hi;
            if (key0 > qg) s0[r] = -1e30f;
            if (key0 + 32 > qg) s1[r] = -1e30f;
          }
        }

        float m8[8];
        #pragma unroll
        for (int j = 0; j < 8; ++j)
          m8[j] = fmaxf(fmaxf(s0[j], s0[j + 8]), fmaxf(s1[j], s1[j + 8]));
        float ma = fmaxf(fmaxf(m8[0], m8[4]), fmaxf(m8[1], m8[5]));
        float mb = fmaxf(fmaxf(m8[2], m8[6]), fmaxf(m8[3], m8[7]));
        float mh = fmaxf(ma, mb);
        float mfull = fmaxf(mh, __shfl_xor(mh, 32));

        // T13 defer-max: keep old max (P bounded by 2^8) unless some lane grew > 8.
        float mn;
        bool defer = (mfull - m_old <= 8.0f);
        if (__all((int)defer)) {
          mn = m_old;
        } else {
          mn = fmaxf(m_old, mfull);
          float sc = exp2f(m_old - mn);
          #pragma unroll
          for (int r = 0; r < 16; ++r) {
            int qi = (r & 3) + 8 * (r >> 2) + 4 * hi;
            float scv = __int_as_float(__builtin_amdgcn_ds_bpermute(qi << 2, __float_as_int(sc)));
            oa[0][r] *= scv; oa[1][r] *= scv; oa[2][r] *= scv; oa[3][r] *= scv;
          }
          lrow *= sc;   // sc is lane-local for q = l31
          m_old = mn;
        }

        #pragma unroll
        for (int r = 0; r < 16; ++r) {
          s0[r] = exp2f(s0[r] - mn);
          s1[r] = exp2f(s1[r] - mn);
        }
        float rsA = 0.f, rsB = 0.f, rsC = 0.f, rsD = 0.f;
        #pragma unroll
        for (int r = 0; r < 16; r += 4) {
          rsA += s0[r];     rsB += s0[r + 1]; rsC += s0[r + 2]; rsD += s0[r + 3];
          rsA += s1[r];     rsB += s1[r + 1]; rsC += s1[r + 2]; rsD += s1[r + 3];
        }
        float rs = (rsA + rsB) + (rsC + rsD);
        rs += __shfl_xor(rs, 32);
        lrow = lrow + rs;

        #pragma unroll
        for (int ks = 0; ks < 4; ++ks) {
          const int qi0 = (ks & 1) * 8;
          union { bf16_t hh[4]; int ii[2]; } ku, su;
          #pragma unroll
          for (int j = 0; j < 4; ++j) {
            float lo, hv;
            if (ks >> 1) { lo = s1[qi0 + j]; hv = s1[qi0 + 4 + j]; }
            else         { lo = s0[qi0 + j]; hv = s0[qi0 + 4 + j]; }
            ku.hh[j] = (bf16_t)(hi ? hv : lo);
            su.hh[j] = (bf16_t)(hi ? lo : hv);
          }
          int r0 = __shfl_xor(su.ii[0], 32), r1 = __shfl_xor(su.ii[1], 32);
          union { int ii[4]; bf16x8 v; } fa;
          fa.ii[0] = hi ? r0 : ku.ii[0];
          fa.ii[1] = hi ? r1 : ku.ii[1];
          fa.ii[2] = hi ? ku.ii[0] : r0;
          fa.ii[3] = hi ? ku.ii[1] : r1;
          __builtin_amdgcn_s_setprio(1);
          #pragma unroll
          for (int nc = 0; nc < 4; ++nc) {
            int lb = (nc * 32 + l31) * 128 + ks * 32 + hi * 16;
            int pb = lb ^ (((lb >> 7) & 7) << 4);
            bf16x8 vf = *(const bf16x8*)&Vs[cur][pb >> 1];
            oa[nc] = __builtin_amdgcn_mfma_f32_32x32x16_bf16(fa.v, vf, oa[nc], 0, 0, 0);
          }
          __builtin_amdgcn_s_setprio(0);
        }
      }
      __syncthreads();
    }

    float inv = 1.0f / lrow;
    bf16_t* Op = Oout + ((size_t)(b * 2048 + q0w)) * 4096 + (size_t)h * 128;
    #pragma unroll
    for (int r = 0; r < 16; ++r) {
      int qi = (r & 3) + 8 * (r >> 2) + 4 * hi;
      float iv = __int_as_float(__builtin_amdgcn_ds_bpermute(qi << 2, __float_as_int(inv)));
      #pragma unroll
      for (int nc = 0; nc < 4; ++nc)
        Op[(size_t)qi * 4096 + nc * 32 + l31] = (bf16_t)(oa[nc][r] * iv);
    }
  }
}

extern "C" void kernel_launch(void* const* d_in, const int* in_sizes, int n_in,
                              void* d_out, int out_size, void* d_ws, size_t ws_size,
                              hipStream_t stream) {
  const float* x    = (const float*)d_in[0];
  const float* cosT = (const float*)d_in[1];
  const float* sinT = (const float*)d_in[2];
  const float* wq   = (const float*)d_in[3];
  const float* wk   = (const float*)d_in[4];
  const float* wv   = (const float*)d_in[5];
  const float* wo   = (const float*)d_in[6];
  float* out = (float*)d_out;
  char* ws = (char*)d_ws;

  bf16_t* wqkvT = (bf16_t*)(ws + 0);           // 6144*4096*2
  bf16_t* woT   = wqkvT;                       // reused after QKV GEMM
  bf16_t* xb    = (bf16_t*)(ws + 50331648);    // 4096*4096*2
  bf16_t* Qb    = xb;                          // reused after QKV GEMM
  bf16_t* qkv   = (bf16_t*)(ws + 83886080);    // 4096*6144*2
  bf16_t* attn_out = qkv;                      // reused after rope/transpose_v
  bf16_t* Kb    = (bf16_t*)(ws + 134217728);
  bf16_t* Vt    = (bf16_t*)(ws + 142606336);

  convert_f32_bf16<<<16384, 256, 0, stream>>>(x, xb, 4194304);
  transpose_convert<<<dim3(128, 128), 256, 0, stream>>>(wq, wqkvT, 4096);
  transpose_convert<<<dim3(32, 128), 256, 0, stream>>>(wk, wqkvT + (size_t)4096 * 4096, 1024);
  transpose_convert<<<dim3(32, 128), 256, 0, stream>>>(wv, wqkvT + (size_t)5120 * 4096, 1024);

  gemm192<<<dim3(32, 32), 256, 0, stream>>>(xb, wqkvT, qkv, 4096, 6144, 4096);

  transpose_convert<<<dim3(128, 128), 256, 0, stream>>>(wo, woT, 4096);  // wqkvT now dead
  rope_qk<<<10240, 256, 0, stream>>>(qkv, cosT, sinT, Qb, Kb);           // xb now dead
  transpose_v<<<dim3(64, 4, 16), 256, 0, stream>>>(qkv, Vt);

  attn_kernel<<<dim3(8, 64), 256, 0, stream>>>(Qb, Kb, Vt, attn_out);    // qkv now dead

  gemm256j<<<dim3(16, 16), 512, 0, stream>>>(attn_out, woT, out, 4096, 4096, 4096);
}

// Round 17
// 511.240 us; speedup vs baseline: 1.1432x; 1.0039x over previous
//
#include <hip/hip_runtime.h>

typedef __bf16 bf16_t;
typedef __bf16 bf16x8 __attribute__((ext_vector_type(8)));
typedef __bf16 bf16x4 __attribute__((ext_vector_type(4)));
typedef float  f32x4  __attribute__((ext_vector_type(4)));
typedef float  f32x16 __attribute__((ext_vector_type(16)));

#define NB   2
#define NS   2048
#define ND   4096
#define NH   32
#define NKVH 8
#define NHD  128

#define BAR()     asm volatile("s_barrier" ::: "memory")
#define LGKM0()   asm volatile("s_waitcnt lgkmcnt(0)" ::: "memory")
#define VMCNT10() asm volatile("s_waitcnt vmcnt(10)" ::: "memory")
#define VMCNT8()  asm volatile("s_waitcnt vmcnt(8)" ::: "memory")
#define VMCNT6()  asm volatile("s_waitcnt vmcnt(6)" ::: "memory")
#define VMCNT0()  asm volatile("s_waitcnt vmcnt(0)" ::: "memory")

__device__ __forceinline__ void gl_lds16(const bf16_t* g, bf16_t* l) {
  __builtin_amdgcn_global_load_lds(
      (const __attribute__((address_space(1))) void*)g,
      (__attribute__((address_space(3))) void*)l, 16, 0, 0);
}

// ---------------- convert x fp32 -> bf16 ----------------
__global__ void convert_f32_bf16(const float* __restrict__ in, bf16_t* __restrict__ out, int n4) {
  int i = blockIdx.x * 256 + threadIdx.x;
  if (i < n4) {
    f32x4 v = *(const f32x4*)&in[(size_t)i * 4];
    bf16x4 o;
    #pragma unroll
    for (int j = 0; j < 4; ++j) o[j] = (bf16_t)v[j];
    *(bf16x4*)&out[(size_t)i * 4] = o;
  }
}

// ------------- transpose-convert W[4096][Nin] fp32 -> Wt[Nin][4096] bf16 -------------
__global__ void transpose_convert(const float* __restrict__ in, bf16_t* __restrict__ out, int Nin) {
  __shared__ float t[32][33];
  int tx = threadIdx.x & 31, ty = threadIdx.x >> 5;
  int n0 = blockIdx.x * 32, k0 = blockIdx.y * 32;
  #pragma unroll
  for (int i = 0; i < 4; ++i)
    t[ty + i * 8][tx] = in[(size_t)(k0 + ty + i * 8) * Nin + n0 + tx];
  __syncthreads();
  #pragma unroll
  for (int i = 0; i < 4; ++i)
    out[(size_t)(n0 + ty + i * 8) * 4096 + k0 + tx] = (bf16_t)t[tx][ty + i * 8];
}

// ============ 128x192 GEMM for QKV: 2-PHASE, 2x2 wave grid, 2 BLOCKS/CU (R16-proven) ============
__global__ __launch_bounds__(256, 2) void gemm192(const bf16_t* __restrict__ A,
                                                  const bf16_t* __restrict__ Bt,
                                                  bf16_t* __restrict__ C, int M, int N, int K) {
  __shared__ __align__(16) bf16_t As[2][128 * 64];
  __shared__ __align__(16) bf16_t Bs[2][192 * 64];
  const int tid = threadIdx.x, lane = tid & 63, wid = tid >> 6;
  const int l15 = lane & 15, l4 = lane >> 4;
  const int wm = wid >> 1, wn = wid & 1;

  const int gx = gridDim.x;
  const int nwg = gx * gridDim.y;
  const int id = blockIdx.y * gx + blockIdx.x;
  const int wg = (id & 7) * (nwg >> 3) + (id >> 3);
  const int bx = wg % gx, by = wg / gx;
  const int row0 = bx * 128, col0 = by * 192;

  const bf16_t* Ab = A + (size_t)row0 * K;
  const bf16_t* Bb = Bt + (size_t)col0 * K;

  auto stA = [&](int t, int buf) {
    #pragma unroll
    for (int i = 0; i < 4; ++i) {
      int phys = i * 4096 + tid * 16;
      int logi = phys ^ (((phys >> 8) & 7) << 4);
      gl_lds16(Ab + (size_t)(logi >> 7) * K + t * 64 + ((logi & 127) >> 1),
               &As[buf][phys >> 1]);
    }
  };
  auto stB = [&](int t, int buf) {
    #pragma unroll
    for (int i = 0; i < 6; ++i) {
      int phys = i * 4096 + tid * 16;
      int logi = phys ^ (((phys >> 8) & 7) << 4);
      gl_lds16(Bb + (size_t)(logi >> 7) * K + t * 64 + ((logi & 127) >> 1),
               &Bs[buf][phys >> 1]);
    }
  };

  f32x4 acc[4][6];
  #pragma unroll
  for (int m = 0; m < 4; ++m)
    #pragma unroll
    for (int n = 0; n < 6; ++n)
      #pragma unroll
      for (int j = 0; j < 4; ++j) acc[m][n][j] = 0.f;

  const int nt = K >> 6;
  stA(0, 0); stB(0, 0);
  stA(1, 1); stB(1, 1);
  VMCNT10();
  BAR();

  auto ardA = [&](int buf, int mf, int kh) -> bf16x8 {
    int lb = (wm * 64 + mf * 16 + l15) * 128 + kh * 64 + l4 * 16;
    return *(const bf16x8*)&As[buf][(lb ^ (((lb >> 8) & 7) << 4)) >> 1];
  };
  auto brdB = [&](int buf, int kh, int nf) -> bf16x8 {
    int lb = (wn * 96 + nf * 16 + l15) * 128 + kh * 64 + l4 * 16;
    return *(const bf16x8*)&Bs[buf][(lb ^ (((lb >> 8) & 7) << 4)) >> 1];
  };

  #pragma unroll 2
  for (int t = 0; t < nt; ++t) {
    const int cur = t & 1;
    bf16x8 a[4][2], b0[6], b1[6];

    #pragma unroll
    for (int mf = 0; mf < 4; ++mf)
      #pragma unroll
      for (int kh = 0; kh < 2; ++kh) a[mf][kh] = ardA(cur, mf, kh);
    #pragma unroll
    for (int nf = 0; nf < 6; ++nf) b0[nf] = brdB(cur, 0, nf);
    BAR();
    LGKM0();
    __builtin_amdgcn_s_setprio(1);
    #pragma unroll
    for (int mf = 0; mf < 4; ++mf)
      #pragma unroll
      for (int nf = 0; nf < 6; ++nf)
        acc[mf][nf] = __builtin_amdgcn_mfma_f32_16x16x32_bf16(a[mf][0], b0[nf], acc[mf][nf], 0, 0, 0);
    __builtin_amdgcn_s_setprio(0);
    BAR();

    #pragma unroll
    for (int nf = 0; nf < 6; ++nf) b1[nf] = brdB(cur, 1, nf);
    if (t + 2 < nt) { stA(t + 2, cur); stB(t + 2, cur); }
    BAR();
    LGKM0();
    __builtin_amdgcn_s_setprio(1);
    #pragma unroll
    for (int mf = 0; mf < 4; ++mf)
      #pragma unroll
      for (int nf = 0; nf < 6; ++nf)
        acc[mf][nf] = __builtin_amdgcn_mfma_f32_16x16x32_bf16(a[mf][1], b1[nf], acc[mf][nf], 0, 0, 0);
    __builtin_amdgcn_s_setprio(0);
    if (t + 2 < nt) { VMCNT10(); } else { VMCNT0(); }
    BAR();
  }

  #pragma unroll
  for (int mf = 0; mf < 4; ++mf)
    #pragma unroll
    for (int nf = 0; nf < 6; ++nf)
      #pragma unroll
      for (int r = 0; r < 4; ++r) {
        size_t row = (size_t)row0 + wm * 64 + mf * 16 + l4 * 4 + r;
        size_t col = (size_t)col0 + wn * 96 + nf * 16 + l15;
        C[row * N + col] = (bf16_t)acc[mf][nf][r];
      }
}

// ============ 256x256 GEMM for WO: 2-PHASE schedule (R13-proven) ============
__global__ __launch_bounds__(512, 2) void gemm256j(const bf16_t* __restrict__ A,
                                                   const bf16_t* __restrict__ Bt,
                                                   float* __restrict__ C, int M, int N, int K) {
  __shared__ __align__(16) bf16_t As[2][2][128 * 64];
  __shared__ __align__(16) bf16_t Bs[2][256 * 64];
  const int tid = threadIdx.x, lane = tid & 63, wid = tid >> 6;
  const int l15 = lane & 15, l4 = lane >> 4;
  const int wm = wid >> 2, wn = wid & 3;

  const int gx = gridDim.x;
  const int nwg = gx * gridDim.y;
  const int id = blockIdx.y * gx + blockIdx.x;
  const int wg = (id & 7) * (nwg >> 3) + (id >> 3);
  const int bx = wg % gx, by = wg / gx;
  const int row0 = bx * 256, col0 = by * 256;

  const bf16_t* Ab = A + (size_t)row0 * K;
  const bf16_t* Bb = Bt + (size_t)col0 * K;

  auto stA = [&](int t, int h, int buf) {
    #pragma unroll
    for (int i = 0; i < 2; ++i) {
      int phys = i * 8192 + tid * 16;
      int logi = phys ^ (((phys >> 8) & 7) << 4);
      gl_lds16(Ab + (size_t)(h * 128 + (logi >> 7)) * K + t * 64 + ((logi & 127) >> 1),
               &As[buf][h][phys >> 1]);
    }
  };
  auto stB = [&](int t, int buf) {
    #pragma unroll
    for (int i = 0; i < 4; ++i) {
      int phys = i * 8192 + tid * 16;
      int logi = phys ^ (((phys >> 8) & 7) << 4);
      gl_lds16(Bb + (size_t)(logi >> 7) * K + t * 64 + ((logi & 127) >> 1),
               &Bs[buf][phys >> 1]);
    }
  };

  f32x4 acc[8][4];
  #pragma unroll
  for (int m = 0; m < 8; ++m)
    #pragma unroll
    for (int n = 0; n < 4; ++n)
      #pragma unroll
      for (int j = 0; j < 4; ++j) acc[m][n][j] = 0.f;

  const int nt = K >> 6;
  stA(0, 0, 0); stA(0, 1, 0); stB(0, 0);
  stA(1, 0, 1); stB(1, 1);
  VMCNT6();
  BAR();

  auto ardA = [&](int buf, int mh, int kh, int mf) -> bf16x8 {
    int lb = (mh * 64 + mf * 16 + l15) * 128 + kh * 64 + l4 * 16;
    return *(const bf16x8*)&As[buf][wm][(lb ^ (((lb >> 8) & 7) << 4)) >> 1];
  };
  auto brdB = [&](int buf, int kh, int nf) -> bf16x8 {
    int lb = (wn * 64 + nf * 16 + l15) * 128 + kh * 64 + l4 * 16;
    return *(const bf16x8*)&Bs[buf][(lb ^ (((lb >> 8) & 7) << 4)) >> 1];
  };

  #pragma unroll 2
  for (int t = 0; t < nt; ++t) {
    const int cur = t & 1, nxt = cur ^ 1;
    bf16x8 a00[4], a01[4], a10[4], a11[4], b0[4], b1[4];

    #pragma unroll
    for (int mf = 0; mf < 4; ++mf) a00[mf] = ardA(cur, 0, 0, mf);
    #pragma unroll
    for (int nf = 0; nf < 4; ++nf) b0[nf] = brdB(cur, 0, nf);
    #pragma unroll
    for (int mf = 0; mf < 4; ++mf) a01[mf] = ardA(cur, 0, 1, mf);
    #pragma unroll
    for (int nf = 0; nf < 4; ++nf) b1[nf] = brdB(cur, 1, nf);
    if (t + 1 < nt) stA(t + 1, 1, nxt);
    BAR();
    LGKM0();
    __builtin_amdgcn_s_setprio(1);
    #pragma unroll
    for (int mf = 0; mf < 4; ++mf)
      #pragma unroll
      for (int nf = 0; nf < 4; ++nf)
        acc[mf][nf] = __builtin_amdgcn_mfma_f32_16x16x32_bf16(a00[mf], b0[nf], acc[mf][nf], 0, 0, 0);
    #pragma unroll
    for (int mf = 0; mf < 4; ++mf)
      #pragma unroll
      for (int nf = 0; nf < 4; ++nf)
        acc[mf][nf] = __builtin_amdgcn_mfma_f32_16x16x32_bf16(a01[mf], b1[nf], acc[mf][nf], 0, 0, 0);
    __builtin_amdgcn_s_setprio(0);
    BAR();

    #pragma unroll
    for (int mf = 0; mf < 4; ++mf) a10[mf] = ardA(cur, 1, 0, mf);
    #pragma unroll
    for (int mf = 0; mf < 4; ++mf) a11[mf] = ardA(cur, 1, 1, mf);
    if (t + 2 < nt) { stA(t + 2, 0, cur); stB(t + 2, cur); }
    BAR();
    LGKM0();
    __builtin_amdgcn_s_setprio(1);
    #pragma unroll
    for (int mf = 0; mf < 4; ++mf)
      #pragma unroll
      for (int nf = 0; nf < 4; ++nf)
        acc[4 + mf][nf] = __builtin_amdgcn_mfma_f32_16x16x32_bf16(a10[mf], b0[nf], acc[4 + mf][nf], 0, 0, 0);
    #pragma unroll
    for (int mf = 0; mf < 4; ++mf)
      #pragma unroll
      for (int nf = 0; nf < 4; ++nf)
        acc[4 + mf][nf] = __builtin_amdgcn_mfma_f32_16x16x32_bf16(a11[mf], b1[nf], acc[4 + mf][nf], 0, 0, 0);
    __builtin_amdgcn_s_setprio(0);
    if (t + 2 < nt) { VMCNT6(); } else { VMCNT0(); }
    BAR();
  }

  #pragma unroll
  for (int mh = 0; mh < 2; ++mh)
    #pragma unroll
    for (int mf = 0; mf < 4; ++mf)
      #pragma unroll
      for (int nf = 0; nf < 4; ++nf)
        #pragma unroll
        for (int r = 0; r < 4; ++r) {
          size_t row = (size_t)row0 + wm * 128 + mh * 64 + mf * 16 + l4 * 4 + r;
          size_t col = (size_t)col0 + wn * 64 + nf * 16 + l15;
          C[row * N + col] = acc[mh * 4 + mf][nf][r];
        }
}

// ---------------- RoPE on Q and K, reshape to [b][h][s][hd] ----------------
__global__ void rope_qk(const bf16_t* __restrict__ qkv, const float* __restrict__ cosT,
                        const float* __restrict__ sinT, bf16_t* __restrict__ Q,
                        bf16_t* __restrict__ Kout) {
  int it = blockIdx.x * 256 + threadIdx.x;
  int chunk = it & 15;
  int hs = (it >> 4) % 40;
  int m = (it >> 4) / 40;
  int b = m >> 11, srow = m & 2047;

  bf16x8 v = *(const bf16x8*)&qkv[(size_t)m * 6144 + hs * 128 + chunk * 8];
  f32x4 c4 = *(const f32x4*)&cosT[(size_t)srow * 64 + chunk * 4];
  f32x4 s4 = *(const f32x4*)&sinT[(size_t)srow * 64 + chunk * 4];
  bf16x8 o;
  #pragma unroll
  for (int j = 0; j < 4; ++j) {
    float t1 = (float)v[2 * j], t2 = (float)v[2 * j + 1];
    o[2 * j]     = (bf16_t)(t1 * c4[j] - t2 * s4[j]);
    o[2 * j + 1] = (bf16_t)(t1 * s4[j] + t2 * c4[j]);
  }
  bf16_t* dst;
  if (hs < 32) dst = Q + (((size_t)(b * 32 + hs)) * 2048 + srow) * 128 + chunk * 8;
  else         dst = Kout + (((size_t)(b * 8 + (hs - 32))) * 2048 + srow) * 128 + chunk * 8;
  *(bf16x8*)dst = o;
}

// ---------------- transpose V section of qkv -> Vt[b*8+kv][128][2048] ----------------
__global__ void transpose_v(const bf16_t* __restrict__ qkv, bf16_t* __restrict__ Vt) {
  __shared__ bf16_t t[32][33];
  int tx = threadIdx.x & 31, ty = threadIdx.x >> 5;
  int s0 = blockIdx.x * 32, d0 = blockIdx.y * 32, g = blockIdx.z;
  int b = g >> 3, kv = g & 7;
  const bf16_t* src = qkv + (size_t)(b * 2048) * 6144 + 5120 + kv * 128;
  #pragma unroll
  for (int i = 0; i < 4; ++i)
    t[ty + i * 8][tx] = src[(size_t)(s0 + ty + i * 8) * 6144 + d0 + tx];
  __syncthreads();
  bf16_t* dst = Vt + (size_t)g * 128 * 2048;
  #pragma unroll
  for (int i = 0; i < 4; ++i)
    dst[(size_t)(d0 + ty + i * 8) * 2048 + s0 + tx] = t[tx][ty + i * 8];
}

// ---------------- causal flash attention: counted-vmcnt raw-barrier pipeline (R17) ----------------
// 4-wave blocks, 2 blocks/CU, T13 defer-max. __syncthreads (vmcnt(0) drain!) replaced
// by: issue stage(kt+1); vmcnt(8) [drain stage(kt), keep kt+1's 8 in flight]; BAR;
// compute(cur); BAR. Stage(kt+1)->nxt has 1 BAR after nxt's last reader (compute kt-1).
__global__ __launch_bounds__(256, 2) void attn_kernel(const bf16_t* __restrict__ Q,
                                                      const bf16_t* __restrict__ Kc,
                                                      const bf16_t* __restrict__ Vt,
                                                      bf16_t* __restrict__ Oout) {
  __shared__ __align__(16) bf16_t Ks[2][64 * 128];
  __shared__ __align__(16) bf16_t Vs[2][128 * 64];

  const int tid = threadIdx.x, wid = tid >> 6, lane = tid & 63;
  const int l31 = lane & 31, hi = lane >> 5;
  const int bh = blockIdx.y;
  const int b = bh >> 5, h = bh & 31, kv = h >> 2;
  const int pr = blockIdx.x;  // 0..7 ; pair {15-pr, pr} -> uniform 34 KV-tiles

  const bf16_t* Qp = Q + ((size_t)bh * 2048) * 128;
  const bf16_t* Kp = Kc + ((size_t)(b * 8 + kv) * 2048) * 128;
  const bf16_t* Vp = Vt + ((size_t)(b * 8 + kv) * 128) * 2048;

  const float kscale = 0.08838834764831845f * 1.44269504088896f;

  auto stage = [&](int kt, int buf) {
    const int k0 = kt * 64;
    #pragma unroll
    for (int i = 0; i < 4; ++i) {
      int phys = i * 4096 + tid * 16;
      int logi = phys ^ (((phys >> 8) & 15) << 4);
      gl_lds16(Kp + (size_t)(k0 + (phys >> 8)) * 128 + ((logi & 255) >> 1), &Ks[buf][phys >> 1]);
    }
    #pragma unroll
    for (int i = 0; i < 4; ++i) {
      int phys = i * 4096 + tid * 16;
      int logi = phys ^ (((phys >> 7) & 7) << 4);
      gl_lds16(Vp + (size_t)(phys >> 7) * 2048 + k0 + ((logi & 127) >> 1), &Vs[buf][phys >> 1]);
    }
  };

  for (int half = 0; half < 2; ++half) {
    const int qt = half ? pr : 15 - pr;
    const int q0b = qt * 128;
    const int q0w = q0b + wid * 32;
    const int qg = q0w + l31;
    const int nkt = (qt + 1) * 2;

    bf16x8 qf[8];
    #pragma unroll
    for (int c = 0; c < 8; ++c) {
      bf16x8 t = *(const bf16x8*)&Qp[(size_t)qg * 128 + c * 16 + hi * 8];
      #pragma unroll
      for (int j = 0; j < 8; ++j) t[j] = (bf16_t)((float)t[j] * kscale);
      qf[c] = t;
    }

    f32x16 oa[4];
    #pragma unroll
    for (int nc = 0; nc < 4; ++nc)
      #pragma unroll
      for (int r = 0; r < 16; ++r) oa[nc][r] = 0.f;
    float m_old = -1e30f, lrow = 0.f;

    stage(0, 0);

    for (int kt = 0; kt < nkt; ++kt) {
      const int k0 = kt * 64, cur = kt & 1;
      // issue next-tile prefetch, then counted drain of THIS tile's stage (T4)
      if (kt + 1 < nkt) { stage(kt + 1, cur ^ 1); VMCNT8(); } else { VMCNT0(); }
      BAR();

      if (k0 <= q0w + 31) {
        f32x16 s0, s1;
        #pragma unroll
        for (int r = 0; r < 16; ++r) { s0[r] = 0.f; s1[r] = 0.f; }
        __builtin_amdgcn_s_setprio(1);
        #pragma unroll
        for (int c = 0; c < 8; ++c) {
          int lb0 = l31 * 256 + c * 32 + hi * 16;
          int pb0 = lb0 ^ (((lb0 >> 8) & 15) << 4);
          bf16x8 kf0 = *(const bf16x8*)&Ks[cur][pb0 >> 1];
          s0 = __builtin_amdgcn_mfma_f32_32x32x16_bf16(kf0, qf[c], s0, 0, 0, 0);
          int lb1 = (32 + l31) * 256 + c * 32 + hi * 16;
          int pb1 = lb1 ^ (((lb1 >> 8) & 15) << 4);
          bf16x8 kf1 = *(const bf16x8*)&Ks[cur][pb1 >> 1];
          s1 = __builtin_amdgcn_mfma_f32_32x32x16_bf16(kf1, qf[c], s1, 0, 0, 0);
        }
        __builtin_amdgcn_s_setprio(0);

        if (k0 + 63 > q0w) {
          #pragma unroll
          for (int r = 0; r < 16; ++r) {
            int key0 = k0 + ((r & 3) + 8 * (r >> 2)) + 4 * hi;
            if (key0 > qg) s0[r] = -1e30f;
            if (key0 + 32 > qg) s1[r] = -1e30f;
          }
        }

        float m8[8];
        #pragma unroll
        for (int j = 0; j < 8; ++j)
          m8[j] = fmaxf(fmaxf(s0[j], s0[j + 8]), fmaxf(s1[j], s1[j + 8]));
        float ma = fmaxf(fmaxf(m8[0], m8[4]), fmaxf(m8[1], m8[5]));
        float mb = fmaxf(fmaxf(m8[2], m8[6]), fmaxf(m8[3], m8[7]));
        float mh = fmaxf(ma, mb);
        float mfull = fmaxf(mh, __shfl_xor(mh, 32));

        // T13 defer-max
        float mn;
        bool defer = (mfull - m_old <= 8.0f);
        if (__all((int)defer)) {
          mn = m_old;
        } else {
          mn = fmaxf(m_old, mfull);
          float sc = exp2f(m_old - mn);
          #pragma unroll
          for (int r = 0; r < 16; ++r) {
            int qi = (r & 3) + 8 * (r >> 2) + 4 * hi;
            float scv = __int_as_float(__builtin_amdgcn_ds_bpermute(qi << 2, __float_as_int(sc)));
            oa[0][r] *= scv; oa[1][r] *= scv; oa[2][r] *= scv; oa[3][r] *= scv;
          }
          lrow *= sc;
          m_old = mn;
        }

        #pragma unroll
        for (int r = 0; r < 16; ++r) {
          s0[r] = exp2f(s0[r] - mn);
          s1[r] = exp2f(s1[r] - mn);
        }
        float rsA = 0.f, rsB = 0.f, rsC = 0.f, rsD = 0.f;
        #pragma unroll
        for (int r = 0; r < 16; r += 4) {
          rsA += s0[r];     rsB += s0[r + 1]; rsC += s0[r + 2]; rsD += s0[r + 3];
          rsA += s1[r];     rsB += s1[r + 1]; rsC += s1[r + 2]; rsD += s1[r + 3];
        }
        float rs = (rsA + rsB) + (rsC + rsD);
        rs += __shfl_xor(rs, 32);
        lrow = lrow + rs;

        #pragma unroll
        for (int ks = 0; ks < 4; ++ks) {
          const int qi0 = (ks & 1) * 8;
          union { bf16_t hh[4]; int ii[2]; } ku, su;
          #pragma unroll
          for (int j = 0; j < 4; ++j) {
            float lo, hv;
            if (ks >> 1) { lo = s1[qi0 + j]; hv = s1[qi0 + 4 + j]; }
            else         { lo = s0[qi0 + j]; hv = s0[qi0 + 4 + j]; }
            ku.hh[j] = (bf16_t)(hi ? hv : lo);
            su.hh[j] = (bf16_t)(hi ? lo : hv);
          }
          int r0 = __shfl_xor(su.ii[0], 32), r1 = __shfl_xor(su.ii[1], 32);
          union { int ii[4]; bf16x8 v; } fa;
          fa.ii[0] = hi ? r0 : ku.ii[0];
          fa.ii[1] = hi ? r1 : ku.ii[1];
          fa.ii[2] = hi ? ku.ii[0] : r0;
          fa.ii[3] = hi ? ku.ii[1] : r1;
          __builtin_amdgcn_s_setprio(1);
          #pragma unroll
          for (int nc = 0; nc < 4; ++nc) {
            int lb = (nc * 32 + l31) * 128 + ks * 32 + hi * 16;
            int pb = lb ^ (((lb >> 7) & 7) << 4);
            bf16x8 vf = *(const bf16x8*)&Vs[cur][pb >> 1];
            oa[nc] = __builtin_amdgcn_mfma_f32_32x32x16_bf16(fa.v, vf, oa[nc], 0, 0, 0);
          }
          __builtin_amdgcn_s_setprio(0);
        }
      }
      BAR();  // reads of buf[cur] done before next iteration stages into it
    }

    float inv = 1.0f / lrow;
    bf16_t* Op = Oout + ((size_t)(b * 2048 + q0w)) * 4096 + (size_t)h * 128;
    #pragma unroll
    for (int r = 0; r < 16; ++r) {
      int qi = (r & 3) + 8 * (r >> 2) + 4 * hi;
      float iv = __int_as_float(__builtin_amdgcn_ds_bpermute(qi << 2, __float_as_int(inv)));
      #pragma unroll
      for (int nc = 0; nc < 4; ++nc)
        Op[(size_t)qi * 4096 + nc * 32 + l31] = (bf16_t)(oa[nc][r] * iv);
    }
  }
}

extern "C" void kernel_launch(void* const* d_in, const int* in_sizes, int n_in,
                              void* d_out, int out_size, void* d_ws, size_t ws_size,
                              hipStream_t stream) {
  const float* x    = (const float*)d_in[0];
  const float* cosT = (const float*)d_in[1];
  const float* sinT = (const float*)d_in[2];
  const float* wq   = (const float*)d_in[3];
  const float* wk   = (const float*)d_in[4];
  const float* wv   = (const float*)d_in[5];
  const float* wo   = (const float*)d_in[6];
  float* out = (float*)d_out;
  char* ws = (char*)d_ws;

  bf16_t* wqkvT = (bf16_t*)(ws + 0);           // 6144*4096*2
  bf16_t* woT   = wqkvT;                       // reused after QKV GEMM
  bf16_t* xb    = (bf16_t*)(ws + 50331648);    // 4096*4096*2
  bf16_t* Qb    = xb;                          // reused after QKV GEMM
  bf16_t* qkv   = (bf16_t*)(ws + 83886080);    // 4096*6144*2
  bf16_t* attn_out = qkv;                      // reused after rope/transpose_v
  bf16_t* Kb    = (bf16_t*)(ws + 134217728);
  bf16_t* Vt    = (bf16_t*)(ws + 142606336);

  convert_f32_bf16<<<16384, 256, 0, stream>>>(x, xb, 4194304);
  transpose_convert<<<dim3(128, 128), 256, 0, stream>>>(wq, wqkvT, 4096);
  transpose_convert<<<dim3(32, 128), 256, 0, stream>>>(wk, wqkvT + (size_t)4096 * 4096, 1024);
  transpose_convert<<<dim3(32, 128), 256, 0, stream>>>(wv, wqkvT + (size_t)5120 * 4096, 1024);

  gemm192<<<dim3(32, 32), 256, 0, stream>>>(xb, wqkvT, qkv, 4096, 6144, 4096);

  transpose_convert<<<dim3(128, 128), 256, 0, stream>>>(wo, woT, 4096);  // wqkvT now dead
  rope_qk<<<10240, 256, 0, stream>>>(qkv, cosT, sinT, Qb, Kb);           // xb now dead
  transpose_v<<<dim3(64, 4, 16), 256, 0, stream>>>(qkv, Vt);

  attn_kernel<<<dim3(8, 64), 256, 0, stream>>>(Qb, Kb, Vt, attn_out);    // qkv now dead

  gemm256j<<<dim3(16, 16), 512, 0, stream>>>(attn_out, woT, out, 4096, 4096, 4096);
}